// Round 5
// baseline (1418.330 us; speedup 1.0000x reference)
//
#include <hip/hip_runtime.h>
#include <math.h>

// ---------------------------------------------------------------------------
// 2-step recurrent attention cell, N=8, I=128, C=Hc=A=P=O=256, H=W=40
// (Q=1600), VALID 3x3 -> 38x38 (D=1444). fp32 reference.
//
// Algebraic reductions (R0-R2): step1 h uniform -> 9-class tables; step2 (0,1)
// attention collapses to 9 key classes; dead branches removed.
// R3: heavy GEMMs on MFMA via split-bf16 (f32 = hi+lo, 3 products).
// R4: classed section fused into shape-specialized kernels.
// R5: mgemm v2 (global_load_lds 16B DMA staging, KB=64, XOR-swizzled LDS ->
// conflict-free ds_read_b128, swap flag for L2-friendly block order); convs
// emit final layouts directly (qT/kxT/vxp/xaT) -- all transposing cvt passes
// deleted; attn_b1 coalesced epilogue.
// ---------------------------------------------------------------------------

typedef __attribute__((ext_vector_type(8))) short bf8;   // 8 bf16 (4 VGPRs)
typedef __attribute__((ext_vector_type(4))) float f4;

__device__ __forceinline__ ushort f2bf(float f) {
  unsigned u = __float_as_uint(f);
  u += 0x7fffu + ((u >> 16) & 1u);
  return (ushort)(u >> 16);
}
__device__ __forceinline__ float bf2f(ushort h) {
  return __uint_as_float(((unsigned)h) << 16);
}

// ---------------- MFMA split-bf16 GEMM v2 ----------------
// C[m][n] = sum_k A[m][k]*B[n][k], both k-contig, K % 64 == 0.
// 128x128 tile, 4 waves (64x64 quadrant each), KB=64 chunks.
// Staging: global_load_lds 16B; chunk c of row r stored at slot c^(r&7)
// (swizzle folded into the per-lane global address). LDS rows are 128 B
// (exact bank wrap) -> frag reads conflict-free.
// swap: if 1, blockIdx.x indexes n-tiles (x is dispatch-fastest).
// Epilogue modes:
//  0: fp32  Y[bz*sYb + (nn/nPer)*sYb2 + mm*sYm + nn%nPer] (+bias[mm])
//  1: pair  Yh/Yl[bz*sYpb + mm*sYpm + nn + pOff]          (+bias[nn] if biasN)
//  2: qk-split: gm=gRow0+mm -> (n8,q); nn<256 -> qT=Yh/Yl [n8][q][256];
//     else SAME->VALID crop -> kxT=Y2h/Y2l [n8][dp][256] at col nn-256
//  3: v-crop:   gn=gRow0+nn -> (n8,q); crop -> vxp=Yh/Yl [n8][mm][1472] col dp
__global__ __launch_bounds__(256) void mgemm(
    const ushort* __restrict__ Ah, const ushort* __restrict__ Al, long sAb,
    const ushort* __restrict__ Bh, const ushort* __restrict__ Bl, long sBb,
    int M, int Nn, int K, int mode, int gRow0, int swap,
    float* __restrict__ Y, long sYb, long sYm, int nPer, long sYb2,
    const float* __restrict__ bias, int biasN,
    ushort* __restrict__ Yh, ushort* __restrict__ Yl, long sYpb, long sYpm, long pOff,
    ushort* __restrict__ Y2h, ushort* __restrict__ Y2l)
{
  __shared__ ushort S[4][128][64];   // planes Ah,Al,Bh,Bl ; 64 KB
  const int bz = blockIdx.z;
  Ah += (long)bz * sAb; Al += (long)bz * sAb;
  Bh += (long)bz * sBb; Bl += (long)bz * sBb;
  const int mb = swap ? blockIdx.y : blockIdx.x;
  const int nb = swap ? blockIdx.x : blockIdx.y;
  const int m0 = mb * 128, n0 = nb * 128;
  const int t = threadIdx.x;
  const int lane = t & 63, wv = t >> 6;
  const int r = lane & 15, qd = lane >> 4;
  const int wm = (wv & 1) * 64, wn = (wv >> 1) * 64;
  const int lrow = lane >> 3, lch = lane & 7;     // staging: 8 lanes per row
  f4 acc[4][4];
  #pragma unroll
  for (int i = 0; i < 4; ++i)
    #pragma unroll
    for (int j = 0; j < 4; ++j) acc[i][j] = (f4){0.f, 0.f, 0.f, 0.f};

  ushort* lbase = (ushort*)S;
  for (int kc = 0; kc < K; kc += 64) {
    __syncthreads();                   // all waves done reading previous chunk
    #pragma unroll
    for (int i = 0; i < 4; ++i) {
      int row = wv * 32 + i * 8 + lrow;
      int cg = lch ^ (row & 7);        // swizzle folded into global address
      int seg = wv * 2048 + i * 512;   // wave-uniform LDS segment (ushorts)
      {
        int gr = m0 + row; if (gr > M - 1) gr = M - 1;
        size_t go = (size_t)gr * K + kc + cg * 8;
        __builtin_amdgcn_global_load_lds(Ah + go, lbase + seg, 16, 0, 0);
        __builtin_amdgcn_global_load_lds(Al + go, lbase + 8192 + seg, 16, 0, 0);
      }
      {
        int gr = n0 + row; if (gr > Nn - 1) gr = Nn - 1;
        size_t go = (size_t)gr * K + kc + cg * 8;
        __builtin_amdgcn_global_load_lds(Bh + go, lbase + 16384 + seg, 16, 0, 0);
        __builtin_amdgcn_global_load_lds(Bl + go, lbase + 24576 + seg, 16, 0, 0);
      }
    }
    __syncthreads();                   // waits vmcnt(0): DMA deposits complete
    #pragma unroll
    for (int kk = 0; kk < 2; ++kk) {
      int off = (((kk << 2) + qd) ^ (r & 7)) << 3;   // swizzled chunk * 8
      bf8 ah[4], al[4], bh[4], bl[4];
      #pragma unroll
      for (int mt = 0; mt < 4; ++mt) {
        ah[mt] = *(const bf8*)&S[0][wm + mt * 16 + r][off];
        al[mt] = *(const bf8*)&S[1][wm + mt * 16 + r][off];
        bh[mt] = *(const bf8*)&S[2][wn + mt * 16 + r][off];
        bl[mt] = *(const bf8*)&S[3][wn + mt * 16 + r][off];
      }
      #pragma unroll
      for (int mt = 0; mt < 4; ++mt)
        #pragma unroll
        for (int nt = 0; nt < 4; ++nt) {
          acc[mt][nt] = __builtin_amdgcn_mfma_f32_16x16x32_bf16(ah[mt], bh[nt], acc[mt][nt], 0, 0, 0);
          acc[mt][nt] = __builtin_amdgcn_mfma_f32_16x16x32_bf16(ah[mt], bl[nt], acc[mt][nt], 0, 0, 0);
          acc[mt][nt] = __builtin_amdgcn_mfma_f32_16x16x32_bf16(al[mt], bh[nt], acc[mt][nt], 0, 0, 0);
        }
    }
  }
  #pragma unroll
  for (int mt = 0; mt < 4; ++mt)
    #pragma unroll
    for (int nt = 0; nt < 4; ++nt) {
      int nn = n0 + wn + nt * 16 + r;
      if (nn >= Nn) continue;
      #pragma unroll
      for (int e = 0; e < 4; ++e) {
        int mm = m0 + wm + mt * 16 + qd * 4 + e;
        if (mm >= M) continue;
        float v = acc[mt][nt][e];
        if (mode == 0) {
          if (bias) v += bias[mm];
          int b2 = nn / nPer, nq = nn - b2 * nPer;
          Y[(size_t)bz * sYb + (size_t)b2 * sYb2 + (size_t)mm * sYm + nq] = v;
        } else if (mode == 1) {
          if (bias) v += bias[biasN ? nn : mm];
          size_t o = (size_t)bz * sYpb + (size_t)mm * sYpm + nn + pOff;
          ushort h = f2bf(v);
          Yh[o] = h; Yl[o] = f2bf(v - bf2f(h));
        } else if (mode == 2) {
          int gm = gRow0 + mm;
          int n8 = gm / 1600, q = gm - n8 * 1600;
          ushort h = f2bf(v), l = f2bf(v - bf2f(h));
          if (nn < 256) {
            size_t o = (size_t)n8 * 409600 + (size_t)q * 256 + nn;
            Yh[o] = h; Yl[o] = l;
          } else {
            int qy = q / 40, qx = q - qy * 40;
            if (qy >= 1 && qy <= 38 && qx >= 1 && qx <= 38) {
              size_t o = (size_t)n8 * 369664 + (size_t)((qy - 1) * 38 + qx - 1) * 256 + (nn - 256);
              Y2h[o] = h; Y2l[o] = l;
            }
          }
        } else {   // mode 3
          int gn = gRow0 + nn;
          int n8 = gn / 1600, q = gn - n8 * 1600;
          int qy = q / 40, qx = q - qy * 40;
          if (qy >= 1 && qy <= 38 && qx >= 1 && qx <= 38) {
            size_t o = (size_t)n8 * 376832 + (size_t)mm * 1472 + (qy - 1) * 38 + qx - 1;
            ushort h = f2bf(v);
            Yh[o] = h; Yl[o] = f2bf(v - bf2f(h));
          }
        }
      }
    }
}

// generic fp32 -> bf16 hi/lo pair conversion (strided read, contig write)
__global__ __launch_bounds__(256) void cvt_pair(
    const float* __restrict__ src, long s0, long s1, long sb,
    ushort* __restrict__ dh, ushort* __restrict__ dl, long d0, long db,
    int n0, int n1, int pad1, long total)
{
  long i = (long)blockIdx.x * 256 + threadIdx.x;
  if (i >= total) return;
  int wdt = n1 + pad1;
  int i1 = (int)(i % wdt); long rr = i / wdt;
  int i0 = (int)(rr % n0); int b = (int)(rr / n0);
  float f = 0.f;
  if (i1 < n1) f = src[(long)b * sb + (long)i0 * s0 + (long)i1 * s1];
  ushort h = f2bf(f);
  dh[(long)b * db + (long)i0 * d0 + i1] = h;
  dl[(long)b * db + (long)i0 * d0 + i1] = f2bf(f - bf2f(h));
}

// concat w_qx|w_kx -> Wqk pair [512][2304]
__global__ __launch_bounds__(256) void concat_wqk(
    const float* __restrict__ wq, const float* __restrict__ wk,
    ushort* __restrict__ dh, ushort* __restrict__ dl)
{
  int i = blockIdx.x * 256 + threadIdx.x;
  if (i >= 512 * 2304) return;
  float f = (i < 256 * 2304) ? wq[i] : wk[i - 256 * 2304];
  ushort h = f2bf(f);
  dh[i] = h; dl[i] = f2bf(f - bf2f(h));
}

// im2col (SAME 3x3, row-per-position) copying hi/lo planes from xaT cols 0..255
__global__ __launch_bounds__(256) void im2colT(
    const ushort* __restrict__ xaTh, const ushort* __restrict__ xaTl,
    ushort* __restrict__ dh, ushort* __restrict__ dl, int nb0, long total)
{
  long i = (long)blockIdx.x * 256 + threadIdx.x;
  if (i >= total) return;
  int k = (int)(i % 2304); long rr = i / 2304;
  int q = (int)(rr % 1600); int nbl = (int)(rr / 1600);
  int c = k / 9, tap = k - c * 9;
  int dy = tap / 3, dx = tap - dy * 3;
  int qy = q / 40, qx = q - qy * 40;
  int y = qy + dy - 1, x = qx + dx - 1;
  ushort h = 0, l = 0;
  if (y >= 0 && y < 40 && x >= 0 && x < 40) {
    size_t o = ((size_t)(nb0 + nbl) * 1600 + y * 40 + x) * 768 + c;
    h = xaTh[o]; l = xaTl[o];
  }
  dh[i] = h; dl[i] = l;
}

// zero the vxp pad columns 1444..1471 (ws is re-poisoned every call)
__global__ __launch_bounds__(256) void pad_vxp(
    ushort* __restrict__ vxph, ushort* __restrict__ vxpl)
{
  int i = blockIdx.x * 256 + threadIdx.x;
  if (i >= 8 * 256 * 28) return;
  int j = i % 28; int rr = i / 28;
  int c = rr % 256; int n = rr / 256;
  size_t o = (size_t)n * 376832 + (size_t)c * 1472 + 1444 + j;
  vxph[o] = 0; vxpl[o] = 0;
}

// step-1 uniform-h class tables: j<9 -> q_h1[j][a]; j==9 -> k_h1[a]; j==10 -> v_h1[a]
__global__ __launch_bounds__(64) void uniform_kv_kern(
    const float* __restrict__ h0, const float* __restrict__ w_qh,
    const float* __restrict__ w_kh, const float* __restrict__ w_vh,
    float* __restrict__ qh1, float* __restrict__ kh1, float* __restrict__ vh1)
{
  int a = blockIdx.x, j = blockIdx.y, t = threadIdx.x;
  const float* wsel = (j < 9) ? w_qh : (j == 9) ? w_kh : w_vh;
  bool dyok0 = true, dyok2 = true, dxok0 = true, dxok2 = true;
  if (j < 9) {
    int uy = j / 3, ux = j - uy * 3;
    dyok0 = (uy != 0); dyok2 = (uy != 2);
    dxok0 = (ux != 0); dxok2 = (ux != 2);
  }
  float acc = 0.f;
  for (int c = t; c < 256; c += 64) {
    const float* wp = wsel + a * 2304 + c * 9;
    float s = 0.f;
    #pragma unroll
    for (int dy = 0; dy < 3; ++dy) {
      if ((dy == 0 && !dyok0) || (dy == 2 && !dyok2)) continue;
      #pragma unroll
      for (int dx = 0; dx < 3; ++dx) {
        if ((dx == 0 && !dxok0) || (dx == 2 && !dxok2)) continue;
        s += wp[dy * 3 + dx];
      }
    }
    acc += s * h0[c];
  }
  #pragma unroll
  for (int o = 32; o; o >>= 1) acc += __shfl_down(acc, o);
  if (t == 0) {
    if (j < 9) qh1[j * 256 + a] = acc;
    else if (j == 9) kh1[a] = acc;
    else vh1[a] = acc;
  }
}

// L0[n][u][d] = sum_c qh1[u][c] * k_x[n][d][c]  (k from kxT pair)
__global__ __launch_bounds__(256) void l0_logits(
    const float* __restrict__ qh1, const ushort* __restrict__ kxTh,
    const ushort* __restrict__ kxTl, float* __restrict__ L0)
{
  __shared__ float qs[2304];
  int db = blockIdx.x, n = blockIdx.y;
  for (int i = threadIdx.x; i < 2304; i += 256) qs[i] = qh1[i];
  __syncthreads();
  int d = db * 256 + threadIdx.x;
  bool act = d < 1444;
  size_t ro = (size_t)n * 369664 + (act ? (size_t)d * 256 : 0);
  const ushort* vh = kxTh + ro;
  const ushort* vl = kxTl + ro;
  float acc[9] = {0.f,0.f,0.f,0.f,0.f,0.f,0.f,0.f,0.f};
  for (int c8 = 0; c8 < 256; c8 += 8) {
    uint4 H = *(const uint4*)(vh + c8);
    uint4 L = *(const uint4*)(vl + c8);
    unsigned hw[4] = {H.x, H.y, H.z, H.w};
    unsigned lw[4] = {L.x, L.y, L.z, L.w};
    #pragma unroll
    for (int j = 0; j < 4; ++j) {
      float f0 = bf2f((ushort)(hw[j] & 0xffff)) + bf2f((ushort)(lw[j] & 0xffff));
      float f1 = bf2f((ushort)(hw[j] >> 16)) + bf2f((ushort)(lw[j] >> 16));
      int c = c8 + j * 2;
      #pragma unroll
      for (int u = 0; u < 9; ++u) acc[u] += qs[u * 256 + c] * f0 + qs[u * 256 + c + 1] * f1;
    }
  }
  if (act)
    for (int u = 0; u < 9; ++u) L0[n * 12996 + u * 1444 + d] = acc[u];
}

// fp32 in-place row softmax
__global__ __launch_bounds__(256) void softmax_rows(float* __restrict__ p, int L)
{
  float* rp = p + (long)blockIdx.x * L;
  int t = threadIdx.x;
  __shared__ float redm[4], reds[4];
  float mx = -3.4e38f;
  for (int i = t; i < L; i += 256) mx = fmaxf(mx, rp[i]);
  #pragma unroll
  for (int o = 32; o; o >>= 1) mx = fmaxf(mx, __shfl_down(mx, o));
  if ((t & 63) == 0) redm[t >> 6] = mx;
  __syncthreads();
  mx = fmaxf(fmaxf(redm[0], redm[1]), fmaxf(redm[2], redm[3]));
  float s = 0.f;
  for (int i = t; i < L; i += 256) { float v = expf(rp[i] - mx); rp[i] = v; s += v; }
  #pragma unroll
  for (int o = 32; o; o >>= 1) s += __shfl_down(s, o);
  if ((t & 63) == 0) reds[t >> 6] = s;
  __syncthreads();
  float inv = 1.f / (reds[0] + reds[1] + reds[2] + reds[3]);
  for (int i = t; i < L; i += 256) rp[i] *= inv;
}

// a10[n][u][p] = sum_d wt[n][u][d] * v[n][p][d]  (v from vxp pair)
__global__ __launch_bounds__(256) void a10_pv(
    const float* __restrict__ L0, const ushort* __restrict__ vxph,
    const ushort* __restrict__ vxpl, float* __restrict__ a10)
{
  int u = blockIdx.x, n = blockIdx.y;   // grid(9,8)
  __shared__ float wts[1472];
  const float* wrow = L0 + n * 12996 + u * 1444;
  for (int i = threadIdx.x; i < 1472; i += 256) wts[i] = (i < 1444) ? wrow[i] : 0.f;
  __syncthreads();
  int p = threadIdx.x;
  const ushort* vh = vxph + (size_t)n * 376832 + (size_t)p * 1472;
  const ushort* vl = vxpl + (size_t)n * 376832 + (size_t)p * 1472;
  float acc = 0.f;
  for (int d8 = 0; d8 < 1472; d8 += 8) {
    uint4 hv = *(const uint4*)(vh + d8);
    uint4 lv = *(const uint4*)(vl + d8);
    unsigned hw[4] = {hv.x, hv.y, hv.z, hv.w};
    unsigned lw[4] = {lv.x, lv.y, lv.z, lv.w};
    #pragma unroll
    for (int j = 0; j < 4; ++j) {
      float f0 = bf2f((ushort)(hw[j] & 0xffff)) + bf2f((ushort)(lw[j] & 0xffff));
      float f1 = bf2f((ushort)(hw[j] >> 16)) + bf2f((ushort)(lw[j] >> 16));
      acc += wts[d8 + j * 2] * f0 + wts[d8 + j * 2 + 1] * f1;
    }
  }
  a10[n * 2304 + u * 256 + p] = acc;
}

// gates fused: z/h preact + GRU blend, 9 classes
__global__ __launch_bounds__(256) void gates_k(
    const float* __restrict__ a10, const float* __restrict__ vh1,
    const float* __restrict__ w_z, const float* __restrict__ b_z,
    const float* __restrict__ w_h, const float* __restrict__ b_h,
    const float* __restrict__ h0, float* __restrict__ h1)
{
  int n = blockIdx.x;
  __shared__ float as[2304], vs[256];
  for (int i = threadIdx.x; i < 2304; i += 256) as[i] = a10[n * 2304 + i];
  if (threadIdx.x < 256) vs[threadIdx.x] = vh1[threadIdx.x];
  __syncthreads();
  int hc = threadIdx.x;
  const float* wz = w_z + hc * 512;
  const float* wh = w_h + hc * 512;
  float az[9], ah[9];
  float bz = b_z[hc], bh = b_h[hc];
  #pragma unroll
  for (int u = 0; u < 9; ++u) { az[u] = bz; ah[u] = bh; }
  for (int k = 0; k < 256; ++k) {
    float wzv = wz[k], whv = wh[k];
    #pragma unroll
    for (int u = 0; u < 9; ++u) {
      float vv = as[u * 256 + k];
      az[u] += wzv * vv; ah[u] += whv * vv;
    }
  }
  float sz = 0.f, sh = 0.f;
  for (int k = 0; k < 256; ++k) { float vv = vs[k]; sz += wz[256 + k] * vv; sh += wh[256 + k] * vv; }
  float h0v = h0[hc];
  #pragma unroll
  for (int u = 0; u < 9; ++u) {
    float z = 1.f / (1.f + expf(-(az[u] + sz)));
    float hv = tanhf(ah[u] + sh);
    h1[n * 2304 + hc * 9 + u] = z * h0v + (1.f - z) * hv;
  }
}

// khc/vhc: classed VALID conv over piecewise-constant h1
__global__ __launch_bounds__(256) void khvh_k(
    const float* __restrict__ h1, const float* __restrict__ w_kh,
    const float* __restrict__ w_vh, float* __restrict__ khc, float* __restrict__ vhc)
{
  int u = blockIdx.x, n = blockIdx.y;   // grid(9,8)
  int ty = u / 3, tx = u - ty * 3;
  __shared__ float Gs[2304];
  for (int k = threadIdx.x; k < 2304; k += 256) {
    int c = k / 9, tap = k - c * 9, dy = tap / 3, dx = tap - dy * 3;
    int uy = (ty == 0) ? (dy == 0 ? 0 : 1) : (ty == 2) ? (dy == 2 ? 2 : 1) : 1;
    int ux = (tx == 0) ? (dx == 0 ? 0 : 1) : (tx == 2) ? (dx == 2 ? 2 : 1) : 1;
    Gs[k] = h1[n * 2304 + c * 9 + uy * 3 + ux];
  }
  __syncthreads();
  int hc = threadIdx.x;
  const float* wk = w_kh + hc * 2304;
  const float* wv = w_vh + hc * 2304;
  float ak = 0.f, av = 0.f;
  for (int k = 0; k < 2304; ++k) { float g = Gs[k]; ak += wk[k] * g; av += wv[k] * g; }
  khc[n * 2304 + hc * 9 + u] = ak;
  vhc[n * 2304 + hc * 9 + u] = av;
}

// softmax over 1444 logits -> bf16 pair rows padded to 1472
__global__ __launch_bounds__(256) void softmax_pair(
    const float* __restrict__ p, ushort* __restrict__ wh, ushort* __restrict__ wl)
{
  long row = blockIdx.x;
  const float* rp = p + row * 1444;
  ushort* oh = wh + row * 1472;
  ushort* ol = wl + row * 1472;
  int t = threadIdx.x;
  __shared__ float buf[1444];
  __shared__ float redm[4], reds[4];
  float mx = -3.4e38f;
  for (int i = t; i < 1444; i += 256) { float v = rp[i]; buf[i] = v; mx = fmaxf(mx, v); }
  #pragma unroll
  for (int o = 32; o; o >>= 1) mx = fmaxf(mx, __shfl_down(mx, o));
  if ((t & 63) == 0) redm[t >> 6] = mx;
  __syncthreads();
  mx = fmaxf(fmaxf(redm[0], redm[1]), fmaxf(redm[2], redm[3]));
  float s = 0.f;
  for (int i = t; i < 1444; i += 256) { float v = expf(buf[i] - mx); buf[i] = v; s += v; }
  #pragma unroll
  for (int o = 32; o; o >>= 1) s += __shfl_down(s, o);
  if ((t & 63) == 0) reds[t >> 6] = s;
  __syncthreads();
  float inv = 1.f / (reds[0] + reds[1] + reds[2] + reds[3]);
  for (int i = t; i < 1472; i += 256) {
    float v = (i < 1444) ? buf[i] * inv : 0.f;
    ushort h = f2bf(v);
    oh[i] = h; ol[i] = f2bf(v - bf2f(h));
  }
}

// step-2 (a=0,b=1) classed attention; q from qT pair; coalesced pair output
__global__ __launch_bounds__(256) void attn_b1(
    const ushort* __restrict__ qTh, const ushort* __restrict__ qTl,
    const float* __restrict__ khc, const float* __restrict__ vhc,
    ushort* __restrict__ xaTh, ushort* __restrict__ xaTl)
{
  __shared__ float ks[2304];
  __shared__ float vs[2304];
  __shared__ float es[256][10];
  int n = blockIdx.y;
  int q0 = blockIdx.x * 256;
  for (int i = threadIdx.x; i < 2304; i += 256) { ks[i] = khc[n * 2304 + i]; vs[i] = vhc[n * 2304 + i]; }
  __syncthreads();
  int q = q0 + threadIdx.x;
  bool act = (q < 1600);
  float Lg[9] = {0.f,0.f,0.f,0.f,0.f,0.f,0.f,0.f,0.f};
  size_t ro = (size_t)n * 409600 + (act ? (size_t)q * 256 : 0);
  const ushort* qh = qTh + ro;
  const ushort* ql = qTl + ro;
  for (int c8 = 0; c8 < 256; c8 += 8) {
    uint4 H = *(const uint4*)(qh + c8);
    uint4 L = *(const uint4*)(ql + c8);
    unsigned hw[4] = {H.x, H.y, H.z, H.w};
    unsigned lw[4] = {L.x, L.y, L.z, L.w};
    #pragma unroll
    for (int j = 0; j < 4; ++j) {
      float f0 = bf2f((ushort)(hw[j] & 0xffff)) + bf2f((ushort)(lw[j] & 0xffff));
      float f1 = bf2f((ushort)(hw[j] >> 16)) + bf2f((ushort)(lw[j] >> 16));
      int c = c8 + j * 2;
      #pragma unroll
      for (int tt = 0; tt < 9; ++tt)
        Lg[tt] += f0 * ks[c * 9 + tt] + f1 * ks[(c + 1) * 9 + tt];
    }
  }
  float mx = Lg[0];
  #pragma unroll
  for (int tt = 1; tt < 9; ++tt) mx = fmaxf(mx, Lg[tt]);
  float Z = 0.f;
  float e[9];
  #pragma unroll
  for (int tt = 0; tt < 9; ++tt) {
    float m = ((tt / 3) == 1 ? 36.f : 1.f) * ((tt % 3) == 1 ? 36.f : 1.f);
    e[tt] = act ? m * expf(Lg[tt] - mx) : 0.f;
    Z += e[tt];
  }
  float inv = act ? (1.f / Z) : 0.f;
  #pragma unroll
  for (int tt = 0; tt < 9; ++tt) es[threadIdx.x][tt] = e[tt] * inv;
  __syncthreads();
  int nact = 1600 - q0; if (nact > 256) nact = 256;
  int p = threadIdx.x;
  for (int qq = 0; qq < nact; ++qq) {
    float s = 0.f;
    #pragma unroll
    for (int tt = 0; tt < 9; ++tt) s += es[qq][tt] * vs[p * 9 + tt];
    ushort h = f2bf(s);
    size_t o = (size_t)n * 1228800 + (size_t)(q0 + qq) * 768 + 512 + p;
    xaTh[o] = h; xaTl[o] = f2bf(s - bf2f(h));
  }
}

// ---------------------------------------------------------------------------
extern "C" void kernel_launch(void* const* d_in, const int* in_sizes, int n_in,
                              void* d_out, int out_size, void* d_ws, size_t ws_size,
                              hipStream_t stream)
{
  const float* x     = (const float*)d_in[0];
  const float* h0    = (const float*)d_in[1];
  const float* w_px  = (const float*)d_in[2];
  const float* b_px  = (const float*)d_in[3];
  const float* w_qx  = (const float*)d_in[4];
  const float* w_qh  = (const float*)d_in[5];
  const float* w_kx  = (const float*)d_in[6];
  const float* w_kh  = (const float*)d_in[7];
  const float* w_vx  = (const float*)d_in[8];
  const float* w_vh  = (const float*)d_in[9];
  const float* w_z   = (const float*)d_in[10];
  const float* b_z   = (const float*)d_in[11];
  const float* w_h   = (const float*)d_in[12];
  const float* b_h   = (const float*)d_in[13];
  const float* w_out = (const float*)d_in[14];
  const float* b_out = (const float*)d_in[15];
  float* out = (float*)d_out;

  char* base = (char*)d_ws;
  size_t off = 0;
  auto alloc = [&](size_t bytes) -> char* {
    off = (off + 255) & ~(size_t)255;
    char* p = base + off; off += bytes; return p;
  };
  ushort* xaTh  = (ushort*)alloc(19660800);          // [8][1600][768]
  ushort* xaTl  = (ushort*)alloc(19660800);
  ushort* qTh   = (ushort*)alloc(6553600);           // [8][1600][256]
  ushort* qTl   = (ushort*)alloc(6553600);
  ushort* kxTh  = (ushort*)alloc(5914624);           // [8][1444][256]
  ushort* kxTl  = (ushort*)alloc(5914624);
  ushort* vxph  = (ushort*)alloc(6029312);           // [8][256][1472]
  ushort* vxpl  = (ushort*)alloc(6029312);
  ushort* xTh   = (ushort*)alloc(3276800);           // [12800][128]
  ushort* xTl   = (ushort*)alloc(3276800);
  ushort* Wqkh  = (ushort*)alloc(2359296);           // [512][2304]
  ushort* Wqkl  = (ushort*)alloc(2359296);
  ushort* Wvh   = (ushort*)alloc(1179648);           // [256][2304]
  ushort* Wvl   = (ushort*)alloc(1179648);
  ushort* wpxh  = (ushort*)alloc(65536);             // [256][128]
  ushort* wpxl  = (ushort*)alloc(65536);
  ushort* wouth = (ushort*)alloc(393216);            // [256][768]
  ushort* woutl = (ushort*)alloc(393216);
  float*  qh1   = (float*)alloc(9216);
  float*  kh1   = (float*)alloc(1024);
  float*  vh1   = (float*)alloc(1024);
  float*  L0    = (float*)alloc(415872);             // [8][9][1444]
  float*  a10   = (float*)alloc(73728);
  float*  h1    = (float*)alloc(73728);
  float*  khc   = (float*)alloc(73728);
  float*  vhc   = (float*)alloc(73728);
  off = (off + 255) & ~(size_t)255;
  char* chunk = base + off;
  long avail = (long)ws_size - (long)off;
  if (avail < 0) avail = 0;
  int cn = (int)(avail / 14745600L); if (cn < 1) cn = 1; if (cn > 8) cn = 8;
  int an = (int)(avail / 18662400L); if (an < 1) an = 1; if (an > 8) an = 8;

  auto mg = [&](dim3 grid,
                const ushort* Ah, const ushort* Al, long sAb,
                const ushort* Bh, const ushort* Bl, long sBb,
                int M, int Nn, int K, int mode, int gRow0, int swap,
                float* Y, long sYb, long sYm, int nPer, long sYb2,
                const float* bias, int biasN,
                ushort* Yh, ushort* Yl, long sYpb, long sYpm, long pOff,
                ushort* Y2h, ushort* Y2l) {
    mgemm<<<grid, dim3(256), 0, stream>>>(Ah, Al, sAb, Bh, Bl, sBb,
        M, Nn, K, mode, gRow0, swap, Y, sYb, sYm, nPer, sYb2, bias, biasN,
        Yh, Yl, sYpb, sYpm, pOff, Y2h, Y2l);
  };
  const int BIG = 0x40000000;

  // ---- 1) weight/input conversions ----
  cvt_pair<<<dim3(6400), dim3(256), 0, stream>>>(x, 1, 1600, 204800, xTh, xTl, 128, 204800, 1600, 128, 0, 1638400);
  concat_wqk<<<dim3(4608), dim3(256), 0, stream>>>(w_qx, w_kx, Wqkh, Wqkl);
  cvt_pair<<<dim3(2304), dim3(256), 0, stream>>>(w_vx, 2304, 1, 0, Wvh, Wvl, 2304, 0, 256, 2304, 0, 589824);
  cvt_pair<<<dim3(128), dim3(256), 0, stream>>>(w_px, 128, 1, 0, wpxh, wpxl, 128, 0, 256, 128, 0, 32768);
  cvt_pair<<<dim3(768), dim3(256), 0, stream>>>(w_out, 768, 1, 0, wouth, woutl, 768, 0, 256, 768, 0, 196608);

  // ---- 2) xp-conv (transposed): A=xT[12800][128], B=wpx -> xaT cols 0..255 ----
  mg(dim3(2, 100, 1), xTh, xTl, 0, wpxh, wpxl, 0,
     12800, 256, 128, 1, 0, 1,
     nullptr, 0, 0, 0, 0, b_px, 1,
     xaTh, xaTl, 0, 768, 0, nullptr, nullptr);

  // ---- 3) qkv convs (batch-chunked) ----
  {
    ushort* ich = (ushort*)chunk;
    for (int nb0 = 0; nb0 < 8; nb0 += cn) {
      int c = (8 - nb0 < cn) ? (8 - nb0) : cn;
      ushort* icl = ich + (long)c * 3686400;
      long tot = (long)c * 3686400;
      im2colT<<<dim3((unsigned)((tot + 255) / 256)), dim3(256), 0, stream>>>(xaTh, xaTl, ich, icl, nb0, tot);
      int mt = (1600 * c + 127) / 128;
      // qk-conv: A=icol rows, B=Wqk; epilogue routes to qT / kxT
      mg(dim3(4, mt, 1), ich, icl, 0, Wqkh, Wqkl, 0,
         1600 * c, 512, 2304, 2, nb0 * 1600, 1,
         nullptr, 0, 0, 0, 0, nullptr, 0,
         qTh, qTl, 0, 0, 0, kxTh, kxTl);
      // v-conv: A=Wv, B=icol rows; epilogue crop-stores into vxp
      mg(dim3(2, mt, 1), Wvh, Wvl, 0, ich, icl, 0,
         256, 1600 * c, 2304, 3, nb0 * 1600, 0,
         nullptr, 0, 0, 0, 0, nullptr, 0,
         vxph, vxpl, 0, 0, 0, nullptr, nullptr);
    }
  }
  pad_vxp<<<dim3(224), dim3(256), 0, stream>>>(vxph, vxpl);

  // ---- 4) classed section ----
  uniform_kv_kern<<<dim3(256, 11), dim3(64), 0, stream>>>(h0, w_qh, w_kh, w_vh, qh1, kh1, vh1);
  l0_logits<<<dim3(6, 8), dim3(256), 0, stream>>>(qh1, kxTh, kxTl, L0);
  softmax_rows<<<dim3(72), dim3(256), 0, stream>>>(L0, 1444);
  a10_pv<<<dim3(9, 8), dim3(256), 0, stream>>>(L0, vxph, vxpl, a10);
  gates_k<<<dim3(8), dim3(256), 0, stream>>>(a10, vh1, w_z, b_z, w_h, b_h, h0, h1);
  khvh_k<<<dim3(9, 8), dim3(256), 0, stream>>>(h1, w_kh, w_vh, khc, vhc);
  attn_b1<<<dim3(7, 8), dim3(256), 0, stream>>>(qTh, qTl, khc, vhc, xaTh, xaTl);

  // ---- 5) step-2 (0,0) full attention ----
  {
    float* scL = (float*)chunk;
    for (int nb0 = 0; nb0 < 8; nb0 += an) {
      int c = (8 - nb0 < an) ? (8 - nb0) : an;
      ushort* wth = (ushort*)(chunk + (long)c * 9241600);
      ushort* wtl = wth + (long)c * 2355200;
      mg(dim3(13, 12, c), qTh + (long)nb0 * 409600, qTl + (long)nb0 * 409600, 409600,
         kxTh + (long)nb0 * 369664, kxTl + (long)nb0 * 369664, 369664,
         1600, 1444, 256, 0, 0, 0,
         scL, 2310400, 1444, BIG, 0, nullptr, 0,
         nullptr, nullptr, 0, 0, 0, nullptr, nullptr);
      softmax_pair<<<dim3(c * 1600), dim3(256), 0, stream>>>(scL, wth, wtl);
      mg(dim3(2, 13, c), wth, wtl, 2355200,
         vxph + (long)nb0 * 376832, vxpl + (long)nb0 * 376832, 376832,
         1600, 256, 1472, 1, 0, 1,
         nullptr, 0, 0, 0, 0, nullptr, 0,
         xaTh + (long)nb0 * 1228800, xaTl + (long)nb0 * 1228800, 1228800, 768, 256,
         nullptr, nullptr);
    }
  }

  // ---- 6) out-conv: A=wout[256][768], B=xaT rows -> fp32 NCHW ----
  mg(dim3(2, 100, 1), wouth, woutl, 0, xaTh, xaTl, 0,
     256, 12800, 768, 0, 0, 0,
     out, 0, 1600, 1600, 409600, b_out, 0,
     nullptr, nullptr, 0, 0, 0, nullptr, nullptr);
}

// Round 6
// 1321.616 us; speedup vs baseline: 1.0732x; 1.0732x over previous
//
#include <hip/hip_runtime.h>
#include <math.h>

// ---------------------------------------------------------------------------
// 2-step recurrent attention cell, N=8, I=128, C=Hc=A=P=O=256, H=W=40
// (Q=1600), VALID 3x3 -> 38x38 (D=1444). fp32 reference.
//
// Algebraic reductions (R0-R2): step1 h uniform -> 9-class tables; step2 (0,1)
// attention collapses to 9 key classes; dead branches removed.
// R3: heavy GEMMs on MFMA via split-bf16 (f32 = hi+lo, 3 products).
// R4: classed section fused into shape-specialized kernels.
// R5: mgemm with global_load_lds DMA staging + XOR swizzle (bank conflicts = 0).
// R6: direct shifted-tap conv -- 3x3 conv = 9 shifted 1x1s with tap-major
// weights; position operand reads xaT rows with per-tap shift (zero page at
// borders). im2col buffer (118 MB write + ~700 MB re-read) deleted. scL rows
// 128-B aligned (stride 1472).
// ---------------------------------------------------------------------------

typedef __attribute__((ext_vector_type(8))) short bf8;   // 8 bf16 (4 VGPRs)
typedef __attribute__((ext_vector_type(4))) float f4;

__device__ __forceinline__ ushort f2bf(float f) {
  unsigned u = __float_as_uint(f);
  u += 0x7fffu + ((u >> 16) & 1u);
  return (ushort)(u >> 16);
}
__device__ __forceinline__ float bf2f(ushort h) {
  return __uint_as_float(((unsigned)h) << 16);
}

// ---------------- MFMA split-bf16 GEMM ----------------
// C[m][n] = sum_k A[m][k]*B[n][k], k-contig, K % 64 == 0.
// 128x128 tile, 4 waves, KB=64, global_load_lds 16B staging, XOR swizzle.
// aConv/bConv: operand rows are image positions (row -> n8,y,x over 8x40x40);
// k = tap*256 + c (tap-major weights); chunk-uniform tap shift (dy,dx);
// border-invalid rows read the 64-ushort zero page zp. Row stride 768 (xaT).
// Epilogue modes: 0 fp32 / 1 pair / 2 qk-split(qT,kxT) / 3 v-crop(vxp).
__global__ __launch_bounds__(256) void mgemm(
    const ushort* __restrict__ Ah, const ushort* __restrict__ Al, long sAb,
    const ushort* __restrict__ Bh, const ushort* __restrict__ Bl, long sBb,
    int M, int Nn, int K, int mode, int gRow0, int swap, int aConv, int bConv,
    const ushort* __restrict__ zp,
    float* __restrict__ Y, long sYb, long sYm, int nPer, long sYb2,
    const float* __restrict__ bias, int biasN,
    ushort* __restrict__ Yh, ushort* __restrict__ Yl, long sYpb, long sYpm, long pOff,
    ushort* __restrict__ Y2h, ushort* __restrict__ Y2l)
{
  __shared__ ushort S[4][128][64];   // planes Ah,Al,Bh,Bl ; 64 KB
  const int bz = blockIdx.z;
  Ah += (long)bz * sAb; Al += (long)bz * sAb;
  Bh += (long)bz * sBb; Bl += (long)bz * sBb;
  const int mb = swap ? blockIdx.y : blockIdx.x;
  const int nb = swap ? blockIdx.x : blockIdx.y;
  const int m0 = mb * 128, n0 = nb * 128;
  const int t = threadIdx.x;
  const int lane = t & 63, wv = t >> 6;
  const int r = lane & 15, qd = lane >> 4;
  const int wm = (wv & 1) * 64, wn = (wv >> 1) * 64;
  const int lrow = lane >> 3, lch = lane & 7;
  f4 acc[4][4];
  #pragma unroll
  for (int i = 0; i < 4; ++i)
    #pragma unroll
    for (int j = 0; j < 4; ++j) acc[i][j] = (f4){0.f, 0.f, 0.f, 0.f};

  // per-thread row precompute (rows fixed across k-chunks)
  int cg8[4];
  int aB[4], aY[4], aX[4]; long aO[4];
  int bB[4], bY[4], bX[4]; long bO[4];
  #pragma unroll
  for (int i = 0; i < 4; ++i) {
    int row = wv * 32 + i * 8 + lrow;
    cg8[i] = (lch ^ (row & 7)) * 8;
    {
      int gr = m0 + row;
      if (aConv) {
        int n8 = gr / 1600, pos = gr - n8 * 1600;
        int py = pos / 40, px = pos - py * 40;
        aB[i] = n8 * 1600; aY[i] = py; aX[i] = px;
      } else { if (gr > M - 1) gr = M - 1; aO[i] = (long)gr * K; }
    }
    {
      int gr = n0 + row;
      if (bConv) {
        int n8 = gr / 1600, pos = gr - n8 * 1600;
        int py = pos / 40, px = pos - py * 40;
        bB[i] = n8 * 1600; bY[i] = py; bX[i] = px;
      } else { if (gr > Nn - 1) gr = Nn - 1; bO[i] = (long)gr * K; }
    }
  }

  ushort* lbase = (ushort*)S;
  for (int kc = 0; kc < K; kc += 64) {
    __syncthreads();
    int tap = kc >> 8;
    int tdy = tap / 3 - 1, tdx = tap - (tap / 3) * 3 - 1;
    int kin = kc & 255;
    #pragma unroll
    for (int i = 0; i < 4; ++i) {
      int seg = wv * 2048 + i * 512;
      {
        const ushort *ph, *pl; size_t go;
        if (aConv) {
          int yy = aY[i] + tdy, xx = aX[i] + tdx;
          bool v = ((unsigned)yy < 40u) && ((unsigned)xx < 40u);
          if (v) { go = (size_t)(aB[i] + yy * 40 + xx) * 768 + kin + cg8[i]; ph = Ah; pl = Al; }
          else   { go = 0; ph = zp; pl = zp; }
        } else { go = (size_t)(aO[i] + kc + cg8[i]); ph = Ah; pl = Al; }
        __builtin_amdgcn_global_load_lds(ph + go, lbase + seg, 16, 0, 0);
        __builtin_amdgcn_global_load_lds(pl + go, lbase + 8192 + seg, 16, 0, 0);
      }
      {
        const ushort *ph, *pl; size_t go;
        if (bConv) {
          int yy = bY[i] + tdy, xx = bX[i] + tdx;
          bool v = ((unsigned)yy < 40u) && ((unsigned)xx < 40u);
          if (v) { go = (size_t)(bB[i] + yy * 40 + xx) * 768 + kin + cg8[i]; ph = Bh; pl = Bl; }
          else   { go = 0; ph = zp; pl = zp; }
        } else { go = (size_t)(bO[i] + kc + cg8[i]); ph = Bh; pl = Bl; }
        __builtin_amdgcn_global_load_lds(ph + go, lbase + 16384 + seg, 16, 0, 0);
        __builtin_amdgcn_global_load_lds(pl + go, lbase + 24576 + seg, 16, 0, 0);
      }
    }
    __syncthreads();
    #pragma unroll
    for (int kk = 0; kk < 2; ++kk) {
      int off = (((kk << 2) + qd) ^ (r & 7)) << 3;
      bf8 ah[4], al[4], bh[4], bl[4];
      #pragma unroll
      for (int mt = 0; mt < 4; ++mt) {
        ah[mt] = *(const bf8*)&S[0][wm + mt * 16 + r][off];
        al[mt] = *(const bf8*)&S[1][wm + mt * 16 + r][off];
        bh[mt] = *(const bf8*)&S[2][wn + mt * 16 + r][off];
        bl[mt] = *(const bf8*)&S[3][wn + mt * 16 + r][off];
      }
      #pragma unroll
      for (int mt = 0; mt < 4; ++mt)
        #pragma unroll
        for (int nt = 0; nt < 4; ++nt) {
          acc[mt][nt] = __builtin_amdgcn_mfma_f32_16x16x32_bf16(ah[mt], bh[nt], acc[mt][nt], 0, 0, 0);
          acc[mt][nt] = __builtin_amdgcn_mfma_f32_16x16x32_bf16(ah[mt], bl[nt], acc[mt][nt], 0, 0, 0);
          acc[mt][nt] = __builtin_amdgcn_mfma_f32_16x16x32_bf16(al[mt], bh[nt], acc[mt][nt], 0, 0, 0);
        }
    }
  }
  #pragma unroll
  for (int mt = 0; mt < 4; ++mt)
    #pragma unroll
    for (int nt = 0; nt < 4; ++nt) {
      int nn = n0 + wn + nt * 16 + r;
      if (nn >= Nn) continue;
      #pragma unroll
      for (int e = 0; e < 4; ++e) {
        int mm = m0 + wm + mt * 16 + qd * 4 + e;
        if (mm >= M) continue;
        float v = acc[mt][nt][e];
        if (mode == 0) {
          if (bias) v += bias[mm];
          int b2 = nn / nPer, nq = nn - b2 * nPer;
          Y[(size_t)bz * sYb + (size_t)b2 * sYb2 + (size_t)mm * sYm + nq] = v;
        } else if (mode == 1) {
          if (bias) v += bias[biasN ? nn : mm];
          size_t o = (size_t)bz * sYpb + (size_t)mm * sYpm + nn + pOff;
          ushort h = f2bf(v);
          Yh[o] = h; Yl[o] = f2bf(v - bf2f(h));
        } else if (mode == 2) {
          int gm = gRow0 + mm;
          int n8 = gm / 1600, q = gm - n8 * 1600;
          ushort h = f2bf(v), l = f2bf(v - bf2f(h));
          if (nn < 256) {
            size_t o = (size_t)n8 * 409600 + (size_t)q * 256 + nn;
            Yh[o] = h; Yl[o] = l;
          } else {
            int qy = q / 40, qx = q - qy * 40;
            if (qy >= 1 && qy <= 38 && qx >= 1 && qx <= 38) {
              size_t o = (size_t)n8 * 369664 + (size_t)((qy - 1) * 38 + qx - 1) * 256 + (nn - 256);
              Y2h[o] = h; Y2l[o] = l;
            }
          }
        } else {   // mode 3
          int gn = gRow0 + nn;
          int n8 = gn / 1600, q = gn - n8 * 1600;
          int qy = q / 40, qx = q - qy * 40;
          if (qy >= 1 && qy <= 38 && qx >= 1 && qx <= 38) {
            size_t o = (size_t)n8 * 376832 + (size_t)mm * 1472 + (qy - 1) * 38 + qx - 1;
            ushort h = f2bf(v);
            Yh[o] = h; Yl[o] = f2bf(v - bf2f(h));
          }
        }
      }
    }
}

// generic fp32 -> bf16 hi/lo pair conversion (strided read, contig write)
__global__ __launch_bounds__(256) void cvt_pair(
    const float* __restrict__ src, long s0, long s1, long sb,
    ushort* __restrict__ dh, ushort* __restrict__ dl, long d0, long db,
    int n0, int n1, int pad1, long total)
{
  long i = (long)blockIdx.x * 256 + threadIdx.x;
  if (i >= total) return;
  int wdt = n1 + pad1;
  int i1 = (int)(i % wdt); long rr = i / wdt;
  int i0 = (int)(rr % n0); int b = (int)(rr / n0);
  float f = 0.f;
  if (i1 < n1) f = src[(long)b * sb + (long)i0 * s0 + (long)i1 * s1];
  ushort h = f2bf(f);
  dh[(long)b * db + (long)i0 * d0 + i1] = h;
  dl[(long)b * db + (long)i0 * d0 + i1] = f2bf(f - bf2f(h));
}

// tap-major weight reorder + pair convert: Wqk[512][tap*256+c], Wv[256][...];
// also zeroes the 64-ushort zero page.
__global__ __launch_bounds__(256) void reorder_w(
    const float* __restrict__ wq, const float* __restrict__ wk,
    const float* __restrict__ wv,
    ushort* __restrict__ qkh, ushort* __restrict__ qkl,
    ushort* __restrict__ vh2, ushort* __restrict__ vl2, ushort* __restrict__ zp)
{
  int i = blockIdx.x * 256 + threadIdx.x;
  if (blockIdx.x == 0 && threadIdx.x < 64) zp[threadIdx.x] = 0;
  if (i >= 768 * 2304) return;
  int o = i / 2304, k = i - o * 2304;
  int tap = k >> 8, c = k & 255;
  int si = c * 9 + tap;
  float f; ushort *dh, *dl; int oo;
  if (o < 256)      { f = wq[o * 2304 + si];        dh = qkh; dl = qkl; oo = o; }
  else if (o < 512) { f = wk[(o - 256) * 2304 + si]; dh = qkh; dl = qkl; oo = o; }
  else              { f = wv[(o - 512) * 2304 + si]; dh = vh2; dl = vl2; oo = o - 512; }
  ushort h = f2bf(f);
  dh[oo * 2304 + k] = h; dl[oo * 2304 + k] = f2bf(f - bf2f(h));
}

// zero the vxp pad columns 1444..1471
__global__ __launch_bounds__(256) void pad_vxp(
    ushort* __restrict__ vxph, ushort* __restrict__ vxpl)
{
  int i = blockIdx.x * 256 + threadIdx.x;
  if (i >= 8 * 256 * 28) return;
  int j = i % 28; int rr = i / 28;
  int c = rr % 256; int n = rr / 256;
  size_t o = (size_t)n * 376832 + (size_t)c * 1472 + 1444 + j;
  vxph[o] = 0; vxpl[o] = 0;
}

// step-1 uniform-h class tables
__global__ __launch_bounds__(64) void uniform_kv_kern(
    const float* __restrict__ h0, const float* __restrict__ w_qh,
    const float* __restrict__ w_kh, const float* __restrict__ w_vh,
    float* __restrict__ qh1, float* __restrict__ kh1, float* __restrict__ vh1)
{
  int a = blockIdx.x, j = blockIdx.y, t = threadIdx.x;
  const float* wsel = (j < 9) ? w_qh : (j == 9) ? w_kh : w_vh;
  bool dyok0 = true, dyok2 = true, dxok0 = true, dxok2 = true;
  if (j < 9) {
    int uy = j / 3, ux = j - uy * 3;
    dyok0 = (uy != 0); dyok2 = (uy != 2);
    dxok0 = (ux != 0); dxok2 = (ux != 2);
  }
  float acc = 0.f;
  for (int c = t; c < 256; c += 64) {
    const float* wp = wsel + a * 2304 + c * 9;
    float s = 0.f;
    #pragma unroll
    for (int dy = 0; dy < 3; ++dy) {
      if ((dy == 0 && !dyok0) || (dy == 2 && !dyok2)) continue;
      #pragma unroll
      for (int dx = 0; dx < 3; ++dx) {
        if ((dx == 0 && !dxok0) || (dx == 2 && !dxok2)) continue;
        s += wp[dy * 3 + dx];
      }
    }
    acc += s * h0[c];
  }
  #pragma unroll
  for (int o = 32; o; o >>= 1) acc += __shfl_down(acc, o);
  if (t == 0) {
    if (j < 9) qh1[j * 256 + a] = acc;
    else if (j == 9) kh1[a] = acc;
    else vh1[a] = acc;
  }
}

// L0[n][u][d] = sum_c qh1[u][c] * k_x[n][d][c]  (k from kxT pair)
__global__ __launch_bounds__(256) void l0_logits(
    const float* __restrict__ qh1, const ushort* __restrict__ kxTh,
    const ushort* __restrict__ kxTl, float* __restrict__ L0)
{
  __shared__ float qs[2304];
  int db = blockIdx.x, n = blockIdx.y;
  for (int i = threadIdx.x; i < 2304; i += 256) qs[i] = qh1[i];
  __syncthreads();
  int d = db * 256 + threadIdx.x;
  bool act = d < 1444;
  size_t ro = (size_t)n * 369664 + (act ? (size_t)d * 256 : 0);
  const ushort* vh = kxTh + ro;
  const ushort* vl = kxTl + ro;
  float acc[9] = {0.f,0.f,0.f,0.f,0.f,0.f,0.f,0.f,0.f};
  for (int c8 = 0; c8 < 256; c8 += 8) {
    uint4 H = *(const uint4*)(vh + c8);
    uint4 L = *(const uint4*)(vl + c8);
    unsigned hw[4] = {H.x, H.y, H.z, H.w};
    unsigned lw[4] = {L.x, L.y, L.z, L.w};
    #pragma unroll
    for (int j = 0; j < 4; ++j) {
      float f0 = bf2f((ushort)(hw[j] & 0xffff)) + bf2f((ushort)(lw[j] & 0xffff));
      float f1 = bf2f((ushort)(hw[j] >> 16)) + bf2f((ushort)(lw[j] >> 16));
      int c = c8 + j * 2;
      #pragma unroll
      for (int u = 0; u < 9; ++u) acc[u] += qs[u * 256 + c] * f0 + qs[u * 256 + c + 1] * f1;
    }
  }
  if (act)
    for (int u = 0; u < 9; ++u) L0[n * 12996 + u * 1444 + d] = acc[u];
}

// fp32 in-place row softmax
__global__ __launch_bounds__(256) void softmax_rows(float* __restrict__ p, int L)
{
  float* rp = p + (long)blockIdx.x * L;
  int t = threadIdx.x;
  __shared__ float redm[4], reds[4];
  float mx = -3.4e38f;
  for (int i = t; i < L; i += 256) mx = fmaxf(mx, rp[i]);
  #pragma unroll
  for (int o = 32; o; o >>= 1) mx = fmaxf(mx, __shfl_down(mx, o));
  if ((t & 63) == 0) redm[t >> 6] = mx;
  __syncthreads();
  mx = fmaxf(fmaxf(redm[0], redm[1]), fmaxf(redm[2], redm[3]));
  float s = 0.f;
  for (int i = t; i < L; i += 256) { float v = expf(rp[i] - mx); rp[i] = v; s += v; }
  #pragma unroll
  for (int o = 32; o; o >>= 1) s += __shfl_down(s, o);
  if ((t & 63) == 0) reds[t >> 6] = s;
  __syncthreads();
  float inv = 1.f / (reds[0] + reds[1] + reds[2] + reds[3]);
  for (int i = t; i < L; i += 256) rp[i] *= inv;
}

// a10[n][u][p] = sum_d wt[n][u][d] * v[n][p][d]  (v from vxp pair)
__global__ __launch_bounds__(256) void a10_pv(
    const float* __restrict__ L0, const ushort* __restrict__ vxph,
    const ushort* __restrict__ vxpl, float* __restrict__ a10)
{
  int u = blockIdx.x, n = blockIdx.y;
  __shared__ float wts[1472];
  const float* wrow = L0 + n * 12996 + u * 1444;
  for (int i = threadIdx.x; i < 1472; i += 256) wts[i] = (i < 1444) ? wrow[i] : 0.f;
  __syncthreads();
  int p = threadIdx.x;
  const ushort* vh = vxph + (size_t)n * 376832 + (size_t)p * 1472;
  const ushort* vl = vxpl + (size_t)n * 376832 + (size_t)p * 1472;
  float acc = 0.f;
  for (int d8 = 0; d8 < 1472; d8 += 8) {
    uint4 hv = *(const uint4*)(vh + d8);
    uint4 lv = *(const uint4*)(vl + d8);
    unsigned hw[4] = {hv.x, hv.y, hv.z, hv.w};
    unsigned lw[4] = {lv.x, lv.y, lv.z, lv.w};
    #pragma unroll
    for (int j = 0; j < 4; ++j) {
      float f0 = bf2f((ushort)(hw[j] & 0xffff)) + bf2f((ushort)(lw[j] & 0xffff));
      float f1 = bf2f((ushort)(hw[j] >> 16)) + bf2f((ushort)(lw[j] >> 16));
      acc += wts[d8 + j * 2] * f0 + wts[d8 + j * 2 + 1] * f1;
    }
  }
  a10[n * 2304 + u * 256 + p] = acc;
}

// gates fused: z/h preact + GRU blend, 9 classes
__global__ __launch_bounds__(256) void gates_k(
    const float* __restrict__ a10, const float* __restrict__ vh1,
    const float* __restrict__ w_z, const float* __restrict__ b_z,
    const float* __restrict__ w_h, const float* __restrict__ b_h,
    const float* __restrict__ h0, float* __restrict__ h1)
{
  int n = blockIdx.x;
  __shared__ float as[2304], vs[256];
  for (int i = threadIdx.x; i < 2304; i += 256) as[i] = a10[n * 2304 + i];
  if (threadIdx.x < 256) vs[threadIdx.x] = vh1[threadIdx.x];
  __syncthreads();
  int hc = threadIdx.x;
  const float* wz = w_z + hc * 512;
  const float* wh = w_h + hc * 512;
  float az[9], ah[9];
  float bz = b_z[hc], bh = b_h[hc];
  #pragma unroll
  for (int u = 0; u < 9; ++u) { az[u] = bz; ah[u] = bh; }
  for (int k = 0; k < 256; ++k) {
    float wzv = wz[k], whv = wh[k];
    #pragma unroll
    for (int u = 0; u < 9; ++u) {
      float vv = as[u * 256 + k];
      az[u] += wzv * vv; ah[u] += whv * vv;
    }
  }
  float sz = 0.f, sh = 0.f;
  for (int k = 0; k < 256; ++k) { float vv = vs[k]; sz += wz[256 + k] * vv; sh += wh[256 + k] * vv; }
  float h0v = h0[hc];
  #pragma unroll
  for (int u = 0; u < 9; ++u) {
    float z = 1.f / (1.f + expf(-(az[u] + sz)));
    float hv = tanhf(ah[u] + sh);
    h1[n * 2304 + hc * 9 + u] = z * h0v + (1.f - z) * hv;
  }
}

// khc/vhc: classed VALID conv over piecewise-constant h1
__global__ __launch_bounds__(256) void khvh_k(
    const float* __restrict__ h1, const float* __restrict__ w_kh,
    const float* __restrict__ w_vh, float* __restrict__ khc, float* __restrict__ vhc)
{
  int u = blockIdx.x, n = blockIdx.y;
  int ty = u / 3, tx = u - ty * 3;
  __shared__ float Gs[2304];
  for (int k = threadIdx.x; k < 2304; k += 256) {
    int c = k / 9, tap = k - c * 9, dy = tap / 3, dx = tap - dy * 3;
    int uy = (ty == 0) ? (dy == 0 ? 0 : 1) : (ty == 2) ? (dy == 2 ? 2 : 1) : 1;
    int ux = (tx == 0) ? (dx == 0 ? 0 : 1) : (tx == 2) ? (dx == 2 ? 2 : 1) : 1;
    Gs[k] = h1[n * 2304 + c * 9 + uy * 3 + ux];
  }
  __syncthreads();
  int hc = threadIdx.x;
  const float* wk = w_kh + hc * 2304;
  const float* wv = w_vh + hc * 2304;
  float ak = 0.f, av = 0.f;
  for (int k = 0; k < 2304; ++k) { float g = Gs[k]; ak += wk[k] * g; av += wv[k] * g; }
  khc[n * 2304 + hc * 9 + u] = ak;
  vhc[n * 2304 + hc * 9 + u] = av;
}

// softmax over 1444 logits (rows stride 1472) -> bf16 pair rows (1472)
__global__ __launch_bounds__(256) void softmax_pair(
    const float* __restrict__ p, ushort* __restrict__ wh, ushort* __restrict__ wl)
{
  long row = blockIdx.x;
  const float* rp = p + row * 1472;
  ushort* oh = wh + row * 1472;
  ushort* ol = wl + row * 1472;
  int t = threadIdx.x;
  __shared__ float buf[1444];
  __shared__ float redm[4], reds[4];
  float mx = -3.4e38f;
  for (int i = t; i < 1444; i += 256) { float v = rp[i]; buf[i] = v; mx = fmaxf(mx, v); }
  #pragma unroll
  for (int o = 32; o; o >>= 1) mx = fmaxf(mx, __shfl_down(mx, o));
  if ((t & 63) == 0) redm[t >> 6] = mx;
  __syncthreads();
  mx = fmaxf(fmaxf(redm[0], redm[1]), fmaxf(redm[2], redm[3]));
  float s = 0.f;
  for (int i = t; i < 1444; i += 256) { float v = expf(buf[i] - mx); buf[i] = v; s += v; }
  #pragma unroll
  for (int o = 32; o; o >>= 1) s += __shfl_down(s, o);
  if ((t & 63) == 0) reds[t >> 6] = s;
  __syncthreads();
  float inv = 1.f / (reds[0] + reds[1] + reds[2] + reds[3]);
  for (int i = t; i < 1472; i += 256) {
    float v = (i < 1444) ? buf[i] * inv : 0.f;
    ushort h = f2bf(v);
    oh[i] = h; ol[i] = f2bf(v - bf2f(h));
  }
}

// step-2 (a=0,b=1) classed attention; coalesced pair output
__global__ __launch_bounds__(256) void attn_b1(
    const ushort* __restrict__ qTh, const ushort* __restrict__ qTl,
    const float* __restrict__ khc, const float* __restrict__ vhc,
    ushort* __restrict__ xaTh, ushort* __restrict__ xaTl)
{
  __shared__ float ks[2304];
  __shared__ float vs[2304];
  __shared__ float es[256][10];
  int n = blockIdx.y;
  int q0 = blockIdx.x * 256;
  for (int i = threadIdx.x; i < 2304; i += 256) { ks[i] = khc[n * 2304 + i]; vs[i] = vhc[n * 2304 + i]; }
  __syncthreads();
  int q = q0 + threadIdx.x;
  bool act = (q < 1600);
  float Lg[9] = {0.f,0.f,0.f,0.f,0.f,0.f,0.f,0.f,0.f};
  size_t ro = (size_t)n * 409600 + (act ? (size_t)q * 256 : 0);
  const ushort* qh = qTh + ro;
  const ushort* ql = qTl + ro;
  for (int c8 = 0; c8 < 256; c8 += 8) {
    uint4 H = *(const uint4*)(qh + c8);
    uint4 L = *(const uint4*)(ql + c8);
    unsigned hw[4] = {H.x, H.y, H.z, H.w};
    unsigned lw[4] = {L.x, L.y, L.z, L.w};
    #pragma unroll
    for (int j = 0; j < 4; ++j) {
      float f0 = bf2f((ushort)(hw[j] & 0xffff)) + bf2f((ushort)(lw[j] & 0xffff));
      float f1 = bf2f((ushort)(hw[j] >> 16)) + bf2f((ushort)(lw[j] >> 16));
      int c = c8 + j * 2;
      #pragma unroll
      for (int tt = 0; tt < 9; ++tt)
        Lg[tt] += f0 * ks[c * 9 + tt] + f1 * ks[(c + 1) * 9 + tt];
    }
  }
  float mx = Lg[0];
  #pragma unroll
  for (int tt = 1; tt < 9; ++tt) mx = fmaxf(mx, Lg[tt]);
  float Z = 0.f;
  float e[9];
  #pragma unroll
  for (int tt = 0; tt < 9; ++tt) {
    float m = ((tt / 3) == 1 ? 36.f : 1.f) * ((tt % 3) == 1 ? 36.f : 1.f);
    e[tt] = act ? m * expf(Lg[tt] - mx) : 0.f;
    Z += e[tt];
  }
  float inv = act ? (1.f / Z) : 0.f;
  #pragma unroll
  for (int tt = 0; tt < 9; ++tt) es[threadIdx.x][tt] = e[tt] * inv;
  __syncthreads();
  int nact = 1600 - q0; if (nact > 256) nact = 256;
  int p = threadIdx.x;
  for (int qq = 0; qq < nact; ++qq) {
    float s = 0.f;
    #pragma unroll
    for (int tt = 0; tt < 9; ++tt) s += es[qq][tt] * vs[p * 9 + tt];
    ushort h = f2bf(s);
    size_t o = (size_t)n * 1228800 + (size_t)(q0 + qq) * 768 + 512 + p;
    xaTh[o] = h; xaTl[o] = f2bf(s - bf2f(h));
  }
}

// ---------------------------------------------------------------------------
extern "C" void kernel_launch(void* const* d_in, const int* in_sizes, int n_in,
                              void* d_out, int out_size, void* d_ws, size_t ws_size,
                              hipStream_t stream)
{
  const float* x     = (const float*)d_in[0];
  const float* h0    = (const float*)d_in[1];
  const float* w_px  = (const float*)d_in[2];
  const float* b_px  = (const float*)d_in[3];
  const float* w_qx  = (const float*)d_in[4];
  const float* w_qh  = (const float*)d_in[5];
  const float* w_kx  = (const float*)d_in[6];
  const float* w_kh  = (const float*)d_in[7];
  const float* w_vx  = (const float*)d_in[8];
  const float* w_vh  = (const float*)d_in[9];
  const float* w_z   = (const float*)d_in[10];
  const float* b_z   = (const float*)d_in[11];
  const float* w_h   = (const float*)d_in[12];
  const float* b_h   = (const float*)d_in[13];
  const float* w_out = (const float*)d_in[14];
  const float* b_out = (const float*)d_in[15];
  float* out = (float*)d_out;

  char* base = (char*)d_ws;
  size_t off = 0;
  auto alloc = [&](size_t bytes) -> char* {
    off = (off + 255) & ~(size_t)255;
    char* p = base + off; off += bytes; return p;
  };
  ushort* xaTh  = (ushort*)alloc(19660800);          // [8][1600][768]
  ushort* xaTl  = (ushort*)alloc(19660800);
  ushort* qTh   = (ushort*)alloc(6553600);           // [8][1600][256]
  ushort* qTl   = (ushort*)alloc(6553600);
  ushort* kxTh  = (ushort*)alloc(5914624);           // [8][1444][256]
  ushort* kxTl  = (ushort*)alloc(5914624);
  ushort* vxph  = (ushort*)alloc(6029312);           // [8][256][1472]
  ushort* vxpl  = (ushort*)alloc(6029312);
  ushort* xTh   = (ushort*)alloc(3276800);           // [12800][128]
  ushort* xTl   = (ushort*)alloc(3276800);
  ushort* Wqkh  = (ushort*)alloc(2359296);           // [512][2304] tap-major
  ushort* Wqkl  = (ushort*)alloc(2359296);
  ushort* Wvh   = (ushort*)alloc(1179648);           // [256][2304] tap-major
  ushort* Wvl   = (ushort*)alloc(1179648);
  ushort* wpxh  = (ushort*)alloc(65536);             // [256][128]
  ushort* wpxl  = (ushort*)alloc(65536);
  ushort* wouth = (ushort*)alloc(393216);            // [256][768]
  ushort* woutl = (ushort*)alloc(393216);
  ushort* zp    = (ushort*)alloc(128);               // 64-ushort zero page
  float*  qh1   = (float*)alloc(9216);
  float*  kh1   = (float*)alloc(1024);
  float*  vh1   = (float*)alloc(1024);
  float*  L0    = (float*)alloc(415872);             // [8][9][1444]
  float*  a10   = (float*)alloc(73728);
  float*  h1    = (float*)alloc(73728);
  float*  khc   = (float*)alloc(73728);
  float*  vhc   = (float*)alloc(73728);
  off = (off + 255) & ~(size_t)255;
  char* chunk = base + off;
  long avail = (long)ws_size - (long)off;
  if (avail < 0) avail = 0;
  int an = (int)(avail / 18841600L); if (an < 1) an = 1; if (an > 8) an = 8;

  auto mg = [&](dim3 grid,
                const ushort* Ah, const ushort* Al, long sAb,
                const ushort* Bh, const ushort* Bl, long sBb,
                int M, int Nn, int K, int mode, int gRow0, int swap,
                int aConv, int bConv,
                float* Y, long sYb, long sYm, int nPer, long sYb2,
                const float* bias, int biasN,
                ushort* Yh, ushort* Yl, long sYpb, long sYpm, long pOff,
                ushort* Y2h, ushort* Y2l) {
    mgemm<<<grid, dim3(256), 0, stream>>>(Ah, Al, sAb, Bh, Bl, sBb,
        M, Nn, K, mode, gRow0, swap, aConv, bConv, zp,
        Y, sYb, sYm, nPer, sYb2, bias, biasN,
        Yh, Yl, sYpb, sYpm, pOff, Y2h, Y2l);
  };
  const int BIG = 0x40000000;

  // ---- 1) weight/input conversions ----
  cvt_pair<<<dim3(6400), dim3(256), 0, stream>>>(x, 1, 1600, 204800, xTh, xTl, 128, 204800, 1600, 128, 0, 1638400);
  reorder_w<<<dim3(6912), dim3(256), 0, stream>>>(w_qx, w_kx, w_vx, Wqkh, Wqkl, Wvh, Wvl, zp);
  cvt_pair<<<dim3(128), dim3(256), 0, stream>>>(w_px, 128, 1, 0, wpxh, wpxl, 128, 0, 256, 128, 0, 32768);
  cvt_pair<<<dim3(768), dim3(256), 0, stream>>>(w_out, 768, 1, 0, wouth, woutl, 768, 0, 256, 768, 0, 196608);

  // ---- 2) xp-conv: A=xT[12800][128], B=wpx -> xaT cols 0..255 ----
  mg(dim3(2, 100, 1), xTh, xTl, 0, wpxh, wpxl, 0,
     12800, 256, 128, 1, 0, 1, 0, 0,
     nullptr, 0, 0, 0, 0, b_px, 1,
     xaTh, xaTl, 0, 768, 0, nullptr, nullptr);

  // ---- 3) direct shifted-tap convs (no im2col) ----
  // qk-conv: A = xaT positions (conv), B = Wqk tap-major; epilogue -> qT/kxT
  mg(dim3(4, 100, 1), xaTh, xaTl, 0, Wqkh, Wqkl, 0,
     12800, 512, 2304, 2, 0, 1, 1, 0,
     nullptr, 0, 0, 0, 0, nullptr, 0,
     qTh, qTl, 0, 0, 0, kxTh, kxTl);
  // v-conv: A = Wv tap-major, B = xaT positions (conv); epilogue -> vxp
  mg(dim3(2, 100, 1), Wvh, Wvl, 0, xaTh, xaTl, 0,
     256, 12800, 2304, 3, 0, 0, 0, 1,
     nullptr, 0, 0, 0, 0, nullptr, 0,
     vxph, vxpl, 0, 0, 0, nullptr, nullptr);
  pad_vxp<<<dim3(224), dim3(256), 0, stream>>>(vxph, vxpl);

  // ---- 4) classed section ----
  uniform_kv_kern<<<dim3(256, 11), dim3(64), 0, stream>>>(h0, w_qh, w_kh, w_vh, qh1, kh1, vh1);
  l0_logits<<<dim3(6, 8), dim3(256), 0, stream>>>(qh1, kxTh, kxTl, L0);
  softmax_rows<<<dim3(72), dim3(256), 0, stream>>>(L0, 1444);
  a10_pv<<<dim3(9, 8), dim3(256), 0, stream>>>(L0, vxph, vxpl, a10);
  gates_k<<<dim3(8), dim3(256), 0, stream>>>(a10, vh1, w_z, b_z, w_h, b_h, h0, h1);
  khvh_k<<<dim3(9, 8), dim3(256), 0, stream>>>(h1, w_kh, w_vh, khc, vhc);
  attn_b1<<<dim3(7, 8), dim3(256), 0, stream>>>(qTh, qTl, khc, vhc, xaTh, xaTl);

  // ---- 5) step-2 (0,0) full attention ----
  {
    float* scL = (float*)chunk;
    for (int nb0 = 0; nb0 < 8; nb0 += an) {
      int c = (8 - nb0 < an) ? (8 - nb0) : an;
      ushort* wth = (ushort*)(chunk + (long)c * 9420800);
      ushort* wtl = wth + (long)c * 2355200;
      mg(dim3(13, 12, c), qTh + (long)nb0 * 409600, qTl + (long)nb0 * 409600, 409600,
         kxTh + (long)nb0 * 369664, kxTl + (long)nb0 * 369664, 369664,
         1600, 1444, 256, 0, 0, 0, 0, 0,
         scL, 2355200, 1472, BIG, 0, nullptr, 0,
         nullptr, nullptr, 0, 0, 0, nullptr, nullptr);
      softmax_pair<<<dim3(c * 1600), dim3(256), 0, stream>>>(scL, wth, wtl);
      mg(dim3(2, 13, c), wth, wtl, 2355200,
         vxph + (long)nb0 * 376832, vxpl + (long)nb0 * 376832, 376832,
         1600, 256, 1472, 1, 0, 1, 0, 0,
         nullptr, 0, 0, 0, 0, nullptr, 0,
         xaTh + (long)nb0 * 1228800, xaTl + (long)nb0 * 1228800, 1228800, 768, 256,
         nullptr, nullptr);
    }
  }

  // ---- 6) out-conv: A=wout[256][768], B=xaT rows -> fp32 NCHW ----
  mg(dim3(2, 100, 1), wouth, woutl, 0, xaTh, xaTl, 0,
     256, 12800, 768, 0, 0, 0, 0, 0,
     out, 0, 1600, 1600, 409600, b_out, 0,
     nullptr, nullptr, 0, 0, 0, nullptr, nullptr);
}

// Round 7
// 1167.608 us; speedup vs baseline: 1.2147x; 1.1319x over previous
//
#include <hip/hip_runtime.h>
#include <math.h>

// ---------------------------------------------------------------------------
// 2-step recurrent attention cell, N=8, I=128, C=Hc=A=P=O=256, H=W=40
// (Q=1600), VALID 3x3 -> 38x38 (D=1444). fp32 reference.
//
// R0-R2: exact algebraic reductions (step1 uniform h -> 9-class tables; step2
// (0,1) attention collapses; dead branches removed).
// R3: split-bf16 MFMA (f32 = hi+lo, 3 products).  R4: fused classed kernels.
// R5: DMA staging + XOR swizzle (0 bank conflicts).  R6: direct shifted-tap
// conv (no im2col).
// R7: conv K reordered channel-block-major/tap-minor (shifted A-tiles stay
// L2-hot across the 9 taps of each 64-channel slice); mgemm64 (64x64 tile)
// for occupancy-starved GEMMs (xp/PV/out: 200 -> 800 blocks).
// ---------------------------------------------------------------------------

typedef __attribute__((ext_vector_type(8))) short bf8;   // 8 bf16 (4 VGPRs)
typedef __attribute__((ext_vector_type(4))) float f4;

__device__ __forceinline__ ushort f2bf(float f) {
  unsigned u = __float_as_uint(f);
  u += 0x7fffu + ((u >> 16) & 1u);
  return (ushort)(u >> 16);
}
__device__ __forceinline__ float bf2f(ushort h) {
  return __uint_as_float(((unsigned)h) << 16);
}

// ---------------- MFMA split-bf16 GEMM, 128x128 tile ----------------
// C[m][n] = sum_k A[m][k]*B[n][k], k-contig, K % 64 == 0.
// KB=64 chunks, global_load_lds 16B staging, XOR swizzle (conflict-free).
// aConv/bConv: operand rows are image positions (8x40x40), row stride 768
// (xaT); conv K layout: k = cb*576 + tap*64 + ci (chunk-uniform tap; 9
// consecutive chunks share one 64-channel slice at shifted positions).
// Epilogue modes: 0 fp32 / 1 pair / 2 qk-split(qT,kxT) / 3 v-crop(vxp).
__global__ __launch_bounds__(256) void mgemm(
    const ushort* __restrict__ Ah, const ushort* __restrict__ Al, long sAb,
    const ushort* __restrict__ Bh, const ushort* __restrict__ Bl, long sBb,
    int M, int Nn, int K, int mode, int gRow0, int swap, int aConv, int bConv,
    const ushort* __restrict__ zp,
    float* __restrict__ Y, long sYb, long sYm, int nPer, long sYb2,
    const float* __restrict__ bias, int biasN,
    ushort* __restrict__ Yh, ushort* __restrict__ Yl, long sYpb, long sYpm, long pOff,
    ushort* __restrict__ Y2h, ushort* __restrict__ Y2l)
{
  __shared__ ushort S[4][128][64];   // planes Ah,Al,Bh,Bl ; 64 KB
  const int bz = blockIdx.z;
  Ah += (long)bz * sAb; Al += (long)bz * sAb;
  Bh += (long)bz * sBb; Bl += (long)bz * sBb;
  const int mb = swap ? blockIdx.y : blockIdx.x;
  const int nb = swap ? blockIdx.x : blockIdx.y;
  const int m0 = mb * 128, n0 = nb * 128;
  const int t = threadIdx.x;
  const int lane = t & 63, wv = t >> 6;
  const int r = lane & 15, qd = lane >> 4;
  const int wm = (wv & 1) * 64, wn = (wv >> 1) * 64;
  const int lrow = lane >> 3, lch = lane & 7;
  f4 acc[4][4];
  #pragma unroll
  for (int i = 0; i < 4; ++i)
    #pragma unroll
    for (int j = 0; j < 4; ++j) acc[i][j] = (f4){0.f, 0.f, 0.f, 0.f};

  int cg8[4];
  int aB[4], aY[4], aX[4]; long aO[4];
  int bB[4], bY[4], bX[4]; long bO[4];
  #pragma unroll
  for (int i = 0; i < 4; ++i) {
    int row = wv * 32 + i * 8 + lrow;
    cg8[i] = (lch ^ (row & 7)) * 8;
    {
      int gr = m0 + row;
      if (aConv) {
        int n8 = gr / 1600, pos = gr - n8 * 1600;
        int py = pos / 40, px = pos - py * 40;
        aB[i] = n8 * 1600; aY[i] = py; aX[i] = px;
      } else { if (gr > M - 1) gr = M - 1; aO[i] = (long)gr * K; }
    }
    {
      int gr = n0 + row;
      if (bConv) {
        int n8 = gr / 1600, pos = gr - n8 * 1600;
        int py = pos / 40, px = pos - py * 40;
        bB[i] = n8 * 1600; bY[i] = py; bX[i] = px;
      } else { if (gr > Nn - 1) gr = Nn - 1; bO[i] = (long)gr * K; }
    }
  }

  ushort* lbase = (ushort*)S;
  for (int kc = 0; kc < K; kc += 64) {
    __syncthreads();
    int ch = kc >> 6;
    int cb = ch / 9, tap = ch - cb * 9;       // channel-block-major, tap-minor
    int tdy = tap / 3 - 1, tdx = tap - (tap / 3) * 3 - 1;
    int kin = cb << 6;
    #pragma unroll
    for (int i = 0; i < 4; ++i) {
      int seg = wv * 2048 + i * 512;
      {
        const ushort *ph, *pl; size_t go;
        if (aConv) {
          int yy = aY[i] + tdy, xx = aX[i] + tdx;
          bool v = ((unsigned)yy < 40u) && ((unsigned)xx < 40u);
          if (v) { go = (size_t)(aB[i] + yy * 40 + xx) * 768 + kin + cg8[i]; ph = Ah; pl = Al; }
          else   { go = 0; ph = zp; pl = zp; }
        } else { go = (size_t)(aO[i] + kc + cg8[i]); ph = Ah; pl = Al; }
        __builtin_amdgcn_global_load_lds(ph + go, lbase + seg, 16, 0, 0);
        __builtin_amdgcn_global_load_lds(pl + go, lbase + 8192 + seg, 16, 0, 0);
      }
      {
        const ushort *ph, *pl; size_t go;
        if (bConv) {
          int yy = bY[i] + tdy, xx = bX[i] + tdx;
          bool v = ((unsigned)yy < 40u) && ((unsigned)xx < 40u);
          if (v) { go = (size_t)(bB[i] + yy * 40 + xx) * 768 + kin + cg8[i]; ph = Bh; pl = Bl; }
          else   { go = 0; ph = zp; pl = zp; }
        } else { go = (size_t)(bO[i] + kc + cg8[i]); ph = Bh; pl = Bl; }
        __builtin_amdgcn_global_load_lds(ph + go, lbase + 16384 + seg, 16, 0, 0);
        __builtin_amdgcn_global_load_lds(pl + go, lbase + 24576 + seg, 16, 0, 0);
      }
    }
    __syncthreads();
    #pragma unroll
    for (int kk = 0; kk < 2; ++kk) {
      int off = (((kk << 2) + qd) ^ (r & 7)) << 3;
      bf8 ah[4], al[4], bh[4], bl[4];
      #pragma unroll
      for (int mt = 0; mt < 4; ++mt) {
        ah[mt] = *(const bf8*)&S[0][wm + mt * 16 + r][off];
        al[mt] = *(const bf8*)&S[1][wm + mt * 16 + r][off];
        bh[mt] = *(const bf8*)&S[2][wn + mt * 16 + r][off];
        bl[mt] = *(const bf8*)&S[3][wn + mt * 16 + r][off];
      }
      #pragma unroll
      for (int mt = 0; mt < 4; ++mt)
        #pragma unroll
        for (int nt = 0; nt < 4; ++nt) {
          acc[mt][nt] = __builtin_amdgcn_mfma_f32_16x16x32_bf16(ah[mt], bh[nt], acc[mt][nt], 0, 0, 0);
          acc[mt][nt] = __builtin_amdgcn_mfma_f32_16x16x32_bf16(ah[mt], bl[nt], acc[mt][nt], 0, 0, 0);
          acc[mt][nt] = __builtin_amdgcn_mfma_f32_16x16x32_bf16(al[mt], bh[nt], acc[mt][nt], 0, 0, 0);
        }
    }
  }
  #pragma unroll
  for (int mt = 0; mt < 4; ++mt)
    #pragma unroll
    for (int nt = 0; nt < 4; ++nt) {
      int nn = n0 + wn + nt * 16 + r;
      if (nn >= Nn) continue;
      #pragma unroll
      for (int e = 0; e < 4; ++e) {
        int mm = m0 + wm + mt * 16 + qd * 4 + e;
        if (mm >= M) continue;
        float v = acc[mt][nt][e];
        if (mode == 0) {
          if (bias) v += bias[mm];
          int b2 = nn / nPer, nq = nn - b2 * nPer;
          Y[(size_t)bz * sYb + (size_t)b2 * sYb2 + (size_t)mm * sYm + nq] = v;
        } else if (mode == 1) {
          if (bias) v += bias[biasN ? nn : mm];
          size_t o = (size_t)bz * sYpb + (size_t)mm * sYpm + nn + pOff;
          ushort h = f2bf(v);
          Yh[o] = h; Yl[o] = f2bf(v - bf2f(h));
        } else if (mode == 2) {
          int gm = gRow0 + mm;
          int n8 = gm / 1600, q = gm - n8 * 1600;
          ushort h = f2bf(v), l = f2bf(v - bf2f(h));
          if (nn < 256) {
            size_t o = (size_t)n8 * 409600 + (size_t)q * 256 + nn;
            Yh[o] = h; Yl[o] = l;
          } else {
            int qy = q / 40, qx = q - qy * 40;
            if (qy >= 1 && qy <= 38 && qx >= 1 && qx <= 38) {
              size_t o = (size_t)n8 * 369664 + (size_t)((qy - 1) * 38 + qx - 1) * 256 + (nn - 256);
              Y2h[o] = h; Y2l[o] = l;
            }
          }
        } else {   // mode 3
          int gn = gRow0 + nn;
          int n8 = gn / 1600, q = gn - n8 * 1600;
          int qy = q / 40, qx = q - qy * 40;
          if (qy >= 1 && qy <= 38 && qx >= 1 && qx <= 38) {
            size_t o = (size_t)n8 * 376832 + (size_t)mm * 1472 + (qy - 1) * 38 + qx - 1;
            ushort h = f2bf(v);
            Yh[o] = h; Yl[o] = f2bf(v - bf2f(h));
          }
        }
      }
    }
}

// ---------------- MFMA split-bf16 GEMM, 64x64 tile (high occupancy) --------
// Non-conv operands only. Modes 0 (fp32) and 1 (pair).
__global__ __launch_bounds__(256) void mgemm64(
    const ushort* __restrict__ Ah, const ushort* __restrict__ Al, long sAb,
    const ushort* __restrict__ Bh, const ushort* __restrict__ Bl, long sBb,
    int M, int Nn, int K, int mode, int swap,
    float* __restrict__ Y, long sYb, long sYm, int nPer, long sYb2,
    const float* __restrict__ bias, int biasN,
    ushort* __restrict__ Yh, ushort* __restrict__ Yl, long sYpb, long sYpm, long pOff)
{
  __shared__ ushort S[4][64][64];   // 32 KB
  const int bz = blockIdx.z;
  Ah += (long)bz * sAb; Al += (long)bz * sAb;
  Bh += (long)bz * sBb; Bl += (long)bz * sBb;
  const int mb = swap ? blockIdx.y : blockIdx.x;
  const int nb = swap ? blockIdx.x : blockIdx.y;
  const int m0 = mb * 64, n0 = nb * 64;
  const int t = threadIdx.x;
  const int lane = t & 63, wv = t >> 6;
  const int r = lane & 15, qd = lane >> 4;
  f4 acc[4];
  #pragma unroll
  for (int j = 0; j < 4; ++j) acc[j] = (f4){0.f, 0.f, 0.f, 0.f};

  int cg8[2]; long aO[2], bO[2];
  #pragma unroll
  for (int i = 0; i < 2; ++i) {
    int row = i * 32 + wv * 8 + (lane >> 3);
    cg8[i] = ((lane & 7) ^ (row & 7)) * 8;
    int gra = m0 + row; if (gra > M - 1) gra = M - 1;
    int grb = n0 + row; if (grb > Nn - 1) grb = Nn - 1;
    aO[i] = (long)gra * K;
    bO[i] = (long)grb * K;
  }

  ushort* lbase = (ushort*)S;
  for (int kc = 0; kc < K; kc += 64) {
    __syncthreads();
    #pragma unroll
    for (int i = 0; i < 2; ++i) {
      int seg = i * 2048 + wv * 512;
      __builtin_amdgcn_global_load_lds(Ah + aO[i] + kc + cg8[i], lbase + seg, 16, 0, 0);
      __builtin_amdgcn_global_load_lds(Al + aO[i] + kc + cg8[i], lbase + 4096 + seg, 16, 0, 0);
      __builtin_amdgcn_global_load_lds(Bh + bO[i] + kc + cg8[i], lbase + 8192 + seg, 16, 0, 0);
      __builtin_amdgcn_global_load_lds(Bl + bO[i] + kc + cg8[i], lbase + 12288 + seg, 16, 0, 0);
    }
    __syncthreads();
    #pragma unroll
    for (int kk = 0; kk < 2; ++kk) {
      int off = (((kk << 2) + qd) ^ (r & 7)) << 3;
      bf8 ah = *(const bf8*)&S[0][wv * 16 + r][off];
      bf8 al = *(const bf8*)&S[1][wv * 16 + r][off];
      bf8 bh[4], bl[4];
      #pragma unroll
      for (int nt = 0; nt < 4; ++nt) {
        bh[nt] = *(const bf8*)&S[2][nt * 16 + r][off];
        bl[nt] = *(const bf8*)&S[3][nt * 16 + r][off];
      }
      #pragma unroll
      for (int nt = 0; nt < 4; ++nt) {
        acc[nt] = __builtin_amdgcn_mfma_f32_16x16x32_bf16(ah, bh[nt], acc[nt], 0, 0, 0);
        acc[nt] = __builtin_amdgcn_mfma_f32_16x16x32_bf16(ah, bl[nt], acc[nt], 0, 0, 0);
        acc[nt] = __builtin_amdgcn_mfma_f32_16x16x32_bf16(al, bh[nt], acc[nt], 0, 0, 0);
      }
    }
  }
  #pragma unroll
  for (int nt = 0; nt < 4; ++nt) {
    int nn = n0 + nt * 16 + r;
    if (nn >= Nn) continue;
    #pragma unroll
    for (int e = 0; e < 4; ++e) {
      int mm = m0 + wv * 16 + qd * 4 + e;
      if (mm >= M) continue;
      float v = acc[nt][e];
      if (mode == 0) {
        if (bias) v += bias[mm];
        int b2 = nn / nPer, nq = nn - b2 * nPer;
        Y[(size_t)bz * sYb + (size_t)b2 * sYb2 + (size_t)mm * sYm + nq] = v;
      } else {
        if (bias) v += bias[biasN ? nn : mm];
        size_t o = (size_t)bz * sYpb + (size_t)mm * sYpm + nn + pOff;
        ushort h = f2bf(v);
        Yh[o] = h; Yl[o] = f2bf(v - bf2f(h));
      }
    }
  }
}

// generic fp32 -> bf16 hi/lo pair conversion (strided read, contig write)
__global__ __launch_bounds__(256) void cvt_pair(
    const float* __restrict__ src, long s0, long s1, long sb,
    ushort* __restrict__ dh, ushort* __restrict__ dl, long d0, long db,
    int n0, int n1, int pad1, long total)
{
  long i = (long)blockIdx.x * 256 + threadIdx.x;
  if (i >= total) return;
  int wdt = n1 + pad1;
  int i1 = (int)(i % wdt); long rr = i / wdt;
  int i0 = (int)(rr % n0); int b = (int)(rr / n0);
  float f = 0.f;
  if (i1 < n1) f = src[(long)b * sb + (long)i0 * s0 + (long)i1 * s1];
  ushort h = f2bf(f);
  dh[(long)b * db + (long)i0 * d0 + i1] = h;
  dl[(long)b * db + (long)i0 * d0 + i1] = f2bf(f - bf2f(h));
}

// conv-K-layout weight reorder + pair convert:
// k_new = cb*576 + tap*64 + ci  (cb = c/64, ci = c%64); also zero the zp page.
__global__ __launch_bounds__(256) void reorder_w(
    const float* __restrict__ wq, const float* __restrict__ wk,
    const float* __restrict__ wv,
    ushort* __restrict__ qkh, ushort* __restrict__ qkl,
    ushort* __restrict__ vh2, ushort* __restrict__ vl2, ushort* __restrict__ zp)
{
  int i = blockIdx.x * 256 + threadIdx.x;
  if (blockIdx.x == 0 && threadIdx.x < 64) zp[threadIdx.x] = 0;
  if (i >= 768 * 2304) return;
  int o = i / 2304, k = i - o * 2304;
  int cb = k / 576; int rem = k - cb * 576;
  int tap = rem >> 6, ci = rem & 63;
  int si = (cb * 64 + ci) * 9 + tap;
  float f; ushort *dh, *dl; int oo;
  if (o < 256)      { f = wq[o * 2304 + si];         dh = qkh; dl = qkl; oo = o; }
  else if (o < 512) { f = wk[(o - 256) * 2304 + si]; dh = qkh; dl = qkl; oo = o; }
  else              { f = wv[(o - 512) * 2304 + si]; dh = vh2; dl = vl2; oo = o - 512; }
  ushort h = f2bf(f);
  dh[oo * 2304 + k] = h; dl[oo * 2304 + k] = f2bf(f - bf2f(h));
}

// zero the vxp pad columns 1444..1471
__global__ __launch_bounds__(256) void pad_vxp(
    ushort* __restrict__ vxph, ushort* __restrict__ vxpl)
{
  int i = blockIdx.x * 256 + threadIdx.x;
  if (i >= 8 * 256 * 28) return;
  int j = i % 28; int rr = i / 28;
  int c = rr % 256; int n = rr / 256;
  size_t o = (size_t)n * 376832 + (size_t)c * 1472 + 1444 + j;
  vxph[o] = 0; vxpl[o] = 0;
}

// step-1 uniform-h class tables
__global__ __launch_bounds__(64) void uniform_kv_kern(
    const float* __restrict__ h0, const float* __restrict__ w_qh,
    const float* __restrict__ w_kh, const float* __restrict__ w_vh,
    float* __restrict__ qh1, float* __restrict__ kh1, float* __restrict__ vh1)
{
  int a = blockIdx.x, j = blockIdx.y, t = threadIdx.x;
  const float* wsel = (j < 9) ? w_qh : (j == 9) ? w_kh : w_vh;
  bool dyok0 = true, dyok2 = true, dxok0 = true, dxok2 = true;
  if (j < 9) {
    int uy = j / 3, ux = j - uy * 3;
    dyok0 = (uy != 0); dyok2 = (uy != 2);
    dxok0 = (ux != 0); dxok2 = (ux != 2);
  }
  float acc = 0.f;
  for (int c = t; c < 256; c += 64) {
    const float* wp = wsel + a * 2304 + c * 9;
    float s = 0.f;
    #pragma unroll
    for (int dy = 0; dy < 3; ++dy) {
      if ((dy == 0 && !dyok0) || (dy == 2 && !dyok2)) continue;
      #pragma unroll
      for (int dx = 0; dx < 3; ++dx) {
        if ((dx == 0 && !dxok0) || (dx == 2 && !dxok2)) continue;
        s += wp[dy * 3 + dx];
      }
    }
    acc += s * h0[c];
  }
  #pragma unroll
  for (int o = 32; o; o >>= 1) acc += __shfl_down(acc, o);
  if (t == 0) {
    if (j < 9) qh1[j * 256 + a] = acc;
    else if (j == 9) kh1[a] = acc;
    else vh1[a] = acc;
  }
}

// L0[n][u][d] = sum_c qh1[u][c] * k_x[n][d][c]  (k from kxT pair)
__global__ __launch_bounds__(256) void l0_logits(
    const float* __restrict__ qh1, const ushort* __restrict__ kxTh,
    const ushort* __restrict__ kxTl, float* __restrict__ L0)
{
  __shared__ float qs[2304];
  int db = blockIdx.x, n = blockIdx.y;
  for (int i = threadIdx.x; i < 2304; i += 256) qs[i] = qh1[i];
  __syncthreads();
  int d = db * 256 + threadIdx.x;
  bool act = d < 1444;
  size_t ro = (size_t)n * 369664 + (act ? (size_t)d * 256 : 0);
  const ushort* vh = kxTh + ro;
  const ushort* vl = kxTl + ro;
  float acc[9] = {0.f,0.f,0.f,0.f,0.f,0.f,0.f,0.f,0.f};
  for (int c8 = 0; c8 < 256; c8 += 8) {
    uint4 H = *(const uint4*)(vh + c8);
    uint4 L = *(const uint4*)(vl + c8);
    unsigned hw[4] = {H.x, H.y, H.z, H.w};
    unsigned lw[4] = {L.x, L.y, L.z, L.w};
    #pragma unroll
    for (int j = 0; j < 4; ++j) {
      float f0 = bf2f((ushort)(hw[j] & 0xffff)) + bf2f((ushort)(lw[j] & 0xffff));
      float f1 = bf2f((ushort)(hw[j] >> 16)) + bf2f((ushort)(lw[j] >> 16));
      int c = c8 + j * 2;
      #pragma unroll
      for (int u = 0; u < 9; ++u) acc[u] += qs[u * 256 + c] * f0 + qs[u * 256 + c + 1] * f1;
    }
  }
  if (act)
    for (int u = 0; u < 9; ++u) L0[n * 12996 + u * 1444 + d] = acc[u];
}

// fp32 in-place row softmax
__global__ __launch_bounds__(256) void softmax_rows(float* __restrict__ p, int L)
{
  float* rp = p + (long)blockIdx.x * L;
  int t = threadIdx.x;
  __shared__ float redm[4], reds[4];
  float mx = -3.4e38f;
  for (int i = t; i < L; i += 256) mx = fmaxf(mx, rp[i]);
  #pragma unroll
  for (int o = 32; o; o >>= 1) mx = fmaxf(mx, __shfl_down(mx, o));
  if ((t & 63) == 0) redm[t >> 6] = mx;
  __syncthreads();
  mx = fmaxf(fmaxf(redm[0], redm[1]), fmaxf(redm[2], redm[3]));
  float s = 0.f;
  for (int i = t; i < L; i += 256) { float v = expf(rp[i] - mx); rp[i] = v; s += v; }
  #pragma unroll
  for (int o = 32; o; o >>= 1) s += __shfl_down(s, o);
  if ((t & 63) == 0) reds[t >> 6] = s;
  __syncthreads();
  float inv = 1.f / (reds[0] + reds[1] + reds[2] + reds[3]);
  for (int i = t; i < L; i += 256) rp[i] *= inv;
}

// a10[n][u][p] = sum_d wt[n][u][d] * v[n][p][d]  (v from vxp pair)
__global__ __launch_bounds__(256) void a10_pv(
    const float* __restrict__ L0, const ushort* __restrict__ vxph,
    const ushort* __restrict__ vxpl, float* __restrict__ a10)
{
  int u = blockIdx.x, n = blockIdx.y;
  __shared__ float wts[1472];
  const float* wrow = L0 + n * 12996 + u * 1444;
  for (int i = threadIdx.x; i < 1472; i += 256) wts[i] = (i < 1444) ? wrow[i] : 0.f;
  __syncthreads();
  int p = threadIdx.x;
  const ushort* vh = vxph + (size_t)n * 376832 + (size_t)p * 1472;
  const ushort* vl = vxpl + (size_t)n * 376832 + (size_t)p * 1472;
  float acc = 0.f;
  for (int d8 = 0; d8 < 1472; d8 += 8) {
    uint4 hv = *(const uint4*)(vh + d8);
    uint4 lv = *(const uint4*)(vl + d8);
    unsigned hw[4] = {hv.x, hv.y, hv.z, hv.w};
    unsigned lw[4] = {lv.x, lv.y, lv.z, lv.w};
    #pragma unroll
    for (int j = 0; j < 4; ++j) {
      float f0 = bf2f((ushort)(hw[j] & 0xffff)) + bf2f((ushort)(lw[j] & 0xffff));
      float f1 = bf2f((ushort)(hw[j] >> 16)) + bf2f((ushort)(lw[j] >> 16));
      acc += wts[d8 + j * 2] * f0 + wts[d8 + j * 2 + 1] * f1;
    }
  }
  a10[n * 2304 + u * 256 + p] = acc;
}

// gates fused: z/h preact + GRU blend, 9 classes
__global__ __launch_bounds__(256) void gates_k(
    const float* __restrict__ a10, const float* __restrict__ vh1,
    const float* __restrict__ w_z, const float* __restrict__ b_z,
    const float* __restrict__ w_h, const float* __restrict__ b_h,
    const float* __restrict__ h0, float* __restrict__ h1)
{
  int n = blockIdx.x;
  __shared__ float as[2304], vs[256];
  for (int i = threadIdx.x; i < 2304; i += 256) as[i] = a10[n * 2304 + i];
  if (threadIdx.x < 256) vs[threadIdx.x] = vh1[threadIdx.x];
  __syncthreads();
  int hc = threadIdx.x;
  const float* wz = w_z + hc * 512;
  const float* wh = w_h + hc * 512;
  float az[9], ah[9];
  float bz = b_z[hc], bh = b_h[hc];
  #pragma unroll
  for (int u = 0; u < 9; ++u) { az[u] = bz; ah[u] = bh; }
  for (int k = 0; k < 256; ++k) {
    float wzv = wz[k], whv = wh[k];
    #pragma unroll
    for (int u = 0; u < 9; ++u) {
      float vv = as[u * 256 + k];
      az[u] += wzv * vv; ah[u] += whv * vv;
    }
  }
  float sz = 0.f, sh = 0.f;
  for (int k = 0; k < 256; ++k) { float vv = vs[k]; sz += wz[256 + k] * vv; sh += wh[256 + k] * vv; }
  float h0v = h0[hc];
  #pragma unroll
  for (int u = 0; u < 9; ++u) {
    float z = 1.f / (1.f + expf(-(az[u] + sz)));
    float hv = tanhf(ah[u] + sh);
    h1[n * 2304 + hc * 9 + u] = z * h0v + (1.f - z) * hv;
  }
}

// khc/vhc: classed VALID conv over piecewise-constant h1
__global__ __launch_bounds__(256) void khvh_k(
    const float* __restrict__ h1, const float* __restrict__ w_kh,
    const float* __restrict__ w_vh, float* __restrict__ khc, float* __restrict__ vhc)
{
  int u = blockIdx.x, n = blockIdx.y;
  int ty = u / 3, tx = u - ty * 3;
  __shared__ float Gs[2304];
  for (int k = threadIdx.x; k < 2304; k += 256) {
    int c = k / 9, tap = k - c * 9, dy = tap / 3, dx = tap - dy * 3;
    int uy = (ty == 0) ? (dy == 0 ? 0 : 1) : (ty == 2) ? (dy == 2 ? 2 : 1) : 1;
    int ux = (tx == 0) ? (dx == 0 ? 0 : 1) : (tx == 2) ? (dx == 2 ? 2 : 1) : 1;
    Gs[k] = h1[n * 2304 + c * 9 + uy * 3 + ux];
  }
  __syncthreads();
  int hc = threadIdx.x;
  const float* wk = w_kh + hc * 2304;
  const float* wv = w_vh + hc * 2304;
  float ak = 0.f, av = 0.f;
  for (int k = 0; k < 2304; ++k) { float g = Gs[k]; ak += wk[k] * g; av += wv[k] * g; }
  khc[n * 2304 + hc * 9 + u] = ak;
  vhc[n * 2304 + hc * 9 + u] = av;
}

// softmax over 1444 logits (rows stride 1472) -> bf16 pair rows (1472)
__global__ __launch_bounds__(256) void softmax_pair(
    const float* __restrict__ p, ushort* __restrict__ wh, ushort* __restrict__ wl)
{
  long row = blockIdx.x;
  const float* rp = p + row * 1472;
  ushort* oh = wh + row * 1472;
  ushort* ol = wl + row * 1472;
  int t = threadIdx.x;
  __shared__ float buf[1444];
  __shared__ float redm[4], reds[4];
  float mx = -3.4e38f;
  for (int i = t; i < 1444; i += 256) { float v = rp[i]; buf[i] = v; mx = fmaxf(mx, v); }
  #pragma unroll
  for (int o = 32; o; o >>= 1) mx = fmaxf(mx, __shfl_down(mx, o));
  if ((t & 63) == 0) redm[t >> 6] = mx;
  __syncthreads();
  mx = fmaxf(fmaxf(redm[0], redm[1]), fmaxf(redm[2], redm[3]));
  float s = 0.f;
  for (int i = t; i < 1444; i += 256) { float v = expf(buf[i] - mx); buf[i] = v; s += v; }
  #pragma unroll
  for (int o = 32; o; o >>= 1) s += __shfl_down(s, o);
  if ((t & 63) == 0) reds[t >> 6] = s;
  __syncthreads();
  float inv = 1.f / (reds[0] + reds[1] + reds[2] + reds[3]);
  for (int i = t; i < 1472; i += 256) {
    float v = (i < 1444) ? buf[i] * inv : 0.f;
    ushort h = f2bf(v);
    oh[i] = h; ol[i] = f2bf(v - bf2f(h));
  }
}

// step-2 (a=0,b=1) classed attention; coalesced pair output
__global__ __launch_bounds__(256) void attn_b1(
    const ushort* __restrict__ qTh, const ushort* __restrict__ qTl,
    const float* __restrict__ khc, const float* __restrict__ vhc,
    ushort* __restrict__ xaTh, ushort* __restrict__ xaTl)
{
  __shared__ float ks[2304];
  __shared__ float vs[2304];
  __shared__ float es[256][10];
  int n = blockIdx.y;
  int q0 = blockIdx.x * 256;
  for (int i = threadIdx.x; i < 2304; i += 256) { ks[i] = khc[n * 2304 + i]; vs[i] = vhc[n * 2304 + i]; }
  __syncthreads();
  int q = q0 + threadIdx.x;
  bool act = (q < 1600);
  float Lg[9] = {0.f,0.f,0.f,0.f,0.f,0.f,0.f,0.f,0.f};
  size_t ro = (size_t)n * 409600 + (act ? (size_t)q * 256 : 0);
  const ushort* qh = qTh + ro;
  const ushort* ql = qTl + ro;
  for (int c8 = 0; c8 < 256; c8 += 8) {
    uint4 H = *(const uint4*)(qh + c8);
    uint4 L = *(const uint4*)(ql + c8);
    unsigned hw[4] = {H.x, H.y, H.z, H.w};
    unsigned lw[4] = {L.x, L.y, L.z, L.w};
    #pragma unroll
    for (int j = 0; j < 4; ++j) {
      float f0 = bf2f((ushort)(hw[j] & 0xffff)) + bf2f((ushort)(lw[j] & 0xffff));
      float f1 = bf2f((ushort)(hw[j] >> 16)) + bf2f((ushort)(lw[j] >> 16));
      int c = c8 + j * 2;
      #pragma unroll
      for (int tt = 0; tt < 9; ++tt)
        Lg[tt] += f0 * ks[c * 9 + tt] + f1 * ks[(c + 1) * 9 + tt];
    }
  }
  float mx = Lg[0];
  #pragma unroll
  for (int tt = 1; tt < 9; ++tt) mx = fmaxf(mx, Lg[tt]);
  float Z = 0.f;
  float e[9];
  #pragma unroll
  for (int tt = 0; tt < 9; ++tt) {
    float m = ((tt / 3) == 1 ? 36.f : 1.f) * ((tt % 3) == 1 ? 36.f : 1.f);
    e[tt] = act ? m * expf(Lg[tt] - mx) : 0.f;
    Z += e[tt];
  }
  float inv = act ? (1.f / Z) : 0.f;
  #pragma unroll
  for (int tt = 0; tt < 9; ++tt) es[threadIdx.x][tt] = e[tt] * inv;
  __syncthreads();
  int nact = 1600 - q0; if (nact > 256) nact = 256;
  int p = threadIdx.x;
  for (int qq = 0; qq < nact; ++qq) {
    float s = 0.f;
    #pragma unroll
    for (int tt = 0; tt < 9; ++tt) s += es[qq][tt] * vs[p * 9 + tt];
    ushort h = f2bf(s);
    size_t o = (size_t)n * 1228800 + (size_t)(q0 + qq) * 768 + 512 + p;
    xaTh[o] = h; xaTl[o] = f2bf(s - bf2f(h));
  }
}

// ---------------------------------------------------------------------------
extern "C" void kernel_launch(void* const* d_in, const int* in_sizes, int n_in,
                              void* d_out, int out_size, void* d_ws, size_t ws_size,
                              hipStream_t stream)
{
  const float* x     = (const float*)d_in[0];
  const float* h0    = (const float*)d_in[1];
  const float* w_px  = (const float*)d_in[2];
  const float* b_px  = (const float*)d_in[3];
  const float* w_qx  = (const float*)d_in[4];
  const float* w_qh  = (const float*)d_in[5];
  const float* w_kx  = (const float*)d_in[6];
  const float* w_kh  = (const float*)d_in[7];
  const float* w_vx  = (const float*)d_in[8];
  const float* w_vh  = (const float*)d_in[9];
  const float* w_z   = (const float*)d_in[10];
  const float* b_z   = (const float*)d_in[11];
  const float* w_h   = (const float*)d_in[12];
  const float* b_h   = (const float*)d_in[13];
  const float* w_out = (const float*)d_in[14];
  const float* b_out = (const float*)d_in[15];
  float* out = (float*)d_out;

  char* base = (char*)d_ws;
  size_t off = 0;
  auto alloc = [&](size_t bytes) -> char* {
    off = (off + 255) & ~(size_t)255;
    char* p = base + off; off += bytes; return p;
  };
  ushort* xaTh  = (ushort*)alloc(19660800);          // [8][1600][768]
  ushort* xaTl  = (ushort*)alloc(19660800);
  ushort* qTh   = (ushort*)alloc(6553600);           // [8][1600][256]
  ushort* qTl   = (ushort*)alloc(6553600);
  ushort* kxTh  = (ushort*)alloc(5914624);           // [8][1444][256]
  ushort* kxTl  = (ushort*)alloc(5914624);
  ushort* vxph  = (ushort*)alloc(6029312);           // [8][256][1472]
  ushort* vxpl  = (ushort*)alloc(6029312);
  ushort* xTh   = (ushort*)alloc(3276800);           // [12800][128]
  ushort* xTl   = (ushort*)alloc(3276800);
  ushort* Wqkh  = (ushort*)alloc(2359296);           // [512][2304] conv-K order
  ushort* Wqkl  = (ushort*)alloc(2359296);
  ushort* Wvh   = (ushort*)alloc(1179648);           // [256][2304] conv-K order
  ushort* Wvl   = (ushort*)alloc(1179648);
  ushort* wpxh  = (ushort*)alloc(65536);             // [256][128]
  ushort* wpxl  = (ushort*)alloc(65536);
  ushort* wouth = (ushort*)alloc(393216);            // [256][768]
  ushort* woutl = (ushort*)alloc(393216);
  ushort* zp    = (ushort*)alloc(128);               // 64-ushort zero page
  float*  qh1   = (float*)alloc(9216);
  float*  kh1   = (float*)alloc(1024);
  float*  vh1   = (float*)alloc(1024);
  float*  L0    = (float*)alloc(415872);             // [8][9][1444]
  float*  a10   = (float*)alloc(73728);
  float*  h1    = (float*)alloc(73728);
  float*  khc   = (float*)alloc(73728);
  float*  vhc   = (float*)alloc(73728);
  off = (off + 255) & ~(size_t)255;
  char* chunk = base + off;
  long avail = (long)ws_size - (long)off;
  if (avail < 0) avail = 0;
  int an = (int)(avail / 18841600L); if (an < 1) an = 1; if (an > 8) an = 8;

  auto mg = [&](dim3 grid,
                const ushort* Ah, const ushort* Al, long sAb,
                const ushort* Bh, const ushort* Bl, long sBb,
                int M, int Nn, int K, int mode, int gRow0, int swap,
                int aConv, int bConv,
                float* Y, long sYb, long sYm, int nPer, long sYb2,
                const float* bias, int biasN,
                ushort* Yh, ushort* Yl, long sYpb, long sYpm, long pOff,
                ushort* Y2h, ushort* Y2l) {
    mgemm<<<grid, dim3(256), 0, stream>>>(Ah, Al, sAb, Bh, Bl, sBb,
        M, Nn, K, mode, gRow0, swap, aConv, bConv, zp,
        Y, sYb, sYm, nPer, sYb2, bias, biasN,
        Yh, Yl, sYpb, sYpm, pOff, Y2h, Y2l);
  };
  auto mg64 = [&](dim3 grid,
                  const ushort* Ah, const ushort* Al, long sAb,
                  const ushort* Bh, const ushort* Bl, long sBb,
                  int M, int Nn, int K, int mode, int swap,
                  float* Y, long sYb, long sYm, int nPer, long sYb2,
                  const float* bias, int biasN,
                  ushort* Yh, ushort* Yl, long sYpb, long sYpm, long pOff) {
    mgemm64<<<grid, dim3(256), 0, stream>>>(Ah, Al, sAb, Bh, Bl, sBb,
        M, Nn, K, mode, swap, Y, sYb, sYm, nPer, sYb2, bias, biasN,
        Yh, Yl, sYpb, sYpm, pOff);
  };
  const int BIG = 0x40000000;

  // ---- 1) weight/input conversions ----
  cvt_pair<<<dim3(6400), dim3(256), 0, stream>>>(x, 1, 1600, 204800, xTh, xTl, 128, 204800, 1600, 128, 0, 1638400);
  reorder_w<<<dim3(6912), dim3(256), 0, stream>>>(w_qx, w_kx, w_vx, Wqkh, Wqkl, Wvh, Wvl, zp);
  cvt_pair<<<dim3(128), dim3(256), 0, stream>>>(w_px, 128, 1, 0, wpxh, wpxl, 128, 0, 256, 128, 0, 32768);
  cvt_pair<<<dim3(768), dim3(256), 0, stream>>>(w_out, 768, 1, 0, wouth, woutl, 768, 0, 256, 768, 0, 196608);

  // ---- 2) xp-conv: A=xT[12800][128], B=wpx -> xaT cols 0..255 (64-tile) ----
  mg64(dim3(4, 200, 1), xTh, xTl, 0, wpxh, wpxl, 0,
       12800, 256, 128, 1, 1,
       nullptr, 0, 0, 0, 0, b_px, 1,
       xaTh, xaTl, 0, 768, 0);

  // ---- 3) direct shifted-tap convs (conv-K order: cb-major, tap-minor) ----
  mg(dim3(4, 100, 1), xaTh, xaTl, 0, Wqkh, Wqkl, 0,
     12800, 512, 2304, 2, 0, 1, 1, 0,
     nullptr, 0, 0, 0, 0, nullptr, 0,
     qTh, qTl, 0, 0, 0, kxTh, kxTl);
  mg(dim3(2, 100, 1), Wvh, Wvl, 0, xaTh, xaTl, 0,
     256, 12800, 2304, 3, 0, 0, 0, 1,
     nullptr, 0, 0, 0, 0, nullptr, 0,
     vxph, vxpl, 0, 0, 0, nullptr, nullptr);
  pad_vxp<<<dim3(224), dim3(256), 0, stream>>>(vxph, vxpl);

  // ---- 4) classed section ----
  uniform_kv_kern<<<dim3(256, 11), dim3(64), 0, stream>>>(h0, w_qh, w_kh, w_vh, qh1, kh1, vh1);
  l0_logits<<<dim3(6, 8), dim3(256), 0, stream>>>(qh1, kxTh, kxTl, L0);
  softmax_rows<<<dim3(72), dim3(256), 0, stream>>>(L0, 1444);
  a10_pv<<<dim3(9, 8), dim3(256), 0, stream>>>(L0, vxph, vxpl, a10);
  gates_k<<<dim3(8), dim3(256), 0, stream>>>(a10, vh1, w_z, b_z, w_h, b_h, h0, h1);
  khvh_k<<<dim3(9, 8), dim3(256), 0, stream>>>(h1, w_kh, w_vh, khc, vhc);
  attn_b1<<<dim3(7, 8), dim3(256), 0, stream>>>(qTh, qTl, khc, vhc, xaTh, xaTl);

  // ---- 5) step-2 (0,0) full attention ----
  {
    float* scL = (float*)chunk;
    for (int nb0 = 0; nb0 < 8; nb0 += an) {
      int c = (8 - nb0 < an) ? (8 - nb0) : an;
      ushort* wth = (ushort*)(chunk + (long)c * 9420800);
      ushort* wtl = wth + (long)c * 2355200;
      mg(dim3(13, 12, c), qTh + (long)nb0 * 409600, qTl + (long)nb0 * 409600, 409600,
         kxTh + (long)nb0 * 369664, kxTl + (long)nb0 * 369664, 369664,
         1600, 1444, 256, 0, 0, 0, 0, 0,
         scL, 2355200, 1472, BIG, 0, nullptr, 0,
         nullptr, nullptr, 0, 0, 0, nullptr, nullptr);
      softmax_pair<<<dim3(c * 1600), dim3(256), 0, stream>>>(scL, wth, wtl);
      mg64(dim3(4, 25, c), wth, wtl, 2355200,
           vxph + (long)nb0 * 376832, vxpl + (long)nb0 * 376832, 376832,
           1600, 256, 1472, 1, 1,
           nullptr, 0, 0, 0, 0, nullptr, 0,
           xaTh + (long)nb0 * 1228800, xaTl + (long)nb0 * 1228800, 1228800, 768, 256);
    }
  }

  // ---- 6) out-conv: A=wout[256][768], B=xaT rows -> fp32 NCHW (64-tile) ----
  mg64(dim3(4, 200, 1), wouth, woutl, 0, xaTh, xaTl, 0,
       256, 12800, 768, 0, 0,
       out, 0, 1600, 1600, 409600, b_out, 0,
       nullptr, nullptr, 0, 0, 0);
}

// Round 8
// 737.023 us; speedup vs baseline: 1.9244x; 1.5842x over previous
//
#include <hip/hip_runtime.h>
#include <math.h>

// ---------------------------------------------------------------------------
// 2-step recurrent attention cell, N=8, I=128, C=Hc=A=P=O=256, H=W=40
// (Q=1600), VALID 3x3 -> 38x38 (D=1444). fp32 reference.
//
// R0-R2: exact algebraic reductions (step1 uniform h -> 9-class tables; step2
// (0,1) attention collapses; dead branches removed).
// R3-R7: MFMA GEMMs, DMA staging + XOR swizzle, direct shifted-tap conv,
// conv-K channel-block-major order.
// R8: counters showed ALL mgemms bound by the global_load_lds staging path
// (~3.4 TB/s device-wide; WRITE_SIZE counts the L2->LDS deposits). Switch
// split-bf16 (2 planes, 3 MFMA) -> single-plane fp16 (1 plane, 1 MFMA):
// staged bytes /2, MFMA /3, LDS 32 KB -> 4-5 blocks/CU. PV/out/xp back to the
// staging-optimal 128-tile kernel (64-tile doubled staged bytes); mgemm64
// deleted. fp16 error ~1e-2 abs, below the structural 0.03125 absmax
// (bitwise-identical since pure-fp32 R1).
// ---------------------------------------------------------------------------

typedef _Float16 f16;
typedef _Float16 h8 __attribute__((ext_vector_type(8)));   // 8 fp16 (4 VGPRs)
typedef __attribute__((ext_vector_type(4))) float f4;

__device__ __forceinline__ ushort f2h(float f) {
  union { f16 h; ushort u; } cv; cv.h = (f16)f; return cv.u;
}
__device__ __forceinline__ float h2f(ushort u) {
  union { ushort u; f16 h; } cv; cv.u = u; return (float)cv.h;
}

// ---------------- MFMA fp16 GEMM, 128x128 tile ----------------
// C[m][n] = sum_k A[m][k]*B[n][k], k-contig fp16, K % 64 == 0.
// KB=64 chunks, global_load_lds 16B staging, XOR swizzle (conflict-free).
// aConv/bConv: operand rows are image positions (8x40x40), row stride 768
// (xaT); conv K layout: k = cb*576 + tap*64 + ci (chunk-uniform tap shift).
// Border-invalid rows read the zero page zp.
// Epilogue modes: 0 fp32 / 1 fp16 / 2 qk-split(qT,kxT) / 3 v-crop(vxp).
__global__ __launch_bounds__(256) void mgemm(
    const ushort* __restrict__ A, long sAb,
    const ushort* __restrict__ B, long sBb,
    int M, int Nn, int K, int mode, int gRow0, int swap, int aConv, int bConv,
    const ushort* __restrict__ zp,
    float* __restrict__ Y, long sYb, long sYm, int nPer, long sYb2,
    const float* __restrict__ bias, int biasN,
    ushort* __restrict__ Yh, long sYpb, long sYpm, long pOff,
    ushort* __restrict__ Y2h)
{
  __shared__ ushort S[2][128][64];   // A plane, B plane ; 32 KB
  const int bz = blockIdx.z;
  A += (long)bz * sAb;
  B += (long)bz * sBb;
  const int mb = swap ? blockIdx.y : blockIdx.x;
  const int nb = swap ? blockIdx.x : blockIdx.y;
  const int m0 = mb * 128, n0 = nb * 128;
  const int t = threadIdx.x;
  const int lane = t & 63, wv = t >> 6;
  const int r = lane & 15, qd = lane >> 4;
  const int wm = (wv & 1) * 64, wn = (wv >> 1) * 64;
  const int lrow = lane >> 3, lch = lane & 7;
  f4 acc[4][4];
  #pragma unroll
  for (int i = 0; i < 4; ++i)
    #pragma unroll
    for (int j = 0; j < 4; ++j) acc[i][j] = (f4){0.f, 0.f, 0.f, 0.f};

  int cg8[4];
  int aB[4], aY[4], aX[4]; long aO[4];
  int bB[4], bY[4], bX[4]; long bO[4];
  #pragma unroll
  for (int i = 0; i < 4; ++i) {
    int row = wv * 32 + i * 8 + lrow;
    cg8[i] = (lch ^ (row & 7)) * 8;
    {
      int gr = m0 + row;
      if (aConv) {
        int n8 = gr / 1600, pos = gr - n8 * 1600;
        int py = pos / 40, px = pos - py * 40;
        aB[i] = n8 * 1600; aY[i] = py; aX[i] = px;
      } else { if (gr > M - 1) gr = M - 1; aO[i] = (long)gr * K; }
    }
    {
      int gr = n0 + row;
      if (bConv) {
        int n8 = gr / 1600, pos = gr - n8 * 1600;
        int py = pos / 40, px = pos - py * 40;
        bB[i] = n8 * 1600; bY[i] = py; bX[i] = px;
      } else { if (gr > Nn - 1) gr = Nn - 1; bO[i] = (long)gr * K; }
    }
  }

  ushort* lbase = (ushort*)S;
  for (int kc = 0; kc < K; kc += 64) {
    __syncthreads();
    int ch = kc >> 6;
    int cb = ch / 9, tap = ch - cb * 9;       // conv-K: cb-major, tap-minor
    int tdy = tap / 3 - 1, tdx = tap - (tap / 3) * 3 - 1;
    int kin = cb << 6;
    #pragma unroll
    for (int i = 0; i < 4; ++i) {
      int seg = wv * 2048 + i * 512;
      {
        const ushort* p; size_t go;
        if (aConv) {
          int yy = aY[i] + tdy, xx = aX[i] + tdx;
          bool v = ((unsigned)yy < 40u) && ((unsigned)xx < 40u);
          if (v) { go = (size_t)(aB[i] + yy * 40 + xx) * 768 + kin + cg8[i]; p = A; }
          else   { go = 0; p = zp; }
        } else { go = (size_t)(aO[i] + kc + cg8[i]); p = A; }
        __builtin_amdgcn_global_load_lds(p + go, lbase + seg, 16, 0, 0);
      }
      {
        const ushort* p; size_t go;
        if (bConv) {
          int yy = bY[i] + tdy, xx = bX[i] + tdx;
          bool v = ((unsigned)yy < 40u) && ((unsigned)xx < 40u);
          if (v) { go = (size_t)(bB[i] + yy * 40 + xx) * 768 + kin + cg8[i]; p = B; }
          else   { go = 0; p = zp; }
        } else { go = (size_t)(bO[i] + kc + cg8[i]); p = B; }
        __builtin_amdgcn_global_load_lds(p + go, lbase + 8192 + seg, 16, 0, 0);
      }
    }
    __syncthreads();
    #pragma unroll
    for (int kk = 0; kk < 2; ++kk) {
      int off = (((kk << 2) + qd) ^ (r & 7)) << 3;
      h8 af[4], bf[4];
      #pragma unroll
      for (int mt = 0; mt < 4; ++mt) {
        af[mt] = *(const h8*)&S[0][wm + mt * 16 + r][off];
        bf[mt] = *(const h8*)&S[1][wn + mt * 16 + r][off];
      }
      #pragma unroll
      for (int mt = 0; mt < 4; ++mt)
        #pragma unroll
        for (int nt = 0; nt < 4; ++nt)
          acc[mt][nt] = __builtin_amdgcn_mfma_f32_16x16x32_f16(af[mt], bf[nt], acc[mt][nt], 0, 0, 0);
    }
  }
  #pragma unroll
  for (int mt = 0; mt < 4; ++mt)
    #pragma unroll
    for (int nt = 0; nt < 4; ++nt) {
      int nn = n0 + wn + nt * 16 + r;
      if (nn >= Nn) continue;
      #pragma unroll
      for (int e = 0; e < 4; ++e) {
        int mm = m0 + wm + mt * 16 + qd * 4 + e;
        if (mm >= M) continue;
        float v = acc[mt][nt][e];
        if (mode == 0) {
          if (bias) v += bias[mm];
          int b2 = nn / nPer, nq = nn - b2 * nPer;
          Y[(size_t)bz * sYb + (size_t)b2 * sYb2 + (size_t)mm * sYm + nq] = v;
        } else if (mode == 1) {
          if (bias) v += bias[biasN ? nn : mm];
          Yh[(size_t)bz * sYpb + (size_t)mm * sYpm + nn + pOff] = f2h(v);
        } else if (mode == 2) {
          int gm = gRow0 + mm;
          int n8 = gm / 1600, q = gm - n8 * 1600;
          ushort h = f2h(v);
          if (nn < 256) {
            Yh[(size_t)n8 * 409600 + (size_t)q * 256 + nn] = h;
          } else {
            int qy = q / 40, qx = q - qy * 40;
            if (qy >= 1 && qy <= 38 && qx >= 1 && qx <= 38)
              Y2h[(size_t)n8 * 369664 + (size_t)((qy - 1) * 38 + qx - 1) * 256 + (nn - 256)] = h;
          }
        } else {   // mode 3
          int gn = gRow0 + nn;
          int n8 = gn / 1600, q = gn - n8 * 1600;
          int qy = q / 40, qx = q - qy * 40;
          if (qy >= 1 && qy <= 38 && qx >= 1 && qx <= 38)
            Yh[(size_t)n8 * 376832 + (size_t)mm * 1472 + (qy - 1) * 38 + qx - 1] = f2h(v);
        }
      }
    }
}

// generic fp32 -> fp16 conversion (strided read, contig write)
__global__ __launch_bounds__(256) void cvt_f16(
    const float* __restrict__ src, long s0, long s1, long sb,
    ushort* __restrict__ d, long d0, long db,
    int n0, int n1, int pad1, long total)
{
  long i = (long)blockIdx.x * 256 + threadIdx.x;
  if (i >= total) return;
  int wdt = n1 + pad1;
  int i1 = (int)(i % wdt); long rr = i / wdt;
  int i0 = (int)(rr % n0); int b = (int)(rr / n0);
  float f = 0.f;
  if (i1 < n1) f = src[(long)b * sb + (long)i0 * s0 + (long)i1 * s1];
  d[(long)b * db + (long)i0 * d0 + i1] = f2h(f);
}

// conv-K-layout weight reorder + fp16 convert; zero the zp page.
__global__ __launch_bounds__(256) void reorder_w(
    const float* __restrict__ wq, const float* __restrict__ wk,
    const float* __restrict__ wv,
    ushort* __restrict__ qk, ushort* __restrict__ v2, ushort* __restrict__ zp)
{
  int i = blockIdx.x * 256 + threadIdx.x;
  if (blockIdx.x == 0 && threadIdx.x < 64) zp[threadIdx.x] = 0;
  if (i >= 768 * 2304) return;
  int o = i / 2304, k = i - o * 2304;
  int cb = k / 576; int rem = k - cb * 576;
  int tap = rem >> 6, ci = rem & 63;
  int si = (cb * 64 + ci) * 9 + tap;
  float f; ushort* d; int oo;
  if (o < 256)      { f = wq[o * 2304 + si];         d = qk; oo = o; }
  else if (o < 512) { f = wk[(o - 256) * 2304 + si]; d = qk; oo = o; }
  else              { f = wv[(o - 512) * 2304 + si]; d = v2; oo = o - 512; }
  d[oo * 2304 + k] = f2h(f);
}

// zero the vxp pad columns 1444..1471
__global__ __launch_bounds__(256) void pad_vxp(ushort* __restrict__ vxp)
{
  int i = blockIdx.x * 256 + threadIdx.x;
  if (i >= 8 * 256 * 28) return;
  int j = i % 28; int rr = i / 28;
  int c = rr % 256; int n = rr / 256;
  vxp[(size_t)n * 376832 + (size_t)c * 1472 + 1444 + j] = 0;
}

// step-1 uniform-h class tables
__global__ __launch_bounds__(64) void uniform_kv_kern(
    const float* __restrict__ h0, const float* __restrict__ w_qh,
    const float* __restrict__ w_kh, const float* __restrict__ w_vh,
    float* __restrict__ qh1, float* __restrict__ kh1, float* __restrict__ vh1)
{
  int a = blockIdx.x, j = blockIdx.y, t = threadIdx.x;
  const float* wsel = (j < 9) ? w_qh : (j == 9) ? w_kh : w_vh;
  bool dyok0 = true, dyok2 = true, dxok0 = true, dxok2 = true;
  if (j < 9) {
    int uy = j / 3, ux = j - uy * 3;
    dyok0 = (uy != 0); dyok2 = (uy != 2);
    dxok0 = (ux != 0); dxok2 = (ux != 2);
  }
  float acc = 0.f;
  for (int c = t; c < 256; c += 64) {
    const float* wp = wsel + a * 2304 + c * 9;
    float s = 0.f;
    #pragma unroll
    for (int dy = 0; dy < 3; ++dy) {
      if ((dy == 0 && !dyok0) || (dy == 2 && !dyok2)) continue;
      #pragma unroll
      for (int dx = 0; dx < 3; ++dx) {
        if ((dx == 0 && !dxok0) || (dx == 2 && !dxok2)) continue;
        s += wp[dy * 3 + dx];
      }
    }
    acc += s * h0[c];
  }
  #pragma unroll
  for (int o = 32; o; o >>= 1) acc += __shfl_down(acc, o);
  if (t == 0) {
    if (j < 9) qh1[j * 256 + a] = acc;
    else if (j == 9) kh1[a] = acc;
    else vh1[a] = acc;
  }
}

// L0[n][u][d] = sum_c qh1[u][c] * k_x[n][d][c]  (kxT fp16)
__global__ __launch_bounds__(256) void l0_logits(
    const float* __restrict__ qh1, const ushort* __restrict__ kxT,
    float* __restrict__ L0)
{
  __shared__ float qs[2304];
  int db = blockIdx.x, n = blockIdx.y;
  for (int i = threadIdx.x; i < 2304; i += 256) qs[i] = qh1[i];
  __syncthreads();
  int d = db * 256 + threadIdx.x;
  bool act = d < 1444;
  const ushort* vp = kxT + (size_t)n * 369664 + (act ? (size_t)d * 256 : 0);
  float acc[9] = {0.f,0.f,0.f,0.f,0.f,0.f,0.f,0.f,0.f};
  for (int c8 = 0; c8 < 256; c8 += 8) {
    h8 v = *(const h8*)(const void*)(vp + c8);
    #pragma unroll
    for (int j = 0; j < 8; ++j) {
      float f = (float)v[j];
      #pragma unroll
      for (int u = 0; u < 9; ++u) acc[u] += qs[u * 256 + c8 + j] * f;
    }
  }
  if (act)
    for (int u = 0; u < 9; ++u) L0[n * 12996 + u * 1444 + d] = acc[u];
}

// fp32 in-place row softmax
__global__ __launch_bounds__(256) void softmax_rows(float* __restrict__ p, int L)
{
  float* rp = p + (long)blockIdx.x * L;
  int t = threadIdx.x;
  __shared__ float redm[4], reds[4];
  float mx = -3.4e38f;
  for (int i = t; i < L; i += 256) mx = fmaxf(mx, rp[i]);
  #pragma unroll
  for (int o = 32; o; o >>= 1) mx = fmaxf(mx, __shfl_down(mx, o));
  if ((t & 63) == 0) redm[t >> 6] = mx;
  __syncthreads();
  mx = fmaxf(fmaxf(redm[0], redm[1]), fmaxf(redm[2], redm[3]));
  float s = 0.f;
  for (int i = t; i < L; i += 256) { float v = expf(rp[i] - mx); rp[i] = v; s += v; }
  #pragma unroll
  for (int o = 32; o; o >>= 1) s += __shfl_down(s, o);
  if ((t & 63) == 0) reds[t >> 6] = s;
  __syncthreads();
  float inv = 1.f / (reds[0] + reds[1] + reds[2] + reds[3]);
  for (int i = t; i < L; i += 256) rp[i] *= inv;
}

// a10[n][u][p] = sum_d wt[n][u][d] * v[n][p][d]  (vxp fp16)
__global__ __launch_bounds__(256) void a10_pv(
    const float* __restrict__ L0, const ushort* __restrict__ vxp,
    float* __restrict__ a10)
{
  int u = blockIdx.x, n = blockIdx.y;
  __shared__ float wts[1472];
  const float* wrow = L0 + n * 12996 + u * 1444;
  for (int i = threadIdx.x; i < 1472; i += 256) wts[i] = (i < 1444) ? wrow[i] : 0.f;
  __syncthreads();
  int p = threadIdx.x;
  const ushort* vp = vxp + (size_t)n * 376832 + (size_t)p * 1472;
  float acc = 0.f;
  for (int d8 = 0; d8 < 1472; d8 += 8) {
    h8 v = *(const h8*)(const void*)(vp + d8);
    #pragma unroll
    for (int j = 0; j < 8; ++j) acc += wts[d8 + j] * (float)v[j];
  }
  a10[n * 2304 + u * 256 + p] = acc;
}

// gates fused: z/h preact + GRU blend, 9 classes
__global__ __launch_bounds__(256) void gates_k(
    const float* __restrict__ a10, const float* __restrict__ vh1,
    const float* __restrict__ w_z, const float* __restrict__ b_z,
    const float* __restrict__ w_h, const float* __restrict__ b_h,
    const float* __restrict__ h0, float* __restrict__ h1)
{
  int n = blockIdx.x;
  __shared__ float as[2304], vs[256];
  for (int i = threadIdx.x; i < 2304; i += 256) as[i] = a10[n * 2304 + i];
  if (threadIdx.x < 256) vs[threadIdx.x] = vh1[threadIdx.x];
  __syncthreads();
  int hc = threadIdx.x;
  const float* wz = w_z + hc * 512;
  const float* wh = w_h + hc * 512;
  float az[9], ah[9];
  float bz = b_z[hc], bh = b_h[hc];
  #pragma unroll
  for (int u = 0; u < 9; ++u) { az[u] = bz; ah[u] = bh; }
  for (int k = 0; k < 256; ++k) {
    float wzv = wz[k], whv = wh[k];
    #pragma unroll
    for (int u = 0; u < 9; ++u) {
      float vv = as[u * 256 + k];
      az[u] += wzv * vv; ah[u] += whv * vv;
    }
  }
  float sz = 0.f, sh = 0.f;
  for (int k = 0; k < 256; ++k) { float vv = vs[k]; sz += wz[256 + k] * vv; sh += wh[256 + k] * vv; }
  float h0v = h0[hc];
  #pragma unroll
  for (int u = 0; u < 9; ++u) {
    float z = 1.f / (1.f + expf(-(az[u] + sz)));
    float hv = tanhf(ah[u] + sh);
    h1[n * 2304 + hc * 9 + u] = z * h0v + (1.f - z) * hv;
  }
}

// khc/vhc: classed VALID conv over piecewise-constant h1
__global__ __launch_bounds__(256) void khvh_k(
    const float* __restrict__ h1, const float* __restrict__ w_kh,
    const float* __restrict__ w_vh, float* __restrict__ khc, float* __restrict__ vhc)
{
  int u = blockIdx.x, n = blockIdx.y;
  int ty = u / 3, tx = u - ty * 3;
  __shared__ float Gs[2304];
  for (int k = threadIdx.x; k < 2304; k += 256) {
    int c = k / 9, tap = k - c * 9, dy = tap / 3, dx = tap - dy * 3;
    int uy = (ty == 0) ? (dy == 0 ? 0 : 1) : (ty == 2) ? (dy == 2 ? 2 : 1) : 1;
    int ux = (tx == 0) ? (dx == 0 ? 0 : 1) : (tx == 2) ? (dx == 2 ? 2 : 1) : 1;
    Gs[k] = h1[n * 2304 + c * 9 + uy * 3 + ux];
  }
  __syncthreads();
  int hc = threadIdx.x;
  const float* wk = w_kh + hc * 2304;
  const float* wv = w_vh + hc * 2304;
  float ak = 0.f, av = 0.f;
  for (int k = 0; k < 2304; ++k) { float g = Gs[k]; ak += wk[k] * g; av += wv[k] * g; }
  khc[n * 2304 + hc * 9 + u] = ak;
  vhc[n * 2304 + hc * 9 + u] = av;
}

// softmax over 1444 fp32 logits (row stride 1472) -> fp16 rows (1472, padded)
__global__ __launch_bounds__(256) void softmax_f16(
    const float* __restrict__ p, ushort* __restrict__ wt)
{
  long row = blockIdx.x;
  const float* rp = p + row * 1472;
  ushort* op = wt + row * 1472;
  int t = threadIdx.x;
  __shared__ float buf[1444];
  __shared__ float redm[4], reds[4];
  float mx = -3.4e38f;
  for (int i = t; i < 1444; i += 256) { float v = rp[i]; buf[i] = v; mx = fmaxf(mx, v); }
  #pragma unroll
  for (int o = 32; o; o >>= 1) mx = fmaxf(mx, __shfl_down(mx, o));
  if ((t & 63) == 0) redm[t >> 6] = mx;
  __syncthreads();
  mx = fmaxf(fmaxf(redm[0], redm[1]), fmaxf(redm[2], redm[3]));
  float s = 0.f;
  for (int i = t; i < 1444; i += 256) { float v = expf(buf[i] - mx); buf[i] = v; s += v; }
  #pragma unroll
  for (int o = 32; o; o >>= 1) s += __shfl_down(s, o);
  if ((t & 63) == 0) reds[t >> 6] = s;
  __syncthreads();
  float inv = 1.f / (reds[0] + reds[1] + reds[2] + reds[3]);
  for (int i = t; i < 1472; i += 256)
    op[i] = f2h((i < 1444) ? buf[i] * inv : 0.f);
}

// step-2 (a=0,b=1) classed attention; qT fp16; coalesced fp16 output
__global__ __launch_bounds__(256) void attn_b1(
    const ushort* __restrict__ qT, const float* __restrict__ khc,
    const float* __restrict__ vhc, ushort* __restrict__ xaT)
{
  __shared__ float ks[2304];
  __shared__ float vs[2304];
  __shared__ float es[256][10];
  int n = blockIdx.y;
  int q0 = blockIdx.x * 256;
  for (int i = threadIdx.x; i < 2304; i += 256) { ks[i] = khc[n * 2304 + i]; vs[i] = vhc[n * 2304 + i]; }
  __syncthreads();
  int q = q0 + threadIdx.x;
  bool act = (q < 1600);
  float Lg[9] = {0.f,0.f,0.f,0.f,0.f,0.f,0.f,0.f,0.f};
  const ushort* qp = qT + (size_t)n * 409600 + (act ? (size_t)q * 256 : 0);
  for (int c8 = 0; c8 < 256; c8 += 8) {
    h8 v = *(const h8*)(const void*)(qp + c8);
    #pragma unroll
    for (int j = 0; j < 8; ++j) {
      float f = (float)v[j];
      #pragma unroll
      for (int tt = 0; tt < 9; ++tt) Lg[tt] += f * ks[(c8 + j) * 9 + tt];
    }
  }
  float mx = Lg[0];
  #pragma unroll
  for (int tt = 1; tt < 9; ++tt) mx = fmaxf(mx, Lg[tt]);
  float Z = 0.f;
  float e[9];
  #pragma unroll
  for (int tt = 0; tt < 9; ++tt) {
    float m = ((tt / 3) == 1 ? 36.f : 1.f) * ((tt % 3) == 1 ? 36.f : 1.f);
    e[tt] = act ? m * expf(Lg[tt] - mx) : 0.f;
    Z += e[tt];
  }
  float inv = act ? (1.f / Z) : 0.f;
  #pragma unroll
  for (int tt = 0; tt < 9; ++tt) es[threadIdx.x][tt] = e[tt] * inv;
  __syncthreads();
  int nact = 1600 - q0; if (nact > 256) nact = 256;
  int p = threadIdx.x;
  for (int qq = 0; qq < nact; ++qq) {
    float s = 0.f;
    #pragma unroll
    for (int tt = 0; tt < 9; ++tt) s += es[qq][tt] * vs[p * 9 + tt];
    xaT[(size_t)n * 1228800 + (size_t)(q0 + qq) * 768 + 512 + p] = f2h(s);
  }
}

// ---------------------------------------------------------------------------
extern "C" void kernel_launch(void* const* d_in, const int* in_sizes, int n_in,
                              void* d_out, int out_size, void* d_ws, size_t ws_size,
                              hipStream_t stream)
{
  const float* x     = (const float*)d_in[0];
  const float* h0    = (const float*)d_in[1];
  const float* w_px  = (const float*)d_in[2];
  const float* b_px  = (const float*)d_in[3];
  const float* w_qx  = (const float*)d_in[4];
  const float* w_qh  = (const float*)d_in[5];
  const float* w_kx  = (const float*)d_in[6];
  const float* w_kh  = (const float*)d_in[7];
  const float* w_vx  = (const float*)d_in[8];
  const float* w_vh  = (const float*)d_in[9];
  const float* w_z   = (const float*)d_in[10];
  const float* b_z   = (const float*)d_in[11];
  const float* w_h   = (const float*)d_in[12];
  const float* b_h   = (const float*)d_in[13];
  const float* w_out = (const float*)d_in[14];
  const float* b_out = (const float*)d_in[15];
  float* out = (float*)d_out;

  char* base = (char*)d_ws;
  size_t off = 0;
  auto alloc = [&](size_t bytes) -> char* {
    off = (off + 255) & ~(size_t)255;
    char* p = base + off; off += bytes; return p;
  };
  ushort* xaT  = (ushort*)alloc(19660800);          // [8][1600][768] fp16
  ushort* qT   = (ushort*)alloc(6553600);           // [8][1600][256]
  ushort* kxT  = (ushort*)alloc(5914624);           // [8][1444][256]
  ushort* vxp  = (ushort*)alloc(6029312);           // [8][256][1472]
  ushort* xT   = (ushort*)alloc(3276800);           // [12800][128]
  ushort* Wqk  = (ushort*)alloc(2359296);           // [512][2304] conv-K order
  ushort* Wv   = (ushort*)alloc(1179648);           // [256][2304] conv-K order
  ushort* wpx  = (ushort*)alloc(65536);             // [256][128]
  ushort* wout = (ushort*)alloc(393216);            // [256][768]
  ushort* zp   = (ushort*)alloc(128);               // 64-ushort zero page
  float*  qh1  = (float*)alloc(9216);
  float*  kh1  = (float*)alloc(1024);
  float*  vh1  = (float*)alloc(1024);
  float*  L0   = (float*)alloc(415872);             // [8][9][1444]
  float*  a10  = (float*)alloc(73728);
  float*  h1   = (float*)alloc(73728);
  float*  khc  = (float*)alloc(73728);
  float*  vhc  = (float*)alloc(73728);
  off = (off + 255) & ~(size_t)255;
  char* chunk = base + off;
  long avail = (long)ws_size - (long)off;
  if (avail < 0) avail = 0;
  int an = (int)(avail / 14131200L); if (an < 1) an = 1; if (an > 8) an = 8;

  auto mg = [&](dim3 grid,
                const ushort* A, long sAb, const ushort* B, long sBb,
                int M, int Nn, int K, int mode, int gRow0, int swap,
                int aConv, int bConv,
                float* Y, long sYb, long sYm, int nPer, long sYb2,
                const float* bias, int biasN,
                ushort* Yh, long sYpb, long sYpm, long pOff, ushort* Y2h) {
    mgemm<<<grid, dim3(256), 0, stream>>>(A, sAb, B, sBb,
        M, Nn, K, mode, gRow0, swap, aConv, bConv, zp,
        Y, sYb, sYm, nPer, sYb2, bias, biasN, Yh, sYpb, sYpm, pOff, Y2h);
  };
  const int BIG = 0x40000000;

  // ---- 1) weight/input conversions (fp16 single-plane) ----
  cvt_f16<<<dim3(6400), dim3(256), 0, stream>>>(x, 1, 1600, 204800, xT, 128, 204800, 1600, 128, 0, 1638400);
  reorder_w<<<dim3(6912), dim3(256), 0, stream>>>(w_qx, w_kx, w_vx, Wqk, Wv, zp);
  cvt_f16<<<dim3(128), dim3(256), 0, stream>>>(w_px, 128, 1, 0, wpx, 128, 0, 256, 128, 0, 32768);
  cvt_f16<<<dim3(768), dim3(256), 0, stream>>>(w_out, 768, 1, 0, wout, 768, 0, 256, 768, 0, 196608);

  // ---- 2) xp-conv: A=xT[12800][128], B=wpx -> xaT cols 0..255 ----
  mg(dim3(2, 100, 1), xT, 0, wpx, 0,
     12800, 256, 128, 1, 0, 1, 0, 0,
     nullptr, 0, 0, 0, 0, b_px, 1,
     xaT, 0, 768, 0, nullptr);

  // ---- 3) direct shifted-tap convs (conv-K order) ----
  mg(dim3(4, 100, 1), xaT, 0, Wqk, 0,
     12800, 512, 2304, 2, 0, 1, 1, 0,
     nullptr, 0, 0, 0, 0, nullptr, 0,
     qT, 0, 0, 0, kxT);
  mg(dim3(2, 100, 1), Wv, 0, xaT, 0,
     256, 12800, 2304, 3, 0, 0, 0, 1,
     nullptr, 0, 0, 0, 0, nullptr, 0,
     vxp, 0, 0, 0, nullptr);
  pad_vxp<<<dim3(224), dim3(256), 0, stream>>>(vxp);

  // ---- 4) classed section ----
  uniform_kv_kern<<<dim3(256, 11), dim3(64), 0, stream>>>(h0, w_qh, w_kh, w_vh, qh1, kh1, vh1);
  l0_logits<<<dim3(6, 8), dim3(256), 0, stream>>>(qh1, kxT, L0);
  softmax_rows<<<dim3(72), dim3(256), 0, stream>>>(L0, 1444);
  a10_pv<<<dim3(9, 8), dim3(256), 0, stream>>>(L0, vxp, a10);
  gates_k<<<dim3(8), dim3(256), 0, stream>>>(a10, vh1, w_z, b_z, w_h, b_h, h0, h1);
  khvh_k<<<dim3(9, 8), dim3(256), 0, stream>>>(h1, w_kh, w_vh, khc, vhc);
  attn_b1<<<dim3(7, 8), dim3(256), 0, stream>>>(qT, khc, vhc, xaT);

  // ---- 5) step-2 (0,0) full attention ----
  {
    float* scL = (float*)chunk;
    for (int nb0 = 0; nb0 < 8; nb0 += an) {
      int c = (8 - nb0 < an) ? (8 - nb0) : an;
      ushort* wt = (ushort*)(chunk + (long)c * 9420800);
      mg(dim3(13, 12, c), qT + (long)nb0 * 409600, 409600,
         kxT + (long)nb0 * 369664, 369664,
         1600, 1444, 256, 0, 0, 0, 0, 0,
         scL, 2355200, 1472, BIG, 0, nullptr, 0,
         nullptr, 0, 0, 0, nullptr);
      softmax_f16<<<dim3(c * 1600), dim3(256), 0, stream>>>(scL, wt);
      mg(dim3(13, 2, c), wt, 2355200,
         vxp + (long)nb0 * 376832, 376832,
         1600, 256, 1472, 1, 0, 0, 0, 0,
         nullptr, 0, 0, 0, 0, nullptr, 0,
         xaT + (long)nb0 * 1228800, 1228800, 768, 256, nullptr);
    }
  }

  // ---- 6) out-conv: A=wout[256][768], B=xaT rows -> fp32 NCHW ----
  mg(dim3(2, 100, 1), wout, 0, xaT, 0,
     256, 12800, 768, 0, 0, 0, 0, 0,
     out, 0, 1600, 1600, 409600, b_out, 0,
     nullptr, 0, 0, 0, nullptr);
}

// Round 9
// 595.193 us; speedup vs baseline: 2.3830x; 1.2383x over previous
//
#include <hip/hip_runtime.h>
#include <math.h>

// ---------------------------------------------------------------------------
// 2-step recurrent attention cell, N=8, I=128, C=Hc=A=P=O=256, H=W=40
// (Q=1600), VALID 3x3 -> 38x38 (D=1444). fp32 reference.
//
// R0-R2: exact algebraic reductions (step1 uniform h -> 9-class tables; step2
// (0,1) attention collapses; dead branches removed).
// R3-R7: MFMA GEMMs, DMA staging + XOR swizzle, direct shifted-tap conv,
// conv-K channel-block-major order.
// R8: single-plane fp16 (staged bytes /2, MFMA /3) -- all mgemms bound by the
// ~3.4 TB/s global_load_lds deposit path.
// R9: the two hand-rolled classed matvecs (khvh_k 135us, gates_k ~40us --
// uncoalesced per-thread weight walks at 3% occupancy) re-expressed as tiny
// 72-row MFMA GEMMs (GA/AV fp16 operand builds + mgemm + elementwise tail);
// attn_b1 reads the new [u][hc] khvc layout (broadcast / stride-1, no
// conflicts).
// ---------------------------------------------------------------------------

typedef _Float16 f16;
typedef _Float16 h8 __attribute__((ext_vector_type(8)));   // 8 fp16 (4 VGPRs)
typedef __attribute__((ext_vector_type(4))) float f4;

__device__ __forceinline__ ushort f2h(float f) {
  union { f16 h; ushort u; } cv; cv.h = (f16)f; return cv.u;
}

// ---------------- MFMA fp16 GEMM, 128x128 tile ----------------
// C[m][n] = sum_k A[m][k]*B[n][k], k-contig fp16, K % 64 == 0.
// KB=64 chunks, global_load_lds 16B staging, XOR swizzle (conflict-free).
// aConv/bConv: operand rows are image positions (8x40x40), row stride 768
// (xaT); conv K layout: k = cb*576 + tap*64 + ci (chunk-uniform tap shift).
// Border-invalid rows read the zero page zp.
// Epilogue modes: 0 fp32 / 1 fp16 / 2 qk-split(qT,kxT) / 3 v-crop(vxp).
__global__ __launch_bounds__(256) void mgemm(
    const ushort* __restrict__ A, long sAb,
    const ushort* __restrict__ B, long sBb,
    int M, int Nn, int K, int mode, int gRow0, int swap, int aConv, int bConv,
    const ushort* __restrict__ zp,
    float* __restrict__ Y, long sYb, long sYm, int nPer, long sYb2,
    const float* __restrict__ bias, int biasN,
    ushort* __restrict__ Yh, long sYpb, long sYpm, long pOff,
    ushort* __restrict__ Y2h)
{
  __shared__ ushort S[2][128][64];   // A plane, B plane ; 32 KB
  const int bz = blockIdx.z;
  A += (long)bz * sAb;
  B += (long)bz * sBb;
  const int mb = swap ? blockIdx.y : blockIdx.x;
  const int nb = swap ? blockIdx.x : blockIdx.y;
  const int m0 = mb * 128, n0 = nb * 128;
  const int t = threadIdx.x;
  const int lane = t & 63, wv = t >> 6;
  const int r = lane & 15, qd = lane >> 4;
  const int wm = (wv & 1) * 64, wn = (wv >> 1) * 64;
  const int lrow = lane >> 3, lch = lane & 7;
  f4 acc[4][4];
  #pragma unroll
  for (int i = 0; i < 4; ++i)
    #pragma unroll
    for (int j = 0; j < 4; ++j) acc[i][j] = (f4){0.f, 0.f, 0.f, 0.f};

  int cg8[4];
  int aB[4], aY[4], aX[4]; long aO[4];
  int bB[4], bY[4], bX[4]; long bO[4];
  #pragma unroll
  for (int i = 0; i < 4; ++i) {
    int row = wv * 32 + i * 8 + lrow;
    cg8[i] = (lch ^ (row & 7)) * 8;
    {
      int gr = m0 + row;
      if (aConv) {
        int n8 = gr / 1600, pos = gr - n8 * 1600;
        int py = pos / 40, px = pos - py * 40;
        aB[i] = n8 * 1600; aY[i] = py; aX[i] = px;
      } else { if (gr > M - 1) gr = M - 1; aO[i] = (long)gr * K; }
    }
    {
      int gr = n0 + row;
      if (bConv) {
        int n8 = gr / 1600, pos = gr - n8 * 1600;
        int py = pos / 40, px = pos - py * 40;
        bB[i] = n8 * 1600; bY[i] = py; bX[i] = px;
      } else { if (gr > Nn - 1) gr = Nn - 1; bO[i] = (long)gr * K; }
    }
  }

  ushort* lbase = (ushort*)S;
  for (int kc = 0; kc < K; kc += 64) {
    __syncthreads();
    int ch = kc >> 6;
    int cb = ch / 9, tap = ch - cb * 9;       // conv-K: cb-major, tap-minor
    int tdy = tap / 3 - 1, tdx = tap - (tap / 3) * 3 - 1;
    int kin = cb << 6;
    #pragma unroll
    for (int i = 0; i < 4; ++i) {
      int seg = wv * 2048 + i * 512;
      {
        const ushort* p; size_t go;
        if (aConv) {
          int yy = aY[i] + tdy, xx = aX[i] + tdx;
          bool v = ((unsigned)yy < 40u) && ((unsigned)xx < 40u);
          if (v) { go = (size_t)(aB[i] + yy * 40 + xx) * 768 + kin + cg8[i]; p = A; }
          else   { go = 0; p = zp; }
        } else { go = (size_t)(aO[i] + kc + cg8[i]); p = A; }
        __builtin_amdgcn_global_load_lds(p + go, lbase + seg, 16, 0, 0);
      }
      {
        const ushort* p; size_t go;
        if (bConv) {
          int yy = bY[i] + tdy, xx = bX[i] + tdx;
          bool v = ((unsigned)yy < 40u) && ((unsigned)xx < 40u);
          if (v) { go = (size_t)(bB[i] + yy * 40 + xx) * 768 + kin + cg8[i]; p = B; }
          else   { go = 0; p = zp; }
        } else { go = (size_t)(bO[i] + kc + cg8[i]); p = B; }
        __builtin_amdgcn_global_load_lds(p + go, lbase + 8192 + seg, 16, 0, 0);
      }
    }
    __syncthreads();
    #pragma unroll
    for (int kk = 0; kk < 2; ++kk) {
      int off = (((kk << 2) + qd) ^ (r & 7)) << 3;
      h8 af[4], bf[4];
      #pragma unroll
      for (int mt = 0; mt < 4; ++mt) {
        af[mt] = *(const h8*)&S[0][wm + mt * 16 + r][off];
        bf[mt] = *(const h8*)&S[1][wn + mt * 16 + r][off];
      }
      #pragma unroll
      for (int mt = 0; mt < 4; ++mt)
        #pragma unroll
        for (int nt = 0; nt < 4; ++nt)
          acc[mt][nt] = __builtin_amdgcn_mfma_f32_16x16x32_f16(af[mt], bf[nt], acc[mt][nt], 0, 0, 0);
    }
  }
  #pragma unroll
  for (int mt = 0; mt < 4; ++mt)
    #pragma unroll
    for (int nt = 0; nt < 4; ++nt) {
      int nn = n0 + wn + nt * 16 + r;
      if (nn >= Nn) continue;
      #pragma unroll
      for (int e = 0; e < 4; ++e) {
        int mm = m0 + wm + mt * 16 + qd * 4 + e;
        if (mm >= M) continue;
        float v = acc[mt][nt][e];
        if (mode == 0) {
          if (bias) v += bias[mm];
          int b2 = nn / nPer, nq = nn - b2 * nPer;
          Y[(size_t)bz * sYb + (size_t)b2 * sYb2 + (size_t)mm * sYm + nq] = v;
        } else if (mode == 1) {
          if (bias) v += bias[biasN ? nn : mm];
          Yh[(size_t)bz * sYpb + (size_t)mm * sYpm + nn + pOff] = f2h(v);
        } else if (mode == 2) {
          int gm = gRow0 + mm;
          int n8 = gm / 1600, q = gm - n8 * 1600;
          ushort h = f2h(v);
          if (nn < 256) {
            Yh[(size_t)n8 * 409600 + (size_t)q * 256 + nn] = h;
          } else {
            int qy = q / 40, qx = q - qy * 40;
            if (qy >= 1 && qy <= 38 && qx >= 1 && qx <= 38)
              Y2h[(size_t)n8 * 369664 + (size_t)((qy - 1) * 38 + qx - 1) * 256 + (nn - 256)] = h;
          }
        } else {   // mode 3
          int gn = gRow0 + nn;
          int n8 = gn / 1600, q = gn - n8 * 1600;
          int qy = q / 40, qx = q - qy * 40;
          if (qy >= 1 && qy <= 38 && qx >= 1 && qx <= 38)
            Yh[(size_t)n8 * 376832 + (size_t)mm * 1472 + (qy - 1) * 38 + qx - 1] = f2h(v);
        }
      }
    }
}

// generic fp32 -> fp16 conversion (strided read, contig write)
__global__ __launch_bounds__(256) void cvt_f16(
    const float* __restrict__ src, long s0, long s1, long sb,
    ushort* __restrict__ d, long d0, long db,
    int n0, int n1, int pad1, long total)
{
  long i = (long)blockIdx.x * 256 + threadIdx.x;
  if (i >= total) return;
  int wdt = n1 + pad1;
  int i1 = (int)(i % wdt); long rr = i / wdt;
  int i0 = (int)(rr % n0); int b = (int)(rr / n0);
  float f = 0.f;
  if (i1 < n1) f = src[(long)b * sb + (long)i0 * s0 + (long)i1 * s1];
  d[(long)b * db + (long)i0 * d0 + i1] = f2h(f);
}

// conv-K-layout weight reorder + fp16 convert; zero the zp page.
__global__ __launch_bounds__(256) void reorder_w(
    const float* __restrict__ wq, const float* __restrict__ wk,
    const float* __restrict__ wv,
    ushort* __restrict__ qk, ushort* __restrict__ v2, ushort* __restrict__ zp)
{
  int i = blockIdx.x * 256 + threadIdx.x;
  if (blockIdx.x == 0 && threadIdx.x < 64) zp[threadIdx.x] = 0;
  if (i >= 768 * 2304) return;
  int o = i / 2304, k = i - o * 2304;
  int cb = k / 576; int rem = k - cb * 576;
  int tap = rem >> 6, ci = rem & 63;
  int si = (cb * 64 + ci) * 9 + tap;
  float f; ushort* d; int oo;
  if (o < 256)      { f = wq[o * 2304 + si];         d = qk; oo = o; }
  else if (o < 512) { f = wk[(o - 256) * 2304 + si]; d = qk; oo = o; }
  else              { f = wv[(o - 512) * 2304 + si]; d = v2; oo = o - 512; }
  d[oo * 2304 + k] = f2h(f);
}

// zero the vxp pad columns 1444..1471
__global__ __launch_bounds__(256) void pad_vxp(ushort* __restrict__ vxp)
{
  int i = blockIdx.x * 256 + threadIdx.x;
  if (i >= 8 * 256 * 28) return;
  int j = i % 28; int rr = i / 28;
  int c = rr % 256; int n = rr / 256;
  vxp[(size_t)n * 376832 + (size_t)c * 1472 + 1444 + j] = 0;
}

// step-1 uniform-h class tables
__global__ __launch_bounds__(64) void uniform_kv_kern(
    const float* __restrict__ h0, const float* __restrict__ w_qh,
    const float* __restrict__ w_kh, const float* __restrict__ w_vh,
    float* __restrict__ qh1, float* __restrict__ kh1, float* __restrict__ vh1)
{
  int a = blockIdx.x, j = blockIdx.y, t = threadIdx.x;
  const float* wsel = (j < 9) ? w_qh : (j == 9) ? w_kh : w_vh;
  bool dyok0 = true, dyok2 = true, dxok0 = true, dxok2 = true;
  if (j < 9) {
    int uy = j / 3, ux = j - uy * 3;
    dyok0 = (uy != 0); dyok2 = (uy != 2);
    dxok0 = (ux != 0); dxok2 = (ux != 2);
  }
  float acc = 0.f;
  for (int c = t; c < 256; c += 64) {
    const float* wp = wsel + a * 2304 + c * 9;
    float s = 0.f;
    #pragma unroll
    for (int dy = 0; dy < 3; ++dy) {
      if ((dy == 0 && !dyok0) || (dy == 2 && !dyok2)) continue;
      #pragma unroll
      for (int dx = 0; dx < 3; ++dx) {
        if ((dx == 0 && !dxok0) || (dx == 2 && !dxok2)) continue;
        s += wp[dy * 3 + dx];
      }
    }
    acc += s * h0[c];
  }
  #pragma unroll
  for (int o = 32; o; o >>= 1) acc += __shfl_down(acc, o);
  if (t == 0) {
    if (j < 9) qh1[j * 256 + a] = acc;
    else if (j == 9) kh1[a] = acc;
    else vh1[a] = acc;
  }
}

// L0[n][u][d] = sum_c qh1[u][c] * k_x[n][d][c]  (kxT fp16)
__global__ __launch_bounds__(256) void l0_logits(
    const float* __restrict__ qh1, const ushort* __restrict__ kxT,
    float* __restrict__ L0)
{
  __shared__ float qs[2304];
  int db = blockIdx.x, n = blockIdx.y;
  for (int i = threadIdx.x; i < 2304; i += 256) qs[i] = qh1[i];
  __syncthreads();
  int d = db * 256 + threadIdx.x;
  bool act = d < 1444;
  const ushort* vp = kxT + (size_t)n * 369664 + (act ? (size_t)d * 256 : 0);
  float acc[9] = {0.f,0.f,0.f,0.f,0.f,0.f,0.f,0.f,0.f};
  for (int c8 = 0; c8 < 256; c8 += 8) {
    h8 v = *(const h8*)(const void*)(vp + c8);
    #pragma unroll
    for (int j = 0; j < 8; ++j) {
      float f = (float)v[j];
      #pragma unroll
      for (int u = 0; u < 9; ++u) acc[u] += qs[u * 256 + c8 + j] * f;
    }
  }
  if (act)
    for (int u = 0; u < 9; ++u) L0[n * 12996 + u * 1444 + d] = acc[u];
}

// fp32 in-place row softmax
__global__ __launch_bounds__(256) void softmax_rows(float* __restrict__ p, int L)
{
  float* rp = p + (long)blockIdx.x * L;
  int t = threadIdx.x;
  __shared__ float redm[4], reds[4];
  float mx = -3.4e38f;
  for (int i = t; i < L; i += 256) mx = fmaxf(mx, rp[i]);
  #pragma unroll
  for (int o = 32; o; o >>= 1) mx = fmaxf(mx, __shfl_down(mx, o));
  if ((t & 63) == 0) redm[t >> 6] = mx;
  __syncthreads();
  mx = fmaxf(fmaxf(redm[0], redm[1]), fmaxf(redm[2], redm[3]));
  float s = 0.f;
  for (int i = t; i < L; i += 256) { float v = expf(rp[i] - mx); rp[i] = v; s += v; }
  #pragma unroll
  for (int o = 32; o; o >>= 1) s += __shfl_down(s, o);
  if ((t & 63) == 0) reds[t >> 6] = s;
  __syncthreads();
  float inv = 1.f / (reds[0] + reds[1] + reds[2] + reds[3]);
  for (int i = t; i < L; i += 256) rp[i] *= inv;
}

// a10[n][u][p] = sum_d wt[n][u][d] * v[n][p][d]  (vxp fp16)
__global__ __launch_bounds__(256) void a10_pv(
    const float* __restrict__ L0, const ushort* __restrict__ vxp,
    float* __restrict__ a10)
{
  int u = blockIdx.x, n = blockIdx.y;
  __shared__ float wts[1472];
  const float* wrow = L0 + n * 12996 + u * 1444;
  for (int i = threadIdx.x; i < 1472; i += 256) wts[i] = (i < 1444) ? wrow[i] : 0.f;
  __syncthreads();
  int p = threadIdx.x;
  const ushort* vp = vxp + (size_t)n * 376832 + (size_t)p * 1472;
  float acc = 0.f;
  for (int d8 = 0; d8 < 1472; d8 += 8) {
    h8 v = *(const h8*)(const void*)(vp + d8);
    #pragma unroll
    for (int j = 0; j < 8; ++j) acc += wts[d8 + j] * (float)v[j];
  }
  a10[n * 2304 + u * 256 + p] = acc;
}

// AV[72][512] fp16: row (n*9+u), cols [a10(n,u,:) ; vh1]
__global__ __launch_bounds__(256) void build_AV(
    const float* __restrict__ a10, const float* __restrict__ vh1,
    ushort* __restrict__ AV)
{
  int i = blockIdx.x * 256 + threadIdx.x;
  if (i >= 72 * 512) return;
  int row = i >> 9, j = i & 511;
  int n = row / 9, u = row - n * 9;
  float f = (j < 256) ? a10[n * 2304 + u * 256 + j] : vh1[j - 256];
  AV[i] = f2h(f);
}

// gate tail: pre72[72][512] (+b_z/+b_h) -> h1[n][c][u] fp32
__global__ __launch_bounds__(256) void gate_ew2(
    const float* __restrict__ pre72, const float* __restrict__ b_z,
    const float* __restrict__ b_h, const float* __restrict__ h0,
    float* __restrict__ h1)
{
  int i = blockIdx.x * 256 + threadIdx.x;
  if (i >= 72 * 256) return;
  int row = i >> 8, c = i & 255;
  float z = 1.f / (1.f + expf(-(pre72[row * 512 + c] + b_z[c])));
  float hv = tanhf(pre72[row * 512 + 256 + c] + b_h[c]);
  int n = row / 9, u = row - n * 9;
  h1[n * 2304 + c * 9 + u] = z * h0[c] + (1.f - z) * hv;
}

// GA[72][2304] fp16: classed im2col of h1; k = c*9+tap (plain weight layout)
__global__ __launch_bounds__(256) void build_GA(
    const float* __restrict__ h1, ushort* __restrict__ GA)
{
  int i = blockIdx.x * 256 + threadIdx.x;
  if (i >= 72 * 2304) return;
  int row = i / 2304, k = i - row * 2304;
  int c = k / 9, tap = k - c * 9;
  int u = row % 9;
  int ty = u / 3, tx = u - ty * 3;
  int dy = tap / 3, dx = tap - dy * 3;
  int uy = (ty == 0) ? (dy == 0 ? 0 : 1) : (ty == 2) ? (dy == 2 ? 2 : 1) : 1;
  int ux = (tx == 0) ? (dx == 0 ? 0 : 1) : (tx == 2) ? (dx == 2 ? 2 : 1) : 1;
  GA[i] = f2h(h1[(row / 9) * 2304 + c * 9 + uy * 3 + ux]);
}

// softmax over 1444 fp32 logits (row stride 1472) -> fp16 rows (1472, padded)
__global__ __launch_bounds__(256) void softmax_f16(
    const float* __restrict__ p, ushort* __restrict__ wt)
{
  long row = blockIdx.x;
  const float* rp = p + row * 1472;
  ushort* op = wt + row * 1472;
  int t = threadIdx.x;
  __shared__ float buf[1444];
  __shared__ float redm[4], reds[4];
  float mx = -3.4e38f;
  for (int i = t; i < 1444; i += 256) { float v = rp[i]; buf[i] = v; mx = fmaxf(mx, v); }
  #pragma unroll
  for (int o = 32; o; o >>= 1) mx = fmaxf(mx, __shfl_down(mx, o));
  if ((t & 63) == 0) redm[t >> 6] = mx;
  __syncthreads();
  mx = fmaxf(fmaxf(redm[0], redm[1]), fmaxf(redm[2], redm[3]));
  float s = 0.f;
  for (int i = t; i < 1444; i += 256) { float v = expf(buf[i] - mx); buf[i] = v; s += v; }
  #pragma unroll
  for (int o = 32; o; o >>= 1) s += __shfl_down(s, o);
  if ((t & 63) == 0) reds[t >> 6] = s;
  __syncthreads();
  float inv = 1.f / (reds[0] + reds[1] + reds[2] + reds[3]);
  for (int i = t; i < 1472; i += 256)
    op[i] = f2h((i < 1444) ? buf[i] * inv : 0.f);
}

// step-2 (a=0,b=1) classed attention; khvc[72][512] layout (k | v per class)
__global__ __launch_bounds__(256) void attn_b1(
    const ushort* __restrict__ qT, const float* __restrict__ khvc,
    ushort* __restrict__ xaT)
{
  __shared__ float ks[2304];   // [tt*256 + c]
  __shared__ float vs[2304];
  __shared__ float es[256][10];
  int n = blockIdx.y;
  int q0 = blockIdx.x * 256;
  for (int i = threadIdx.x; i < 2304; i += 256) {
    int tt = i >> 8, c = i & 255;
    const float* kp = khvc + (size_t)(n * 9 + tt) * 512;
    ks[i] = kp[c];
    vs[i] = kp[256 + c];
  }
  __syncthreads();
  int q = q0 + threadIdx.x;
  bool act = (q < 1600);
  float Lg[9] = {0.f,0.f,0.f,0.f,0.f,0.f,0.f,0.f,0.f};
  const ushort* qp = qT + (size_t)n * 409600 + (act ? (size_t)q * 256 : 0);
  for (int c8 = 0; c8 < 256; c8 += 8) {
    h8 v = *(const h8*)(const void*)(qp + c8);
    #pragma unroll
    for (int j = 0; j < 8; ++j) {
      float f = (float)v[j];
      #pragma unroll
      for (int tt = 0; tt < 9; ++tt) Lg[tt] += f * ks[tt * 256 + c8 + j];
    }
  }
  float mx = Lg[0];
  #pragma unroll
  for (int tt = 1; tt < 9; ++tt) mx = fmaxf(mx, Lg[tt]);
  float Z = 0.f;
  float e[9];
  #pragma unroll
  for (int tt = 0; tt < 9; ++tt) {
    float m = ((tt / 3) == 1 ? 36.f : 1.f) * ((tt % 3) == 1 ? 36.f : 1.f);
    e[tt] = act ? m * expf(Lg[tt] - mx) : 0.f;
    Z += e[tt];
  }
  float inv = act ? (1.f / Z) : 0.f;
  #pragma unroll
  for (int tt = 0; tt < 9; ++tt) es[threadIdx.x][tt] = e[tt] * inv;
  __syncthreads();
  int nact = 1600 - q0; if (nact > 256) nact = 256;
  int p = threadIdx.x;
  for (int qq = 0; qq < nact; ++qq) {
    float s = 0.f;
    #pragma unroll
    for (int tt = 0; tt < 9; ++tt) s += es[qq][tt] * vs[tt * 256 + p];
    xaT[(size_t)n * 1228800 + (size_t)(q0 + qq) * 768 + 512 + p] = f2h(s);
  }
}

// ---------------------------------------------------------------------------
extern "C" void kernel_launch(void* const* d_in, const int* in_sizes, int n_in,
                              void* d_out, int out_size, void* d_ws, size_t ws_size,
                              hipStream_t stream)
{
  const float* x     = (const float*)d_in[0];
  const float* h0    = (const float*)d_in[1];
  const float* w_px  = (const float*)d_in[2];
  const float* b_px  = (const float*)d_in[3];
  const float* w_qx  = (const float*)d_in[4];
  const float* w_qh  = (const float*)d_in[5];
  const float* w_kx  = (const float*)d_in[6];
  const float* w_kh  = (const float*)d_in[7];
  const float* w_vx  = (const float*)d_in[8];
  const float* w_vh  = (const float*)d_in[9];
  const float* w_z   = (const float*)d_in[10];
  const float* b_z   = (const float*)d_in[11];
  const float* w_h   = (const float*)d_in[12];
  const float* b_h   = (const float*)d_in[13];
  const float* w_out = (const float*)d_in[14];
  const float* b_out = (const float*)d_in[15];
  float* out = (float*)d_out;

  char* base = (char*)d_ws;
  size_t off = 0;
  auto alloc = [&](size_t bytes) -> char* {
    off = (off + 255) & ~(size_t)255;
    char* p = base + off; off += bytes; return p;
  };
  ushort* xaT  = (ushort*)alloc(19660800);          // [8][1600][768] fp16
  ushort* qT   = (ushort*)alloc(6553600);           // [8][1600][256]
  ushort* kxT  = (ushort*)alloc(5914624);           // [8][1444][256]
  ushort* vxp  = (ushort*)alloc(6029312);           // [8][256][1472]
  ushort* xT   = (ushort*)alloc(3276800);           // [12800][128]
  ushort* Wqk  = (ushort*)alloc(2359296);           // [512][2304] conv-K order
  ushort* Wv   = (ushort*)alloc(1179648);           // [256][2304] conv-K order
  ushort* Wkv  = (ushort*)alloc(2359296);           // [512][2304] plain: w_kh|w_vh
  ushort* Wzh  = (ushort*)alloc(524288);            // [512][512]: w_z|w_h
  ushort* wpx  = (ushort*)alloc(65536);             // [256][128]
  ushort* wout = (ushort*)alloc(393216);            // [256][768]
  ushort* zp   = (ushort*)alloc(128);               // 64-ushort zero page
  ushort* GA   = (ushort*)alloc(331776);            // [72][2304] fp16
  ushort* AV   = (ushort*)alloc(73728);             // [72][512] fp16
  float*  pre72= (float*)alloc(147456);             // [72][512]
  float*  khvc = (float*)alloc(147456);             // [72][512]
  float*  qh1  = (float*)alloc(9216);
  float*  kh1  = (float*)alloc(1024);
  float*  vh1  = (float*)alloc(1024);
  float*  L0   = (float*)alloc(415872);             // [8][9][1444]
  float*  a10  = (float*)alloc(73728);
  float*  h1   = (float*)alloc(73728);
  off = (off + 255) & ~(size_t)255;
  char* chunk = base + off;
  long avail = (long)ws_size - (long)off;
  if (avail < 0) avail = 0;
  int an = (int)(avail / 14131200L); if (an < 1) an = 1; if (an > 8) an = 8;

  auto mg = [&](dim3 grid,
                const ushort* A, long sAb, const ushort* B, long sBb,
                int M, int Nn, int K, int mode, int gRow0, int swap,
                int aConv, int bConv,
                float* Y, long sYb, long sYm, int nPer, long sYb2,
                const float* bias, int biasN,
                ushort* Yh, long sYpb, long sYpm, long pOff, ushort* Y2h) {
    mgemm<<<grid, dim3(256), 0, stream>>>(A, sAb, B, sBb,
        M, Nn, K, mode, gRow0, swap, aConv, bConv, zp,
        Y, sYb, sYm, nPer, sYb2, bias, biasN, Yh, sYpb, sYpm, pOff, Y2h);
  };
  const int BIG = 0x40000000;

  // ---- 1) weight/input conversions (fp16 single-plane) ----
  cvt_f16<<<dim3(6400), dim3(256), 0, stream>>>(x, 1, 1600, 204800, xT, 128, 204800, 1600, 128, 0, 1638400);
  reorder_w<<<dim3(6912), dim3(256), 0, stream>>>(w_qx, w_kx, w_vx, Wqk, Wv, zp);
  cvt_f16<<<dim3(128), dim3(256), 0, stream>>>(w_px, 128, 1, 0, wpx, 128, 0, 256, 128, 0, 32768);
  cvt_f16<<<dim3(768), dim3(256), 0, stream>>>(w_out, 768, 1, 0, wout, 768, 0, 256, 768, 0, 196608);
  cvt_f16<<<dim3(2304), dim3(256), 0, stream>>>(w_kh, 2304, 1, 0, Wkv, 2304, 0, 256, 2304, 0, 589824);
  cvt_f16<<<dim3(2304), dim3(256), 0, stream>>>(w_vh, 2304, 1, 0, Wkv + 589824, 2304, 0, 256, 2304, 0, 589824);
  cvt_f16<<<dim3(512), dim3(256), 0, stream>>>(w_z, 512, 1, 0, Wzh, 512, 0, 256, 512, 0, 131072);
  cvt_f16<<<dim3(512), dim3(256), 0, stream>>>(w_h, 512, 1, 0, Wzh + 131072, 512, 0, 256, 512, 0, 131072);

  // ---- 2) xp-conv: A=xT[12800][128], B=wpx -> xaT cols 0..255 ----
  mg(dim3(2, 100, 1), xT, 0, wpx, 0,
     12800, 256, 128, 1, 0, 1, 0, 0,
     nullptr, 0, 0, 0, 0, b_px, 1,
     xaT, 0, 768, 0, nullptr);

  // ---- 3) direct shifted-tap convs (conv-K order) ----
  mg(dim3(4, 100, 1), xaT, 0, Wqk, 0,
     12800, 512, 2304, 2, 0, 1, 1, 0,
     nullptr, 0, 0, 0, 0, nullptr, 0,
     qT, 0, 0, 0, kxT);
  mg(dim3(2, 100, 1), Wv, 0, xaT, 0,
     256, 12800, 2304, 3, 0, 0, 0, 1,
     nullptr, 0, 0, 0, 0, nullptr, 0,
     vxp, 0, 0, 0, nullptr);
  pad_vxp<<<dim3(224), dim3(256), 0, stream>>>(vxp);

  // ---- 4) classed section (matvecs as 72-row MFMA GEMMs) ----
  uniform_kv_kern<<<dim3(256, 11), dim3(64), 0, stream>>>(h0, w_qh, w_kh, w_vh, qh1, kh1, vh1);
  l0_logits<<<dim3(6, 8), dim3(256), 0, stream>>>(qh1, kxT, L0);
  softmax_rows<<<dim3(72), dim3(256), 0, stream>>>(L0, 1444);
  a10_pv<<<dim3(9, 8), dim3(256), 0, stream>>>(L0, vxp, a10);
  build_AV<<<dim3(144), dim3(256), 0, stream>>>(a10, vh1, AV);
  mg(dim3(1, 4, 1), AV, 0, Wzh, 0,
     72, 512, 512, 0, 0, 0, 0, 0,
     pre72, 0, 512, BIG, 0, nullptr, 0,
     nullptr, 0, 0, 0, nullptr);
  gate_ew2<<<dim3(72), dim3(256), 0, stream>>>(pre72, b_z, b_h, h0, h1);
  build_GA<<<dim3(648), dim3(256), 0, stream>>>(h1, GA);
  mg(dim3(1, 4, 1), GA, 0, Wkv, 0,
     72, 512, 2304, 0, 0, 0, 0, 0,
     khvc, 0, 512, BIG, 0, nullptr, 0,
     nullptr, 0, 0, 0, nullptr);
  attn_b1<<<dim3(7, 8), dim3(256), 0, stream>>>(qT, khvc, xaT);

  // ---- 5) step-2 (0,0) full attention ----
  {
    float* scL = (float*)chunk;
    for (int nb0 = 0; nb0 < 8; nb0 += an) {
      int c = (8 - nb0 < an) ? (8 - nb0) : an;
      ushort* wt = (ushort*)(chunk + (long)c * 9420800);
      mg(dim3(13, 12, c), qT + (long)nb0 * 409600, 409600,
         kxT + (long)nb0 * 369664, 369664,
         1600, 1444, 256, 0, 0, 0, 0, 0,
         scL, 2355200, 1472, BIG, 0, nullptr, 0,
         nullptr, 0, 0, 0, nullptr);
      softmax_f16<<<dim3(c * 1600), dim3(256), 0, stream>>>(scL, wt);
      mg(dim3(13, 2, c), wt, 2355200,
         vxp + (long)nb0 * 376832, 376832,
         1600, 256, 1472, 1, 0, 0, 0, 0,
         nullptr, 0, 0, 0, 0, nullptr, 0,
         xaT + (long)nb0 * 1228800, 1228800, 768, 256, nullptr);
    }
  }

  // ---- 6) out-conv: A=wout[256][768], B=xaT rows -> fp32 NCHW ----
  mg(dim3(2, 100, 1), wout, 0, xaT, 0,
     256, 12800, 768, 0, 0, 0, 0, 0,
     out, 0, 1600, 1600, 409600, b_out, 0,
     nullptr, 0, 0, 0, nullptr);
}

// Round 10
// 531.675 us; speedup vs baseline: 2.6677x; 1.1195x over previous
//
#include <hip/hip_runtime.h>
#include <math.h>

// ---------------------------------------------------------------------------
// 2-step recurrent attention cell, N=8, I=128, C=Hc=A=P=O=256, H=W=40
// (Q=1600), VALID 3x3 -> 38x38 (D=1444). fp32 reference.
//
// R0-R2: exact algebraic reductions. R3-R7: MFMA GEMMs, DMA staging + XOR
// swizzle, direct shifted-tap conv, conv-K channel-block order.
// R8: single-plane fp16 (staged bytes /2, MFMA /3).
// R9: classed matvecs as 72-row MFMA GEMMs.
// R10: long-tail cleanup -- (1) 8 prep kernels merged into one range-dispatch
// kernel; (2) classed GEMMs K-sliced across blockIdx.z (serial chunk chains
// 36->6) with partial-sum tails folded into gate_ew2/attn_b1; (3) (0,0)
// logits written fp16 (halves the scL round-trip).
// ---------------------------------------------------------------------------

typedef _Float16 f16;
typedef _Float16 h8 __attribute__((ext_vector_type(8)));   // 8 fp16 (4 VGPRs)
typedef __attribute__((ext_vector_type(4))) float f4;

__device__ __forceinline__ ushort f2h(float f) {
  union { f16 h; ushort u; } cv; cv.h = (f16)f; return cv.u;
}
__device__ __forceinline__ float h2f(ushort u) {
  union { ushort u; f16 h; } cv; cv.u = u; return (float)cv.h;
}

// ---------------- MFMA fp16 GEMM, 128x128 tile ----------------
// C[m][n] = sum_k A[m][k]*B[n][k], k-contig fp16, K % 64 == 0.
// Krow = full row stride (elements); K = slice length staged by this launch
// (K-slicing: bz indexes a K-slice via sAb/sBb offsets, partial outputs).
// KB=64 chunks, global_load_lds 16B staging, XOR swizzle (conflict-free).
// aConv/bConv: rows are image positions (8x40x40), row stride 768 (xaT);
// conv K layout: k = cb*576 + tap*64 + ci (chunk-uniform tap shift);
// border-invalid rows read the zero page zp.
// Epilogue modes: 0 fp32 / 1 fp16 / 2 qk-split(qT,kxT) / 3 v-crop(vxp).
__global__ __launch_bounds__(256) void mgemm(
    const ushort* __restrict__ A, long sAb,
    const ushort* __restrict__ B, long sBb,
    int M, int Nn, int K, int Krow, int mode, int gRow0, int swap,
    int aConv, int bConv,
    const ushort* __restrict__ zp,
    float* __restrict__ Y, long sYb, long sYm, int nPer, long sYb2,
    const float* __restrict__ bias, int biasN,
    ushort* __restrict__ Yh, long sYpb, long sYpm, long pOff,
    ushort* __restrict__ Y2h)
{
  __shared__ ushort S[2][128][64];   // A plane, B plane ; 32 KB
  const int bz = blockIdx.z;
  A += (long)bz * sAb;
  B += (long)bz * sBb;
  const int mb = swap ? blockIdx.y : blockIdx.x;
  const int nb = swap ? blockIdx.x : blockIdx.y;
  const int m0 = mb * 128, n0 = nb * 128;
  const int t = threadIdx.x;
  const int lane = t & 63, wv = t >> 6;
  const int r = lane & 15, qd = lane >> 4;
  const int wm = (wv & 1) * 64, wn = (wv >> 1) * 64;
  const int lrow = lane >> 3, lch = lane & 7;
  f4 acc[4][4];
  #pragma unroll
  for (int i = 0; i < 4; ++i)
    #pragma unroll
    for (int j = 0; j < 4; ++j) acc[i][j] = (f4){0.f, 0.f, 0.f, 0.f};

  int cg8[4];
  int aB[4], aY[4], aX[4]; long aO[4];
  int bB[4], bY[4], bX[4]; long bO[4];
  #pragma unroll
  for (int i = 0; i < 4; ++i) {
    int row = wv * 32 + i * 8 + lrow;
    cg8[i] = (lch ^ (row & 7)) * 8;
    {
      int gr = m0 + row;
      if (aConv) {
        int n8 = gr / 1600, pos = gr - n8 * 1600;
        int py = pos / 40, px = pos - py * 40;
        aB[i] = n8 * 1600; aY[i] = py; aX[i] = px;
      } else { if (gr > M - 1) gr = M - 1; aO[i] = (long)gr * Krow; }
    }
    {
      int gr = n0 + row;
      if (bConv) {
        int n8 = gr / 1600, pos = gr - n8 * 1600;
        int py = pos / 40, px = pos - py * 40;
        bB[i] = n8 * 1600; bY[i] = py; bX[i] = px;
      } else { if (gr > Nn - 1) gr = Nn - 1; bO[i] = (long)gr * Krow; }
    }
  }

  ushort* lbase = (ushort*)S;
  for (int kc = 0; kc < K; kc += 64) {
    __syncthreads();
    int ch = kc >> 6;
    int cb = ch / 9, tap = ch - cb * 9;       // conv-K: cb-major, tap-minor
    int tdy = tap / 3 - 1, tdx = tap - (tap / 3) * 3 - 1;
    int kin = cb << 6;
    #pragma unroll
    for (int i = 0; i < 4; ++i) {
      int seg = wv * 2048 + i * 512;
      {
        const ushort* p; size_t go;
        if (aConv) {
          int yy = aY[i] + tdy, xx = aX[i] + tdx;
          bool v = ((unsigned)yy < 40u) && ((unsigned)xx < 40u);
          if (v) { go = (size_t)(aB[i] + yy * 40 + xx) * 768 + kin + cg8[i]; p = A; }
          else   { go = 0; p = zp; }
        } else { go = (size_t)(aO[i] + kc + cg8[i]); p = A; }
        __builtin_amdgcn_global_load_lds(p + go, lbase + seg, 16, 0, 0);
      }
      {
        const ushort* p; size_t go;
        if (bConv) {
          int yy = bY[i] + tdy, xx = bX[i] + tdx;
          bool v = ((unsigned)yy < 40u) && ((unsigned)xx < 40u);
          if (v) { go = (size_t)(bB[i] + yy * 40 + xx) * 768 + kin + cg8[i]; p = B; }
          else   { go = 0; p = zp; }
        } else { go = (size_t)(bO[i] + kc + cg8[i]); p = B; }
        __builtin_amdgcn_global_load_lds(p + go, lbase + 8192 + seg, 16, 0, 0);
      }
    }
    __syncthreads();
    #pragma unroll
    for (int kk = 0; kk < 2; ++kk) {
      int off = (((kk << 2) + qd) ^ (r & 7)) << 3;
      h8 af[4], bf[4];
      #pragma unroll
      for (int mt = 0; mt < 4; ++mt) {
        af[mt] = *(const h8*)&S[0][wm + mt * 16 + r][off];
        bf[mt] = *(const h8*)&S[1][wn + mt * 16 + r][off];
      }
      #pragma unroll
      for (int mt = 0; mt < 4; ++mt)
        #pragma unroll
        for (int nt = 0; nt < 4; ++nt)
          acc[mt][nt] = __builtin_amdgcn_mfma_f32_16x16x32_f16(af[mt], bf[nt], acc[mt][nt], 0, 0, 0);
    }
  }
  #pragma unroll
  for (int mt = 0; mt < 4; ++mt)
    #pragma unroll
    for (int nt = 0; nt < 4; ++nt) {
      int nn = n0 + wn + nt * 16 + r;
      if (nn >= Nn) continue;
      #pragma unroll
      for (int e = 0; e < 4; ++e) {
        int mm = m0 + wm + mt * 16 + qd * 4 + e;
        if (mm >= M) continue;
        float v = acc[mt][nt][e];
        if (mode == 0) {
          if (bias) v += bias[mm];
          int b2 = nn / nPer, nq = nn - b2 * nPer;
          Y[(size_t)bz * sYb + (size_t)b2 * sYb2 + (size_t)mm * sYm + nq] = v;
        } else if (mode == 1) {
          if (bias) v += bias[biasN ? nn : mm];
          Yh[(size_t)bz * sYpb + (size_t)mm * sYpm + nn + pOff] = f2h(v);
        } else if (mode == 2) {
          int gm = gRow0 + mm;
          int n8 = gm / 1600, q = gm - n8 * 1600;
          ushort h = f2h(v);
          if (nn < 256) {
            Yh[(size_t)n8 * 409600 + (size_t)q * 256 + nn] = h;
          } else {
            int qy = q / 40, qx = q - qy * 40;
            if (qy >= 1 && qy <= 38 && qx >= 1 && qx <= 38)
              Y2h[(size_t)n8 * 369664 + (size_t)((qy - 1) * 38 + qx - 1) * 256 + (nn - 256)] = h;
          }
        } else {   // mode 3
          int gn = gRow0 + nn;
          int n8 = gn / 1600, q = gn - n8 * 1600;
          int qy = q / 40, qx = q - qy * 40;
          if (qy >= 1 && qy <= 38 && qx >= 1 && qx <= 38)
            Yh[(size_t)n8 * 376832 + (size_t)mm * 1472 + (qy - 1) * 38 + qx - 1] = f2h(v);
        }
      }
    }
}

// ---------------- fused prep: all weight/input conversions + pads ----------
// range-dispatched single kernel (replaces 8 small launches)
__global__ __launch_bounds__(256) void prep_all(
    const float* __restrict__ x,
    const float* __restrict__ w_qx, const float* __restrict__ w_kx,
    const float* __restrict__ w_vx,
    const float* __restrict__ w_px, const float* __restrict__ w_out,
    const float* __restrict__ w_kh, const float* __restrict__ w_vh,
    const float* __restrict__ w_z, const float* __restrict__ w_h,
    ushort* __restrict__ xT, ushort* __restrict__ Wqk, ushort* __restrict__ Wv,
    ushort* __restrict__ wpx, ushort* __restrict__ wout,
    ushort* __restrict__ Wkv, ushort* __restrict__ Wzh,
    ushort* __restrict__ zp, ushort* __restrict__ vxp)
{
  long gi = (long)blockIdx.x * 256 + threadIdx.x;
  if (gi < 64) zp[gi] = 0;
  long i = gi;
  if (i < 1638400) {                         // xT [12800][128] transpose-cvt
    int i1 = (int)(i & 127); long r = i >> 7;
    int q = (int)(r % 1600); int n8 = (int)(r / 1600);
    xT[i] = f2h(x[(long)n8 * 204800 + (long)i1 * 1600 + q]);
    return;
  }
  i -= 1638400;
  if (i < 1769472) {                         // Wqk/Wv conv-K reorder
    int o = (int)(i / 2304), k = (int)(i - (long)o * 2304);
    int cb = k / 576, rem = k - cb * 576;
    int tap = rem >> 6, ci = rem & 63;
    int si = (cb * 64 + ci) * 9 + tap;
    float f; ushort* d; int oo;
    if (o < 256)      { f = w_qx[o * 2304 + si];         d = Wqk; oo = o; }
    else if (o < 512) { f = w_kx[(o - 256) * 2304 + si]; d = Wqk; oo = o; }
    else              { f = w_vx[(o - 512) * 2304 + si]; d = Wv;  oo = o - 512; }
    d[oo * 2304 + k] = f2h(f);
    return;
  }
  i -= 1769472;
  if (i < 32768)  { wpx[i]  = f2h(w_px[i]);  return; }
  i -= 32768;
  if (i < 196608) { wout[i] = f2h(w_out[i]); return; }
  i -= 196608;
  if (i < 1179648) { Wkv[i] = f2h(i < 589824 ? w_kh[i] : w_vh[i - 589824]); return; }
  i -= 1179648;
  if (i < 262144)  { Wzh[i] = f2h(i < 131072 ? w_z[i] : w_h[i - 131072]); return; }
  i -= 262144;
  if (i < 57344) {                           // vxp pad cols 1444..1471
    int j = (int)(i % 28); int rr = (int)(i / 28);
    int c = rr % 256, n = rr / 256;
    vxp[(size_t)n * 376832 + (size_t)c * 1472 + 1444 + j] = 0;
  }
}

// step-1 uniform-h class tables
__global__ __launch_bounds__(64) void uniform_kv_kern(
    const float* __restrict__ h0, const float* __restrict__ w_qh,
    const float* __restrict__ w_kh, const float* __restrict__ w_vh,
    float* __restrict__ qh1, float* __restrict__ kh1, float* __restrict__ vh1)
{
  int a = blockIdx.x, j = blockIdx.y, t = threadIdx.x;
  const float* wsel = (j < 9) ? w_qh : (j == 9) ? w_kh : w_vh;
  bool dyok0 = true, dyok2 = true, dxok0 = true, dxok2 = true;
  if (j < 9) {
    int uy = j / 3, ux = j - uy * 3;
    dyok0 = (uy != 0); dyok2 = (uy != 2);
    dxok0 = (ux != 0); dxok2 = (ux != 2);
  }
  float acc = 0.f;
  for (int c = t; c < 256; c += 64) {
    const float* wp = wsel + a * 2304 + c * 9;
    float s = 0.f;
    #pragma unroll
    for (int dy = 0; dy < 3; ++dy) {
      if ((dy == 0 && !dyok0) || (dy == 2 && !dyok2)) continue;
      #pragma unroll
      for (int dx = 0; dx < 3; ++dx) {
        if ((dx == 0 && !dxok0) || (dx == 2 && !dxok2)) continue;
        s += wp[dy * 3 + dx];
      }
    }
    acc += s * h0[c];
  }
  #pragma unroll
  for (int o = 32; o; o >>= 1) acc += __shfl_down(acc, o);
  if (t == 0) {
    if (j < 9) qh1[j * 256 + a] = acc;
    else if (j == 9) kh1[a] = acc;
    else vh1[a] = acc;
  }
}

// L0[n][u][d] = sum_c qh1[u][c] * k_x[n][d][c]  (kxT fp16)
__global__ __launch_bounds__(256) void l0_logits(
    const float* __restrict__ qh1, const ushort* __restrict__ kxT,
    float* __restrict__ L0)
{
  __shared__ float qs[2304];
  int db = blockIdx.x, n = blockIdx.y;
  for (int i = threadIdx.x; i < 2304; i += 256) qs[i] = qh1[i];
  __syncthreads();
  int d = db * 256 + threadIdx.x;
  bool act = d < 1444;
  const ushort* vp = kxT + (size_t)n * 369664 + (act ? (size_t)d * 256 : 0);
  float acc[9] = {0.f,0.f,0.f,0.f,0.f,0.f,0.f,0.f,0.f};
  for (int c8 = 0; c8 < 256; c8 += 8) {
    h8 v = *(const h8*)(const void*)(vp + c8);
    #pragma unroll
    for (int j = 0; j < 8; ++j) {
      float f = (float)v[j];
      #pragma unroll
      for (int u = 0; u < 9; ++u) acc[u] += qs[u * 256 + c8 + j] * f;
    }
  }
  if (act)
    for (int u = 0; u < 9; ++u) L0[n * 12996 + u * 1444 + d] = acc[u];
}

// fp32 in-place row softmax
__global__ __launch_bounds__(256) void softmax_rows(float* __restrict__ p, int L)
{
  float* rp = p + (long)blockIdx.x * L;
  int t = threadIdx.x;
  __shared__ float redm[4], reds[4];
  float mx = -3.4e38f;
  for (int i = t; i < L; i += 256) mx = fmaxf(mx, rp[i]);
  #pragma unroll
  for (int o = 32; o; o >>= 1) mx = fmaxf(mx, __shfl_down(mx, o));
  if ((t & 63) == 0) redm[t >> 6] = mx;
  __syncthreads();
  mx = fmaxf(fmaxf(redm[0], redm[1]), fmaxf(redm[2], redm[3]));
  float s = 0.f;
  for (int i = t; i < L; i += 256) { float v = expf(rp[i] - mx); rp[i] = v; s += v; }
  #pragma unroll
  for (int o = 32; o; o >>= 1) s += __shfl_down(s, o);
  if ((t & 63) == 0) reds[t >> 6] = s;
  __syncthreads();
  float inv = 1.f / (reds[0] + reds[1] + reds[2] + reds[3]);
  for (int i = t; i < L; i += 256) rp[i] *= inv;
}

// a10[n][u][p] = sum_d wt[n][u][d] * v[n][p][d]  (vxp fp16)
__global__ __launch_bounds__(256) void a10_pv(
    const float* __restrict__ L0, const ushort* __restrict__ vxp,
    float* __restrict__ a10)
{
  int u = blockIdx.x, n = blockIdx.y;
  __shared__ float wts[1472];
  const float* wrow = L0 + n * 12996 + u * 1444;
  for (int i = threadIdx.x; i < 1472; i += 256) wts[i] = (i < 1444) ? wrow[i] : 0.f;
  __syncthreads();
  int p = threadIdx.x;
  const ushort* vp = vxp + (size_t)n * 376832 + (size_t)p * 1472;
  float acc = 0.f;
  for (int d8 = 0; d8 < 1472; d8 += 8) {
    h8 v = *(const h8*)(const void*)(vp + d8);
    #pragma unroll
    for (int j = 0; j < 8; ++j) acc += wts[d8 + j] * (float)v[j];
  }
  a10[n * 2304 + u * 256 + p] = acc;
}

// AV[72][512] fp16: row (n*9+u), cols [a10(n,u,:) ; vh1]
__global__ __launch_bounds__(256) void build_AV(
    const float* __restrict__ a10, const float* __restrict__ vh1,
    ushort* __restrict__ AV)
{
  int i = blockIdx.x * 256 + threadIdx.x;
  if (i >= 72 * 512) return;
  int row = i >> 9, j = i & 511;
  int n = row / 9, u = row - n * 9;
  float f = (j < 256) ? a10[n * 2304 + u * 256 + j] : vh1[j - 256];
  AV[i] = f2h(f);
}

// gate tail: sum 4 K-slice partials pre72p[4][72][512], bias, GRU blend
__global__ __launch_bounds__(256) void gate_ew2(
    const float* __restrict__ pre72p, const float* __restrict__ b_z,
    const float* __restrict__ b_h, const float* __restrict__ h0,
    float* __restrict__ h1)
{
  int i = blockIdx.x * 256 + threadIdx.x;
  if (i >= 72 * 256) return;
  int row = i >> 8, c = i & 255;
  float zs = 0.f, hs = 0.f;
  #pragma unroll
  for (int s = 0; s < 4; ++s) {
    zs += pre72p[s * 36864 + row * 512 + c];
    hs += pre72p[s * 36864 + row * 512 + 256 + c];
  }
  float z = 1.f / (1.f + expf(-(zs + b_z[c])));
  float hv = tanhf(hs + b_h[c]);
  int n = row / 9, u = row - n * 9;
  h1[n * 2304 + c * 9 + u] = z * h0[c] + (1.f - z) * hv;
}

// GA[72][2304] fp16: classed im2col of h1; k = c*9+tap (plain weight layout)
__global__ __launch_bounds__(256) void build_GA(
    const float* __restrict__ h1, ushort* __restrict__ GA)
{
  int i = blockIdx.x * 256 + threadIdx.x;
  if (i >= 72 * 2304) return;
  int row = i / 2304, k = i - row * 2304;
  int c = k / 9, tap = k - c * 9;
  int u = row % 9;
  int ty = u / 3, tx = u - ty * 3;
  int dy = tap / 3, dx = tap - dy * 3;
  int uy = (ty == 0) ? (dy == 0 ? 0 : 1) : (ty == 2) ? (dy == 2 ? 2 : 1) : 1;
  int ux = (tx == 0) ? (dx == 0 ? 0 : 1) : (tx == 2) ? (dx == 2 ? 2 : 1) : 1;
  GA[i] = f2h(h1[(row / 9) * 2304 + c * 9 + uy * 3 + ux]);
}

// softmax over 1444 fp16 logits (row stride 1472) -> fp16 rows (1472, padded)
__global__ __launch_bounds__(256) void softmax_h16(
    const ushort* __restrict__ p, ushort* __restrict__ wt)
{
  long row = blockIdx.x;
  const ushort* rp = p + row * 1472;
  ushort* op = wt + row * 1472;
  int t = threadIdx.x;
  __shared__ float buf[1444];
  __shared__ float redm[4], reds[4];
  float mx = -3.4e38f;
  for (int i = t; i < 1444; i += 256) { float v = h2f(rp[i]); buf[i] = v; mx = fmaxf(mx, v); }
  #pragma unroll
  for (int o = 32; o; o >>= 1) mx = fmaxf(mx, __shfl_down(mx, o));
  if ((t & 63) == 0) redm[t >> 6] = mx;
  __syncthreads();
  mx = fmaxf(fmaxf(redm[0], redm[1]), fmaxf(redm[2], redm[3]));
  float s = 0.f;
  for (int i = t; i < 1444; i += 256) { float v = expf(buf[i] - mx); buf[i] = v; s += v; }
  #pragma unroll
  for (int o = 32; o; o >>= 1) s += __shfl_down(s, o);
  if ((t & 63) == 0) reds[t >> 6] = s;
  __syncthreads();
  float inv = 1.f / (reds[0] + reds[1] + reds[2] + reds[3]);
  for (int i = t; i < 1472; i += 256)
    op[i] = f2h((i < 1444) ? buf[i] * inv : 0.f);
}

// step-2 (a=0,b=1) classed attention; sums 6 khvc K-slice partials
__global__ __launch_bounds__(256) void attn_b1(
    const ushort* __restrict__ qT, const float* __restrict__ khvcp,
    ushort* __restrict__ xaT)
{
  __shared__ float ks[2304];   // [tt*256 + c]
  __shared__ float vs[2304];
  __shared__ float es[256][10];
  int n = blockIdx.y;
  int q0 = blockIdx.x * 256;
  for (int i = threadIdx.x; i < 2304; i += 256) {
    int tt = i >> 8, c = i & 255;
    size_t base = (size_t)(n * 9 + tt) * 512;
    float sk = 0.f, sv = 0.f;
    #pragma unroll
    for (int s = 0; s < 6; ++s) {
      sk += khvcp[s * 36864 + base + c];
      sv += khvcp[s * 36864 + base + 256 + c];
    }
    ks[i] = sk; vs[i] = sv;
  }
  __syncthreads();
  int q = q0 + threadIdx.x;
  bool act = (q < 1600);
  float Lg[9] = {0.f,0.f,0.f,0.f,0.f,0.f,0.f,0.f,0.f};
  const ushort* qp = qT + (size_t)n * 409600 + (act ? (size_t)q * 256 : 0);
  for (int c8 = 0; c8 < 256; c8 += 8) {
    h8 v = *(const h8*)(const void*)(qp + c8);
    #pragma unroll
    for (int j = 0; j < 8; ++j) {
      float f = (float)v[j];
      #pragma unroll
      for (int tt = 0; tt < 9; ++tt) Lg[tt] += f * ks[tt * 256 + c8 + j];
    }
  }
  float mx = Lg[0];
  #pragma unroll
  for (int tt = 1; tt < 9; ++tt) mx = fmaxf(mx, Lg[tt]);
  float Z = 0.f;
  float e[9];
  #pragma unroll
  for (int tt = 0; tt < 9; ++tt) {
    float m = ((tt / 3) == 1 ? 36.f : 1.f) * ((tt % 3) == 1 ? 36.f : 1.f);
    e[tt] = act ? m * expf(Lg[tt] - mx) : 0.f;
    Z += e[tt];
  }
  float inv = act ? (1.f / Z) : 0.f;
  #pragma unroll
  for (int tt = 0; tt < 9; ++tt) es[threadIdx.x][tt] = e[tt] * inv;
  __syncthreads();
  int nact = 1600 - q0; if (nact > 256) nact = 256;
  int p = threadIdx.x;
  for (int qq = 0; qq < nact; ++qq) {
    float s = 0.f;
    #pragma unroll
    for (int tt = 0; tt < 9; ++tt) s += es[qq][tt] * vs[tt * 256 + p];
    xaT[(size_t)n * 1228800 + (size_t)(q0 + qq) * 768 + 512 + p] = f2h(s);
  }
}

// ---------------------------------------------------------------------------
extern "C" void kernel_launch(void* const* d_in, const int* in_sizes, int n_in,
                              void* d_out, int out_size, void* d_ws, size_t ws_size,
                              hipStream_t stream)
{
  const float* x     = (const float*)d_in[0];
  const float* h0    = (const float*)d_in[1];
  const float* w_px  = (const float*)d_in[2];
  const float* b_px  = (const float*)d_in[3];
  const float* w_qx  = (const float*)d_in[4];
  const float* w_qh  = (const float*)d_in[5];
  const float* w_kx  = (const float*)d_in[6];
  const float* w_kh  = (const float*)d_in[7];
  const float* w_vx  = (const float*)d_in[8];
  const float* w_vh  = (const float*)d_in[9];
  const float* w_z   = (const float*)d_in[10];
  const float* b_z   = (const float*)d_in[11];
  const float* w_h   = (const float*)d_in[12];
  const float* b_h   = (const float*)d_in[13];
  const float* w_out = (const float*)d_in[14];
  const float* b_out = (const float*)d_in[15];
  float* out = (float*)d_out;

  char* base = (char*)d_ws;
  size_t off = 0;
  auto alloc = [&](size_t bytes) -> char* {
    off = (off + 255) & ~(size_t)255;
    char* p = base + off; off += bytes; return p;
  };
  ushort* xaT   = (ushort*)alloc(19660800);         // [8][1600][768] fp16
  ushort* qT    = (ushort*)alloc(6553600);          // [8][1600][256]
  ushort* kxT   = (ushort*)alloc(5914624);          // [8][1444][256]
  ushort* vxp   = (ushort*)alloc(6029312);          // [8][256][1472]
  ushort* xT    = (ushort*)alloc(3276800);          // [12800][128]
  ushort* Wqk   = (ushort*)alloc(2359296);          // [512][2304] conv-K order
  ushort* Wv    = (ushort*)alloc(1179648);          // [256][2304] conv-K order
  ushort* Wkv   = (ushort*)alloc(2359296);          // [512][2304]: w_kh|w_vh
  ushort* Wzh   = (ushort*)alloc(524288);           // [512][512]: w_z|w_h
  ushort* wpx   = (ushort*)alloc(65536);            // [256][128]
  ushort* wout  = (ushort*)alloc(393216);           // [256][768]
  ushort* zp    = (ushort*)alloc(128);              // 64-ushort zero page
  ushort* GA    = (ushort*)alloc(331776);           // [72][2304] fp16
  ushort* AV    = (ushort*)alloc(73728);            // [72][512] fp16
  float*  pre72p= (float*)alloc(589824);            // [4][72][512] partials
  float*  khvcp = (float*)alloc(884736);            // [6][72][512] partials
  float*  qh1   = (float*)alloc(9216);
  float*  kh1   = (float*)alloc(1024);
  float*  vh1   = (float*)alloc(1024);
  float*  L0    = (float*)alloc(415872);            // [8][9][1444]
  float*  a10   = (float*)alloc(73728);
  float*  h1    = (float*)alloc(73728);
  off = (off + 255) & ~(size_t)255;
  char* chunk = base + off;
  long avail = (long)ws_size - (long)off;
  if (avail < 0) avail = 0;
  int an = (int)(avail / 9420800L); if (an < 1) an = 1; if (an > 8) an = 8;

  auto mg = [&](dim3 grid,
                const ushort* A, long sAb, const ushort* B, long sBb,
                int M, int Nn, int K, int Krow, int mode, int gRow0, int swap,
                int aConv, int bConv,
                float* Y, long sYb, long sYm, int nPer, long sYb2,
                const float* bias, int biasN,
                ushort* Yh, long sYpb, long sYpm, long pOff, ushort* Y2h) {
    mgemm<<<grid, dim3(256), 0, stream>>>(A, sAb, B, sBb,
        M, Nn, K, Krow, mode, gRow0, swap, aConv, bConv, zp,
        Y, sYb, sYm, nPer, sYb2, bias, biasN, Yh, sYpb, sYpm, pOff, Y2h);
  };
  const int BIG = 0x40000000;

  // ---- 1) fused prep (all conversions + reorders + pads) ----
  prep_all<<<dim3(20064), dim3(256), 0, stream>>>(
      x, w_qx, w_kx, w_vx, w_px, w_out, w_kh, w_vh, w_z, w_h,
      xT, Wqk, Wv, wpx, wout, Wkv, Wzh, zp, vxp);

  // ---- 2) xp-conv: A=xT[12800][128], B=wpx -> xaT cols 0..255 ----
  mg(dim3(2, 100, 1), xT, 0, wpx, 0,
     12800, 256, 128, 128, 1, 0, 1, 0, 0,
     nullptr, 0, 0, 0, 0, b_px, 1,
     xaT, 0, 768, 0, nullptr);

  // ---- 3) direct shifted-tap convs (conv-K order) ----
  mg(dim3(4, 100, 1), xaT, 0, Wqk, 0,
     12800, 512, 2304, 2304, 2, 0, 1, 1, 0,
     nullptr, 0, 0, 0, 0, nullptr, 0,
     qT, 0, 0, 0, kxT);
  mg(dim3(2, 100, 1), Wv, 0, xaT, 0,
     256, 12800, 2304, 2304, 3, 0, 0, 0, 1,
     nullptr, 0, 0, 0, 0, nullptr, 0,
     vxp, 0, 0, 0, nullptr);

  // ---- 4) classed section (K-sliced 72-row MFMA GEMMs) ----
  uniform_kv_kern<<<dim3(256, 11), dim3(64), 0, stream>>>(h0, w_qh, w_kh, w_vh, qh1, kh1, vh1);
  l0_logits<<<dim3(6, 8), dim3(256), 0, stream>>>(qh1, kxT, L0);
  softmax_rows<<<dim3(72), dim3(256), 0, stream>>>(L0, 1444);
  a10_pv<<<dim3(9, 8), dim3(256), 0, stream>>>(L0, vxp, a10);
  build_AV<<<dim3(144), dim3(256), 0, stream>>>(a10, vh1, AV);
  // AV[72][512] x Wzh[512][512], 4 K-slices of 128 -> pre72p[4][72][512]
  mg(dim3(1, 4, 4), AV, 128, Wzh, 128,
     72, 512, 128, 512, 0, 0, 0, 0, 0,
     pre72p, 36864, 512, BIG, 0, nullptr, 0,
     nullptr, 0, 0, 0, nullptr);
  gate_ew2<<<dim3(72), dim3(256), 0, stream>>>(pre72p, b_z, b_h, h0, h1);
  build_GA<<<dim3(648), dim3(256), 0, stream>>>(h1, GA);
  // GA[72][2304] x Wkv[512][2304], 6 K-slices of 384 -> khvcp[6][72][512]
  mg(dim3(1, 4, 6), GA, 384, Wkv, 384,
     72, 512, 384, 2304, 0, 0, 0, 0, 0,
     khvcp, 36864, 512, BIG, 0, nullptr, 0,
     nullptr, 0, 0, 0, nullptr);
  attn_b1<<<dim3(7, 8), dim3(256), 0, stream>>>(qT, khvcp, xaT);

  // ---- 5) step-2 (0,0) full attention (fp16 logits) ----
  {
    ushort* scL16 = (ushort*)chunk;
    for (int nb0 = 0; nb0 < 8; nb0 += an) {
      int c = (8 - nb0 < an) ? (8 - nb0) : an;
      ushort* wt = (ushort*)(chunk + (long)c * 4710400);
      mg(dim3(13, 12, c), qT + (long)nb0 * 409600, 409600,
         kxT + (long)nb0 * 369664, 369664,
         1600, 1444, 256, 256, 1, 0, 0, 0, 0,
         nullptr, 0, 0, 0, 0, nullptr, 0,
         scL16, 2355200, 1472, 0, nullptr);
      softmax_h16<<<dim3(c * 1600), dim3(256), 0, stream>>>(scL16, wt);
      mg(dim3(13, 2, c), wt, 2355200,
         vxp + (long)nb0 * 376832, 376832,
         1600, 256, 1472, 1472, 1, 0, 0, 0, 0,
         nullptr, 0, 0, 0, 0, nullptr, 0,
         xaT + (long)nb0 * 1228800, 1228800, 768, 256, nullptr);
    }
  }

  // ---- 6) out-conv: A=wout[256][768], B=xaT rows -> fp32 NCHW ----
  mg(dim3(2, 100, 1), wout, 0, xaT, 0,
     256, 12800, 768, 768, 0, 0, 0, 0, 0,
     out, 0, 1600, 1600, 409600, b_out, 0,
     nullptr, 0, 0, 0, nullptr);
}